// Round 1
// baseline (3324.638 us; speedup 1.0000x reference)
//
#include <hip/hip_runtime.h>

#define NN 50000
#define NE 800000

// ---------------- SGEMM 64x64 tile, K multiple of 16, N multiple of 64 ----------------
__global__ __launch_bounds__(256) void sgemm_64x64(
    const float* __restrict__ A, const float* __restrict__ B, float* __restrict__ C,
    int M, int K, int N)
{
    __shared__ float As[16][68];   // [k][m], padded to avoid store conflicts, keeps 16B align
    __shared__ float Bs[16][64];   // [k][n]
    const int tid = threadIdx.x;
    const int tx = tid & 15;       // col group
    const int ty = tid >> 4;       // row group
    const int row0 = blockIdx.x * 64;
    const int col0 = blockIdx.y * 64;

    float acc[4][4];
#pragma unroll
    for (int i = 0; i < 4; ++i)
#pragma unroll
        for (int j = 0; j < 4; ++j) acc[i][j] = 0.f;

    const int lm = tid >> 2;         // 0..63: A row in tile
    const int lk = (tid & 3) << 2;   // 0,4,8,12: A col in tile
    const int br = tid >> 4;         // 0..15: B row in tile
    const int bc = (tid & 15) << 2;  // B col in tile

    for (int k0 = 0; k0 < K; k0 += 16) {
        float4 av;
        const int arow = row0 + lm;
        if (arow < M) av = *(const float4*)&A[(long)arow * K + k0 + lk];
        else          av = make_float4(0.f, 0.f, 0.f, 0.f);
        As[lk + 0][lm] = av.x;
        As[lk + 1][lm] = av.y;
        As[lk + 2][lm] = av.z;
        As[lk + 3][lm] = av.w;
        *(float4*)&Bs[br][bc] = *(const float4*)&B[(long)(k0 + br) * N + col0 + bc];
        __syncthreads();
#pragma unroll
        for (int k = 0; k < 16; ++k) {
            const float4 a = *(const float4*)&As[k][ty << 2];
            const float4 b = *(const float4*)&Bs[k][tx << 2];
            const float avv[4] = {a.x, a.y, a.z, a.w};
            const float bvv[4] = {b.x, b.y, b.z, b.w};
#pragma unroll
            for (int i = 0; i < 4; ++i)
#pragma unroll
                for (int j = 0; j < 4; ++j)
                    acc[i][j] = fmaf(avv[i], bvv[j], acc[i][j]);
        }
        __syncthreads();
    }
#pragma unroll
    for (int i = 0; i < 4; ++i) {
        const int row = row0 + (ty << 2) + i;
        if (row < M) {
            float4 o = make_float4(acc[i][0], acc[i][1], acc[i][2], acc[i][3]);
            *(float4*)&C[(long)row * N + col0 + (tx << 2)] = o;
        }
    }
}

// ---------------- GEMM K=256, N=32 (output layer projection) ----------------
__global__ __launch_bounds__(256) void sgemm_k256_n32(
    const float* __restrict__ A, const float* __restrict__ B, float* __restrict__ C, int M)
{
    __shared__ float Al[32][260];   // padded: bank = (4*ty + k) % 32, conflict-free
    __shared__ float Bl[256 * 32];  // flat, same layout as B
    const int tid = threadIdx.x;
    const int row0 = blockIdx.x * 32;

#pragma unroll
    for (int i = 0; i < 8; ++i) {
        const int f = i * 1024 + tid * 4;
        *(float4*)&Bl[f] = *(const float4*)&B[f];
    }
#pragma unroll
    for (int i = 0; i < 8; ++i) {
        const int f = i * 1024 + tid * 4;
        const int r = f >> 8, c = f & 255;
        float4 v;
        if (row0 + r < M) v = *(const float4*)&A[(long)(row0 + r) * 256 + c];
        else              v = make_float4(0.f, 0.f, 0.f, 0.f);
        *(float4*)&Al[r][c] = v;
    }
    __syncthreads();

    const int tx = tid & 7;    // col group: 4 cols
    const int ty = tid >> 3;   // row 0..31
    float acc[4] = {0.f, 0.f, 0.f, 0.f};
#pragma unroll 8
    for (int k = 0; k < 256; ++k) {
        const float a = Al[ty][k];
        const float4 b = *(const float4*)&Bl[k * 32 + tx * 4];
        acc[0] = fmaf(a, b.x, acc[0]);
        acc[1] = fmaf(a, b.y, acc[1]);
        acc[2] = fmaf(a, b.z, acc[2]);
        acc[3] = fmaf(a, b.w, acc[3]);
    }
    const int row = row0 + ty;
    if (row < M) {
        float4 o = make_float4(acc[0], acc[1], acc[2], acc[3]);
        *(float4*)&C[(long)row * 32 + tx * 4] = o;
    }
}

// ---------------- edge scatter: out[dst] += w * h[src], F=128, out row stride 256 ----------------
__global__ __launch_bounds__(256) void scatter_f128(
    const float* __restrict__ h, const int* __restrict__ src, const int* __restrict__ dst,
    const float* __restrict__ w, float* __restrict__ out)
{
    const int tid = blockIdx.x * 256 + threadIdx.x;
    const int e = tid >> 5;
    if (e >= NE) return;
    const int c = (tid & 31) << 2;
    const int s = src[e], d = dst[e];
    const float we = w[e];
    const float4 v = *(const float4*)&h[(long)s * 128 + c];
    float* o = out + (long)d * 256 + c;
    atomicAdd(o + 0, v.x * we);
    atomicAdd(o + 1, v.y * we);
    atomicAdd(o + 2, v.z * we);
    atomicAdd(o + 3, v.w * we);
}

// ---------------- edge scatter: F=32, out row stride 32 ----------------
__global__ __launch_bounds__(256) void scatter_f32(
    const float* __restrict__ h, const int* __restrict__ src, const int* __restrict__ dst,
    const float* __restrict__ w, float* __restrict__ out)
{
    const int tid = blockIdx.x * 256 + threadIdx.x;
    const int e = tid >> 3;
    if (e >= NE) return;
    const int c = (tid & 7) << 2;
    const int s = src[e], d = dst[e];
    const float we = w[e];
    const float4 v = *(const float4*)&h[(long)s * 32 + c];
    float* o = out + (long)d * 32 + c;
    atomicAdd(o + 0, v.x * we);
    atomicAdd(o + 1, v.y * we);
    atomicAdd(o + 2, v.z * we);
    atomicAdd(o + 3, v.w * we);
}

// ---------------- BN: per-channel sum / sumsq over pre (row stride 256, 128 channels) ----------------
__global__ __launch_bounds__(256) void bn_stats(
    const float* __restrict__ pre, float* __restrict__ sum, float* __restrict__ ss, int M)
{
    const int c = threadIdx.x & 127;
    const int half = threadIdx.x >> 7;
    float s = 0.f, q = 0.f;
    for (int row = blockIdx.x * 2 + half; row < M; row += gridDim.x * 2) {
        const float v = pre[(long)row * 256 + c];
        s += v;
        q = fmaf(v, v, q);
    }
    __shared__ float ls[256], lq[256];
    ls[threadIdx.x] = s;
    lq[threadIdx.x] = q;
    __syncthreads();
    if (threadIdx.x < 128) {
        atomicAdd(&sum[c], ls[threadIdx.x] + ls[threadIdx.x + 128]);
        atomicAdd(&ss[c], lq[threadIdx.x] + lq[threadIdx.x + 128]);
    }
}

__global__ void bn_finalize(
    const float* __restrict__ sum, const float* __restrict__ ss,
    const float* __restrict__ gamma, const float* __restrict__ beta,
    float* __restrict__ scale, float* __restrict__ shift, int M)
{
    const int c = threadIdx.x;  // 128 threads
    const float inv = 1.f / (float)M;
    const float mu = sum[c] * inv;
    const float var = ss[c] * inv - mu * mu;
    const float sc = gamma[c] * rsqrtf(var + 1e-5f);
    scale[c] = sc;
    shift[c] = beta[c] - mu * sc;
}

// reads x[row*256 + 128 + c] (pre), writes relu(bn) to x[row*256 + c]
__global__ __launch_bounds__(256) void bn_apply(
    float* __restrict__ x, const float* __restrict__ scale, const float* __restrict__ shift, int M)
{
    const int tid = blockIdx.x * 256 + threadIdx.x;
    const int row = tid >> 5;
    if (row >= M) return;
    const int c = (tid & 31) << 2;
    const float4 v = *(const float4*)&x[(long)row * 256 + 128 + c];
    const float4 sc = *(const float4*)&scale[c];
    const float4 sh = *(const float4*)&shift[c];
    float4 o;
    o.x = fmaxf(fmaf(v.x, sc.x, sh.x), 0.f);
    o.y = fmaxf(fmaf(v.y, sc.y, sh.y), 0.f);
    o.z = fmaxf(fmaf(v.z, sc.z, sh.z), 0.f);
    o.w = fmaxf(fmaf(v.w, sc.w, sh.w), 0.f);
    *(float4*)&x[(long)row * 256 + c] = o;
}

extern "C" void kernel_launch(void* const* d_in, const int* in_sizes, int n_in,
                              void* d_out, int out_size, void* d_ws, size_t ws_size,
                              hipStream_t stream) {
    const float* x  = (const float*)d_in[0];
    const int*   src = (const int*)d_in[1];
    const int*   dst = (const int*)d_in[2];
    const float* ew  = (const float*)d_in[3];
    const float* W0  = (const float*)d_in[4];
    const float* W1  = (const float*)d_in[5];
    const float* W2  = (const float*)d_in[6];
    const float* g0  = (const float*)d_in[7];
    const float* b0  = (const float*)d_in[8];
    const float* g1  = (const float*)d_in[9];
    const float* b1  = (const float*)d_in[10];
    float* out = (float*)d_out;

    // workspace layout (floats): h[50000*128] | x1[50000*256] | stats[1024]
    float* h  = (float*)d_ws;
    float* x1 = h + (size_t)NN * 128;
    float* st = x1 + (size_t)NN * 256;
    float* sum0 = st,        *ss0 = st + 128, *sc0 = st + 256, *sh0 = st + 384;
    float* sum1 = st + 512,  *ss1 = st + 640, *sc1 = st + 768, *sh1 = st + 896;

    const dim3 gGemm(782, 2);  // ceil(50000/64) x (128/64)

    // ---- layer 0 ----
    hipMemsetAsync(x1, 0, (size_t)NN * 256 * 4, stream);
    hipMemsetAsync(st, 0, 1024 * 4, stream);
    hipMemsetAsync(out, 0, (size_t)out_size * 4, stream);
    sgemm_64x64<<<gGemm, 256, 0, stream>>>(x, W0, h, NN, 256, 128);
    scatter_f128<<<NE * 32 / 256, 256, 0, stream>>>(h, src, dst, ew, x1 + 128);
    bn_stats<<<256, 256, 0, stream>>>(x1 + 128, sum0, ss0, NN);
    bn_finalize<<<1, 128, 0, stream>>>(sum0, ss0, g0, b0, sc0, sh0, NN);
    bn_apply<<<NN * 32 / 256, 256, 0, stream>>>(x1, sc0, sh0, NN);

    // ---- layer 1 (x2 aliases x1: x1 is dead after sgemm reads it) ----
    sgemm_64x64<<<gGemm, 256, 0, stream>>>(x1, W1, h, NN, 256, 128);
    hipMemsetAsync(x1, 0, (size_t)NN * 256 * 4, stream);
    scatter_f128<<<NE * 32 / 256, 256, 0, stream>>>(h, src, dst, ew, x1 + 128);
    bn_stats<<<256, 256, 0, stream>>>(x1 + 128, sum1, ss1, NN);
    bn_finalize<<<1, 128, 0, stream>>>(sum1, ss1, g1, b1, sc1, sh1, NN);
    bn_apply<<<NN * 32 / 256, 256, 0, stream>>>(x1, sc1, sh1, NN);

    // ---- output layer ----
    sgemm_k256_n32<<<(NN + 31) / 32, 256, 0, stream>>>(x1, W2, h, NN);
    scatter_f32<<<NE * 8 / 256, 256, 0, stream>>>(h, src, dst, ew, out);
}

// Round 2
// 619.735 us; speedup vs baseline: 5.3646x; 5.3646x over previous
//
#include <hip/hip_runtime.h>

#define NN 50000
#define NE 800000

// ---------------- SGEMM 64x64 tile, K multiple of 16, N multiple of 64 ----------------
__global__ __launch_bounds__(256) void sgemm_64x64(
    const float* __restrict__ A, const float* __restrict__ B, float* __restrict__ C,
    int M, int K, int N)
{
    __shared__ float As[16][68];
    __shared__ float Bs[16][64];
    const int tid = threadIdx.x;
    const int tx = tid & 15;
    const int ty = tid >> 4;
    const int row0 = blockIdx.x * 64;
    const int col0 = blockIdx.y * 64;

    float acc[4][4];
#pragma unroll
    for (int i = 0; i < 4; ++i)
#pragma unroll
        for (int j = 0; j < 4; ++j) acc[i][j] = 0.f;

    const int lm = tid >> 2;
    const int lk = (tid & 3) << 2;
    const int br = tid >> 4;
    const int bc = (tid & 15) << 2;

    for (int k0 = 0; k0 < K; k0 += 16) {
        float4 av;
        const int arow = row0 + lm;
        if (arow < M) av = *(const float4*)&A[(long)arow * K + k0 + lk];
        else          av = make_float4(0.f, 0.f, 0.f, 0.f);
        As[lk + 0][lm] = av.x;
        As[lk + 1][lm] = av.y;
        As[lk + 2][lm] = av.z;
        As[lk + 3][lm] = av.w;
        *(float4*)&Bs[br][bc] = *(const float4*)&B[(long)(k0 + br) * N + col0 + bc];
        __syncthreads();
#pragma unroll
        for (int k = 0; k < 16; ++k) {
            const float4 a = *(const float4*)&As[k][ty << 2];
            const float4 b = *(const float4*)&Bs[k][tx << 2];
            const float avv[4] = {a.x, a.y, a.z, a.w};
            const float bvv[4] = {b.x, b.y, b.z, b.w};
#pragma unroll
            for (int i = 0; i < 4; ++i)
#pragma unroll
                for (int j = 0; j < 4; ++j)
                    acc[i][j] = fmaf(avv[i], bvv[j], acc[i][j]);
        }
        __syncthreads();
    }
#pragma unroll
    for (int i = 0; i < 4; ++i) {
        const int row = row0 + (ty << 2) + i;
        if (row < M) {
            float4 o = make_float4(acc[i][0], acc[i][1], acc[i][2], acc[i][3]);
            *(float4*)&C[(long)row * N + col0 + (tx << 2)] = o;
        }
    }
}

// ---------------- GEMM K=256, N=32 (output layer projection) ----------------
__global__ __launch_bounds__(256) void sgemm_k256_n32(
    const float* __restrict__ A, const float* __restrict__ B, float* __restrict__ C, int M)
{
    __shared__ float Al[32][260];
    __shared__ float Bl[256 * 32];
    const int tid = threadIdx.x;
    const int row0 = blockIdx.x * 32;

#pragma unroll
    for (int i = 0; i < 8; ++i) {
        const int f = i * 1024 + tid * 4;
        *(float4*)&Bl[f] = *(const float4*)&B[f];
    }
#pragma unroll
    for (int i = 0; i < 8; ++i) {
        const int f = i * 1024 + tid * 4;
        const int r = f >> 8, c = f & 255;
        float4 v;
        if (row0 + r < M) v = *(const float4*)&A[(long)(row0 + r) * 256 + c];
        else              v = make_float4(0.f, 0.f, 0.f, 0.f);
        *(float4*)&Al[r][c] = v;
    }
    __syncthreads();

    const int tx = tid & 7;
    const int ty = tid >> 3;
    float acc[4] = {0.f, 0.f, 0.f, 0.f};
#pragma unroll 8
    for (int k = 0; k < 256; ++k) {
        const float a = Al[ty][k];
        const float4 b = *(const float4*)&Bl[k * 32 + tx * 4];
        acc[0] = fmaf(a, b.x, acc[0]);
        acc[1] = fmaf(a, b.y, acc[1]);
        acc[2] = fmaf(a, b.z, acc[2]);
        acc[3] = fmaf(a, b.w, acc[3]);
    }
    const int row = row0 + ty;
    if (row < M) {
        float4 o = make_float4(acc[0], acc[1], acc[2], acc[3]);
        *(float4*)&C[(long)row * 32 + tx * 4] = o;
    }
}

// ================= CSR build =================
__global__ __launch_bounds__(256) void hist_k(const int* __restrict__ dst, int* __restrict__ deg)
{
    const int e = blockIdx.x * 256 + threadIdx.x;
    if (e < NE) atomicAdd(&deg[dst[e]], 1);
}

// block-local exclusive scan; bsum[b] = block total
__global__ __launch_bounds__(256) void scan1_k(const int* __restrict__ deg, int* __restrict__ rs, int* __restrict__ bsum)
{
    __shared__ int tmp[256];
    const int i = blockIdx.x * 256 + threadIdx.x;
    const int v = (i < NN) ? deg[i] : 0;
    tmp[threadIdx.x] = v;
    __syncthreads();
    for (int off = 1; off < 256; off <<= 1) {
        const int t = (threadIdx.x >= off) ? tmp[threadIdx.x - off] : 0;
        __syncthreads();
        tmp[threadIdx.x] += t;
        __syncthreads();
    }
    if (i < NN) rs[i] = tmp[threadIdx.x] - v;
    if (threadIdx.x == 255) bsum[blockIdx.x] = tmp[255];
}

__global__ void scan2_k(const int* __restrict__ bsum, int* __restrict__ boff, int nb)
{
    __shared__ int tmp[256];
    const int v = (threadIdx.x < nb) ? bsum[threadIdx.x] : 0;
    tmp[threadIdx.x] = v;
    __syncthreads();
    for (int off = 1; off < 256; off <<= 1) {
        const int t = (threadIdx.x >= off) ? tmp[threadIdx.x - off] : 0;
        __syncthreads();
        tmp[threadIdx.x] += t;
        __syncthreads();
    }
    if (threadIdx.x < nb) boff[threadIdx.x] = tmp[threadIdx.x] - v;
}

__global__ __launch_bounds__(256) void addoff_k(int* __restrict__ rs, const int* __restrict__ boff, int* __restrict__ cursor)
{
    const int i = blockIdx.x * 256 + threadIdx.x;
    if (i < NN) {
        const int r = rs[i] + boff[blockIdx.x];
        rs[i] = r;
        cursor[i] = r;
    }
    if (i == 0) rs[NN] = NE;
}

__global__ __launch_bounds__(256) void fill_k(
    const int* __restrict__ src, const int* __restrict__ dst, const float* __restrict__ ew,
    int* __restrict__ cursor, int* __restrict__ psrc, float* __restrict__ pw)
{
    const int e = blockIdx.x * 256 + threadIdx.x;
    if (e >= NE) return;
    const int d = dst[e];
    const int pos = atomicAdd(&cursor[d], 1);
    psrc[pos] = src[e];
    pw[pos] = ew[e];
}

// ================= gather aggregation =================
// out row stride 256 (writes the pre half of the concat buffer), F=128
__global__ __launch_bounds__(256) void agg_f128(
    const float* __restrict__ h, const int* __restrict__ rs,
    const int* __restrict__ psrc, const float* __restrict__ pw, float* __restrict__ out)
{
    const int node = blockIdx.x * 2 + (threadIdx.x >> 7);
    const int c = threadIdx.x & 127;
    if (node >= NN) return;
    int j = rs[node];
    const int j1 = rs[node + 1];
    float acc0 = 0.f, acc1 = 0.f;
    for (; j + 1 < j1; j += 2) {
        const int s0 = psrc[j], s1 = psrc[j + 1];
        const float w0 = pw[j], w1 = pw[j + 1];
        acc0 = fmaf(w0, h[(long)s0 * 128 + c], acc0);
        acc1 = fmaf(w1, h[(long)s1 * 128 + c], acc1);
    }
    if (j < j1) acc0 = fmaf(pw[j], h[(long)psrc[j] * 128 + c], acc0);
    out[(long)node * 256 + c] = acc0 + acc1;
}

// out row stride 32, F=32 (final output)
__global__ __launch_bounds__(256) void agg_f32(
    const float* __restrict__ h, const int* __restrict__ rs,
    const int* __restrict__ psrc, const float* __restrict__ pw, float* __restrict__ out)
{
    const int node = blockIdx.x * 8 + (threadIdx.x >> 5);
    const int c = threadIdx.x & 31;
    if (node >= NN) return;
    int j = rs[node];
    const int j1 = rs[node + 1];
    float acc0 = 0.f, acc1 = 0.f;
    for (; j + 1 < j1; j += 2) {
        const int s0 = psrc[j], s1 = psrc[j + 1];
        const float w0 = pw[j], w1 = pw[j + 1];
        acc0 = fmaf(w0, h[(long)s0 * 32 + c], acc0);
        acc1 = fmaf(w1, h[(long)s1 * 32 + c], acc1);
    }
    if (j < j1) acc0 = fmaf(pw[j], h[(long)psrc[j] * 32 + c], acc0);
    out[(long)node * 32 + c] = acc0 + acc1;
}

// ---------------- BN ----------------
__global__ __launch_bounds__(256) void bn_stats(
    const float* __restrict__ pre, float* __restrict__ sum, float* __restrict__ ss, int M)
{
    const int c = threadIdx.x & 127;
    const int half = threadIdx.x >> 7;
    float s = 0.f, q = 0.f;
    for (int row = blockIdx.x * 2 + half; row < M; row += gridDim.x * 2) {
        const float v = pre[(long)row * 256 + c];
        s += v;
        q = fmaf(v, v, q);
    }
    __shared__ float ls[256], lq[256];
    ls[threadIdx.x] = s;
    lq[threadIdx.x] = q;
    __syncthreads();
    if (threadIdx.x < 128) {
        atomicAdd(&sum[c], ls[threadIdx.x] + ls[threadIdx.x + 128]);
        atomicAdd(&ss[c], lq[threadIdx.x] + lq[threadIdx.x + 128]);
    }
}

__global__ void bn_finalize(
    const float* __restrict__ sum, const float* __restrict__ ss,
    const float* __restrict__ gamma, const float* __restrict__ beta,
    float* __restrict__ scale, float* __restrict__ shift, int M)
{
    const int c = threadIdx.x;
    const float inv = 1.f / (float)M;
    const float mu = sum[c] * inv;
    const float var = ss[c] * inv - mu * mu;
    const float sc = gamma[c] * rsqrtf(var + 1e-5f);
    scale[c] = sc;
    shift[c] = beta[c] - mu * sc;
}

__global__ __launch_bounds__(256) void bn_apply(
    float* __restrict__ x, const float* __restrict__ scale, const float* __restrict__ shift, int M)
{
    const int tid = blockIdx.x * 256 + threadIdx.x;
    const int row = tid >> 5;
    if (row >= M) return;
    const int c = (tid & 31) << 2;
    const float4 v = *(const float4*)&x[(long)row * 256 + 128 + c];
    const float4 sc = *(const float4*)&scale[c];
    const float4 sh = *(const float4*)&shift[c];
    float4 o;
    o.x = fmaxf(fmaf(v.x, sc.x, sh.x), 0.f);
    o.y = fmaxf(fmaf(v.y, sc.y, sh.y), 0.f);
    o.z = fmaxf(fmaf(v.z, sc.z, sh.z), 0.f);
    o.w = fmaxf(fmaf(v.w, sc.w, sh.w), 0.f);
    *(float4*)&x[(long)row * 256 + c] = o;
}

extern "C" void kernel_launch(void* const* d_in, const int* in_sizes, int n_in,
                              void* d_out, int out_size, void* d_ws, size_t ws_size,
                              hipStream_t stream) {
    const float* x  = (const float*)d_in[0];
    const int*   src = (const int*)d_in[1];
    const int*   dst = (const int*)d_in[2];
    const float* ew  = (const float*)d_in[3];
    const float* W0  = (const float*)d_in[4];
    const float* W1  = (const float*)d_in[5];
    const float* W2  = (const float*)d_in[6];
    const float* g0  = (const float*)d_in[7];
    const float* b0  = (const float*)d_in[8];
    const float* g1  = (const float*)d_in[9];
    const float* b1  = (const float*)d_in[10];
    float* out = (float*)d_out;

    // workspace layout (floats/ints):
    // h[50000*128] | x1[50000*256] | st[1024] | rs[50001+pad] | deg/cursor[50000]
    // | bsum[256] | boff[256] | psrc[800000] | pw[800000]
    float* h  = (float*)d_ws;
    float* x1 = h + (size_t)NN * 128;
    float* st = x1 + (size_t)NN * 256;
    int*   rs = (int*)(st + 1024);
    int*   deg = rs + 50004;          // doubles as cursor
    int*   bsum = deg + NN;
    int*   boff = bsum + 256;
    int*   psrc = boff + 256;
    float* pw   = (float*)(psrc + NE);

    float* sum0 = st,        *ss0 = st + 128, *sc0 = st + 256, *sh0 = st + 384;
    float* sum1 = st + 512,  *ss1 = st + 640, *sc1 = st + 768, *sh1 = st + 896;

    const dim3 gGemm(782, 2);
    const int gE = (NE + 255) / 256;      // 3125
    const int gN = (NN + 255) / 256;      // 196

    // ---- CSR build (dst identical for all 3 aggregations) ----
    hipMemsetAsync(deg, 0, (size_t)NN * 4, stream);
    hipMemsetAsync(st, 0, 1024 * 4, stream);
    hist_k<<<gE, 256, 0, stream>>>(dst, deg);
    scan1_k<<<gN, 256, 0, stream>>>(deg, rs, bsum);
    scan2_k<<<1, 256, 0, stream>>>(bsum, boff, gN);
    addoff_k<<<gN, 256, 0, stream>>>(rs, boff, deg);
    fill_k<<<gE, 256, 0, stream>>>(src, dst, ew, deg, psrc, pw);

    // ---- layer 0 ----
    sgemm_64x64<<<gGemm, 256, 0, stream>>>(x, W0, h, NN, 256, 128);
    agg_f128<<<NN / 2, 256, 0, stream>>>(h, rs, psrc, pw, x1 + 128);
    bn_stats<<<256, 256, 0, stream>>>(x1 + 128, sum0, ss0, NN);
    bn_finalize<<<1, 128, 0, stream>>>(sum0, ss0, g0, b0, sc0, sh0, NN);
    bn_apply<<<NN * 32 / 256, 256, 0, stream>>>(x1, sc0, sh0, NN);

    // ---- layer 1 ----
    sgemm_64x64<<<gGemm, 256, 0, stream>>>(x1, W1, h, NN, 256, 128);
    agg_f128<<<NN / 2, 256, 0, stream>>>(h, rs, psrc, pw, x1 + 128);
    bn_stats<<<256, 256, 0, stream>>>(x1 + 128, sum1, ss1, NN);
    bn_finalize<<<1, 128, 0, stream>>>(sum1, ss1, g1, b1, sc1, sh1, NN);
    bn_apply<<<NN * 32 / 256, 256, 0, stream>>>(x1, sc1, sh1, NN);

    // ---- output layer ----
    sgemm_k256_n32<<<(NN + 31) / 32, 256, 0, stream>>>(x1, W2, h, NN);
    agg_f32<<<(NN + 7) / 8, 256, 0, stream>>>(h, rs, psrc, pw, out);
}

// Round 3
// 434.557 us; speedup vs baseline: 7.6506x; 1.4261x over previous
//
#include <hip/hip_runtime.h>

#define NN 50000
#define NE 800000

typedef __attribute__((ext_vector_type(8))) short bf16x8;
typedef __attribute__((ext_vector_type(4))) float f32x4;

__device__ inline float blo(unsigned u) { union { unsigned i; float f; } c; c.i = u << 16; return c.f; }
__device__ inline float bhi(unsigned u) { union { unsigned i; float f; } c; c.i = u & 0xFFFF0000u; return c.f; }
__device__ inline unsigned short f2b(float f) {
    union { float f; unsigned u; } c; c.f = f;
    return (unsigned short)((c.u + 0x7FFFu + ((c.u >> 16) & 1u)) >> 16);
}
__device__ inline unsigned pack2(float x, float y) {
    union { float f; unsigned u; } a, b; a.f = x; b.f = y;
    const unsigned lo = (a.u + 0x7FFFu + ((a.u >> 16) & 1u)) >> 16;
    const unsigned hi = (b.u + 0x7FFFu + ((b.u >> 16) & 1u)) & 0xFFFF0000u;
    return (lo & 0xFFFFu) | hi;
}

// ================= CSR build =================
__global__ __launch_bounds__(256) void hist_k(const int* __restrict__ dst, int* __restrict__ deg)
{
    const int e = blockIdx.x * 256 + threadIdx.x;
    if (e < NE) atomicAdd(&deg[dst[e]], 1);
}

__global__ __launch_bounds__(256) void scan1_k(const int* __restrict__ deg, int* __restrict__ rs, int* __restrict__ bsum)
{
    __shared__ int tmp[256];
    const int i = blockIdx.x * 256 + threadIdx.x;
    const int v = (i < NN) ? deg[i] : 0;
    tmp[threadIdx.x] = v;
    __syncthreads();
    for (int off = 1; off < 256; off <<= 1) {
        const int t = (threadIdx.x >= off) ? tmp[threadIdx.x - off] : 0;
        __syncthreads();
        tmp[threadIdx.x] += t;
        __syncthreads();
    }
    if (i < NN) rs[i] = tmp[threadIdx.x] - v;
    if (threadIdx.x == 255) bsum[blockIdx.x] = tmp[255];
}

__global__ void scan2_k(const int* __restrict__ bsum, int* __restrict__ boff, int nb)
{
    __shared__ int tmp[256];
    const int v = (threadIdx.x < nb) ? bsum[threadIdx.x] : 0;
    tmp[threadIdx.x] = v;
    __syncthreads();
    for (int off = 1; off < 256; off <<= 1) {
        const int t = (threadIdx.x >= off) ? tmp[threadIdx.x - off] : 0;
        __syncthreads();
        tmp[threadIdx.x] += t;
        __syncthreads();
    }
    if (threadIdx.x < nb) boff[threadIdx.x] = tmp[threadIdx.x] - v;
}

__global__ __launch_bounds__(256) void addoff_k(int* __restrict__ rs, const int* __restrict__ boff, int* __restrict__ cursor)
{
    const int i = blockIdx.x * 256 + threadIdx.x;
    if (i < NN) {
        const int r = rs[i] + boff[blockIdx.x];
        rs[i] = r;
        cursor[i] = r;
    }
    if (i == 0) rs[NN] = NE;
}

__global__ __launch_bounds__(256) void fill_k(
    const int* __restrict__ src, const int* __restrict__ dst, const float* __restrict__ ew,
    int* __restrict__ cursor, int2* __restrict__ pe)
{
    const int e = blockIdx.x * 256 + threadIdx.x;
    if (e >= NE) return;
    const int d = dst[e];
    const int pos = atomicAdd(&cursor[d], 1);
    pe[pos] = make_int2(src[e], __float_as_int(ew[e]));
}

// ================= casts / packing =================
__global__ __launch_bounds__(256) void cast_k(const float* __restrict__ x, unsigned* __restrict__ xb, int n4)
{
    const int i = blockIdx.x * 256 + threadIdx.x;
    if (i >= n4) return;
    const float4 v = ((const float4*)x)[i];
    uint2 o;
    o.x = pack2(v.x, v.y);
    o.y = pack2(v.z, v.w);
    ((uint2*)xb)[i] = o;
}

// Bp[((ks*NT+nt)*64+lane)*8+j] = bf16(B[(ks*32+(lane>>4)*8+j)][nt*16+(lane&15)])
__global__ __launch_bounds__(256) void packb_k(const float* __restrict__ B, short* __restrict__ Bp, int NT)
{
    const int o = blockIdx.x * 256 + threadIdx.x;
    if (o >= 4096 * NT) return;
    const int j = o & 7;
    const int lane = (o >> 3) & 63;
    const int tnt = o >> 9;
    const int nt = tnt % NT, ks = tnt / NT;
    const int k = ks * 32 + (lane >> 4) * 8 + j;
    const int n = nt * 16 + (lane & 15);
    Bp[o] = (short)f2b(B[k * (NT * 16) + n]);
}

// ================= MFMA GEMM: C[M, NT*16] = A[M, 256] @ B, bf16 in/out =================
template <int NT>
__global__ __launch_bounds__(256) void gemm_mfma(
    const short* __restrict__ A, const short* __restrict__ Bp,
    short* __restrict__ C, int M)
{
    __shared__ short Al[64 * 264];   // row stride 264 bf16 = 528 B
    const int tid = threadIdx.x;
    const int w = tid >> 6;
    const int lane = tid & 63;
    const int row0 = blockIdx.x * 64;

#pragma unroll
    for (int i = 0; i < 8; ++i) {
        const int chunk = tid + i * 256;        // 0..2047
        const int r = chunk >> 5;
        const int c8 = chunk & 31;
        float4 v = make_float4(0.f, 0.f, 0.f, 0.f);
        if (row0 + r < M) v = *(const float4*)&A[(long)(row0 + r) * 256 + c8 * 8];
        *(float4*)&Al[r * 264 + c8 * 8] = v;
    }
    __syncthreads();

    f32x4 acc[NT];
#pragma unroll
    for (int t = 0; t < NT; ++t) acc[t] = (f32x4){0.f, 0.f, 0.f, 0.f};

    const int quad = lane >> 4;
    const int abase = (w * 16 + (lane & 15)) * 264 + quad * 8;
#pragma unroll
    for (int ks = 0; ks < 8; ++ks) {
        const bf16x8 af = *(const bf16x8*)&Al[abase + ks * 32];
#pragma unroll
        for (int t = 0; t < NT; ++t) {
            const bf16x8 bf = *(const bf16x8*)&Bp[(((ks * NT + t) * 64) + lane) * 8];
            acc[t] = __builtin_amdgcn_mfma_f32_16x16x32_bf16(af, bf, acc[t], 0, 0, 0);
        }
    }

    __syncthreads();   // done reading A tile; reuse LDS for epilogue
    const int NC = NT * 16;
    float* Cl = (float*)Al + w * (16 * NC);
#pragma unroll
    for (int t = 0; t < NT; ++t)
#pragma unroll
        for (int r = 0; r < 4; ++r)
            Cl[(quad * 4 + r) * NC + t * 16 + (lane & 15)] = acc[t][r];
    // same-wave LDS readback (compiler inserts lgkmcnt wait)
#pragma unroll
    for (int i = 0; i < NC / 32; ++i) {
        const int f = i * 512 + lane * 8;
        const int r = f / NC;
        const int col = f % NC;
        const int grow = row0 + w * 16 + r;
        const float4 lo = *(float4*)&Cl[f];
        const float4 hi = *(float4*)&Cl[f + 4];
        uint4 o;
        o.x = pack2(lo.x, lo.y);
        o.y = pack2(lo.z, lo.w);
        o.z = pack2(hi.x, hi.y);
        o.w = pack2(hi.z, hi.w);
        if (grow < M) *(uint4*)&C[(long)grow * NC + col] = o;
    }
}

// ================= gather aggregation (bf16 h) =================
// one wave per node, 2 channels per lane; out row stride 128 uints (256 bf16)
__global__ __launch_bounds__(256) void agg128b(
    const unsigned* __restrict__ h2, const int* __restrict__ rs,
    const int2* __restrict__ pe, unsigned* __restrict__ outp)
{
    const int node = blockIdx.x * 4 + (threadIdx.x >> 6);
    const int l = threadIdx.x & 63;
    int j = rs[node];
    const int j1 = rs[node + 1];
    float a0 = 0.f, a1 = 0.f, b0 = 0.f, b1 = 0.f;
    for (; j + 1 < j1; j += 2) {
        const int2 e0 = pe[j], e1 = pe[j + 1];
        const unsigned v0 = h2[(long)e0.x * 64 + l];
        const unsigned v1 = h2[(long)e1.x * 64 + l];
        const float w0 = __int_as_float(e0.y), w1 = __int_as_float(e1.y);
        a0 = fmaf(w0, blo(v0), a0); a1 = fmaf(w0, bhi(v0), a1);
        b0 = fmaf(w1, blo(v1), b0); b1 = fmaf(w1, bhi(v1), b1);
    }
    if (j < j1) {
        const int2 e = pe[j];
        const unsigned v = h2[(long)e.x * 64 + l];
        const float w0 = __int_as_float(e.y);
        a0 = fmaf(w0, blo(v), a0); a1 = fmaf(w0, bhi(v), a1);
    }
    outp[(long)node * 128 + l] = pack2(a0 + b0, a1 + b1);
}

// h rows of 32 bf16 (16 uints); 16 lanes/node; fp32 output [NN,32]
__global__ __launch_bounds__(256) void agg32b(
    const unsigned* __restrict__ h2, const int* __restrict__ rs,
    const int2* __restrict__ pe, float* __restrict__ out)
{
    const int node = blockIdx.x * 16 + (threadIdx.x >> 4);
    const int l = threadIdx.x & 15;
    int j = rs[node];
    const int j1 = rs[node + 1];
    float a0 = 0.f, a1 = 0.f, b0 = 0.f, b1 = 0.f;
    for (; j + 1 < j1; j += 2) {
        const int2 e0 = pe[j], e1 = pe[j + 1];
        const unsigned v0 = h2[(long)e0.x * 16 + l];
        const unsigned v1 = h2[(long)e1.x * 16 + l];
        const float w0 = __int_as_float(e0.y), w1 = __int_as_float(e1.y);
        a0 = fmaf(w0, blo(v0), a0); a1 = fmaf(w0, bhi(v0), a1);
        b0 = fmaf(w1, blo(v1), b0); b1 = fmaf(w1, bhi(v1), b1);
    }
    if (j < j1) {
        const int2 e = pe[j];
        const unsigned v = h2[(long)e.x * 16 + l];
        const float w0 = __int_as_float(e.y);
        a0 = fmaf(w0, blo(v), a0); a1 = fmaf(w0, bhi(v), a1);
    }
    float2 o; o.x = a0 + b0; o.y = a1 + b1;
    *(float2*)&out[(long)node * 32 + 2 * l] = o;
}

// ================= BN (bf16 data, fp32 stats) =================
__global__ __launch_bounds__(256) void bn_stats_b(
    const unsigned* __restrict__ pre, float* __restrict__ sum, float* __restrict__ ss, int M)
{
    const int c2 = threadIdx.x & 63;
    const int g = threadIdx.x >> 6;
    float s0 = 0.f, s1 = 0.f, q0 = 0.f, q1 = 0.f;
    for (int row = blockIdx.x * 4 + g; row < M; row += gridDim.x * 4) {
        const unsigned v = pre[(long)row * 128 + c2];
        const float lo = blo(v), hi = bhi(v);
        s0 += lo; s1 += hi;
        q0 = fmaf(lo, lo, q0); q1 = fmaf(hi, hi, q1);
    }
    __shared__ float A0[256], A1[256], B0[256], B1[256];
    A0[threadIdx.x] = s0; A1[threadIdx.x] = s1;
    B0[threadIdx.x] = q0; B1[threadIdx.x] = q1;
    __syncthreads();
    if (threadIdx.x < 64) {
        const int t = threadIdx.x;
        atomicAdd(&sum[2 * t],     A0[t] + A0[t + 64] + A0[t + 128] + A0[t + 192]);
        atomicAdd(&sum[2 * t + 1], A1[t] + A1[t + 64] + A1[t + 128] + A1[t + 192]);
        atomicAdd(&ss[2 * t],      B0[t] + B0[t + 64] + B0[t + 128] + B0[t + 192]);
        atomicAdd(&ss[2 * t + 1],  B1[t] + B1[t + 64] + B1[t + 128] + B1[t + 192]);
    }
}

__global__ void bn_finalize(
    const float* __restrict__ sum, const float* __restrict__ ss,
    const float* __restrict__ gamma, const float* __restrict__ beta,
    float* __restrict__ scale, float* __restrict__ shift, int M)
{
    const int c = threadIdx.x;
    const float inv = 1.f / (float)M;
    const float mu = sum[c] * inv;
    const float var = ss[c] * inv - mu * mu;
    const float sc = gamma[c] * rsqrtf(var + 1e-5f);
    scale[c] = sc;
    shift[c] = beta[c] - mu * sc;
}

// reads pre (uints 64..127 of row), writes relu(bn) bf16 to uints 0..63
__global__ __launch_bounds__(256) void bn_apply_b(
    unsigned* __restrict__ x1, const float* __restrict__ scale, const float* __restrict__ shift, int M)
{
    const int idx = blockIdx.x * 256 + threadIdx.x;
    const int row = idx >> 6;
    if (row >= M) return;
    const int c2 = idx & 63;
    const unsigned v = x1[(long)row * 128 + 64 + c2];
    const float2 sc = ((const float2*)scale)[c2];
    const float2 sh = ((const float2*)shift)[c2];
    const float lo = fmaxf(fmaf(blo(v), sc.x, sh.x), 0.f);
    const float hi = fmaxf(fmaf(bhi(v), sc.y, sh.y), 0.f);
    x1[(long)row * 128 + c2] = pack2(lo, hi);
}

extern "C" void kernel_launch(void* const* d_in, const int* in_sizes, int n_in,
                              void* d_out, int out_size, void* d_ws, size_t ws_size,
                              hipStream_t stream) {
    const float* x   = (const float*)d_in[0];
    const int*   src = (const int*)d_in[1];
    const int*   dst = (const int*)d_in[2];
    const float* ew  = (const float*)d_in[3];
    const float* W0  = (const float*)d_in[4];
    const float* W1  = (const float*)d_in[5];
    const float* W2  = (const float*)d_in[6];
    const float* g0  = (const float*)d_in[7];
    const float* b0  = (const float*)d_in[8];
    const float* g1  = (const float*)d_in[9];
    const float* b1  = (const float*)d_in[10];
    float* out = (float*)d_out;

    // workspace layout
    short* xb = (short*)d_ws;                    // [NN*256] bf16
    short* h  = xb + (size_t)NN * 256;           // [NN*128] bf16 (also [NN*32] for out layer)
    short* x1 = h + (size_t)NN * 128;            // [NN*256] bf16 concat buffer
    float* st = (float*)(x1 + (size_t)NN * 256); // 1024 floats
    int*  rs  = (int*)(st + 1024);               // 50004
    int*  deg = rs + 50004;                      // NN (cursor)
    int*  bsum = deg + NN;                       // 256
    int*  boff = bsum + 256;                     // 256
    int2* pe  = (int2*)(boff + 256);             // NE
    short* Bp0 = (short*)(pe + NE);              // 32768
    short* Bp1 = Bp0 + 32768;                    // 32768
    short* Bp2 = Bp1 + 32768;                    // 8192

    float* sum0 = st,       *ss0 = st + 128, *sc0 = st + 256, *sh0 = st + 384;
    float* sum1 = st + 512, *ss1 = st + 640, *sc1 = st + 768, *sh1 = st + 896;

    const int gE = (NE + 255) / 256;   // 3125
    const int gN = (NN + 255) / 256;   // 196

    // ---- CSR build ----
    hipMemsetAsync(deg, 0, (size_t)NN * 4, stream);
    hipMemsetAsync(st, 0, 1024 * 4, stream);
    hist_k<<<gE, 256, 0, stream>>>(dst, deg);
    scan1_k<<<gN, 256, 0, stream>>>(deg, rs, bsum);
    scan2_k<<<1, 256, 0, stream>>>(bsum, boff, gN);
    addoff_k<<<gN, 256, 0, stream>>>(rs, boff, deg);
    fill_k<<<gE, 256, 0, stream>>>(src, dst, ew, deg, pe);

    // ---- casts / weight packing ----
    cast_k<<<12500, 256, 0, stream>>>(x, (unsigned*)xb, NN * 64);
    packb_k<<<128, 256, 0, stream>>>(W0, Bp0, 8);
    packb_k<<<128, 256, 0, stream>>>(W1, Bp1, 8);
    packb_k<<<32, 256, 0, stream>>>(W2, Bp2, 2);

    // ---- layer 0 ----
    gemm_mfma<8><<<782, 256, 0, stream>>>(xb, Bp0, h, NN);
    agg128b<<<12500, 256, 0, stream>>>((const unsigned*)h, rs, pe, (unsigned*)x1 + 64);
    bn_stats_b<<<256, 256, 0, stream>>>((const unsigned*)x1 + 64, sum0, ss0, NN);
    bn_finalize<<<1, 128, 0, stream>>>(sum0, ss0, g0, b0, sc0, sh0, NN);
    bn_apply_b<<<12500, 256, 0, stream>>>((unsigned*)x1, sc0, sh0, NN);

    // ---- layer 1 ----
    gemm_mfma<8><<<782, 256, 0, stream>>>(x1, Bp1, h, NN);
    agg128b<<<12500, 256, 0, stream>>>((const unsigned*)h, rs, pe, (unsigned*)x1 + 64);
    bn_stats_b<<<256, 256, 0, stream>>>((const unsigned*)x1 + 64, sum1, ss1, NN);
    bn_finalize<<<1, 128, 0, stream>>>(sum1, ss1, g1, b1, sc1, sh1, NN);
    bn_apply_b<<<12500, 256, 0, stream>>>((unsigned*)x1, sc1, sh1, NN);

    // ---- output layer ----
    gemm_mfma<2><<<782, 256, 0, stream>>>(x1, Bp2, h, NN);
    agg32b<<<3125, 256, 0, stream>>>((const unsigned*)h, rs, pe, out);
}

// Round 4
// 394.148 us; speedup vs baseline: 8.4350x; 1.1025x over previous
//
#include <hip/hip_runtime.h>
#include <hip/hip_fp16.h>

#define NN 50000
#define NE 800000

typedef __attribute__((ext_vector_type(8))) short bf16x8;
typedef __attribute__((ext_vector_type(4))) float f32x4;

__device__ inline float blo(unsigned u) { union { unsigned i; float f; } c; c.i = u << 16; return c.f; }
__device__ inline float bhi(unsigned u) { union { unsigned i; float f; } c; c.i = u & 0xFFFF0000u; return c.f; }
__device__ inline unsigned short f2b(float f) {
    union { float f; unsigned u; } c; c.f = f;
    return (unsigned short)((c.u + 0x7FFFu + ((c.u >> 16) & 1u)) >> 16);
}
__device__ inline unsigned pack2(float x, float y) {
    union { float f; unsigned u; } a, b; a.f = x; b.f = y;
    const unsigned lo = (a.u + 0x7FFFu + ((a.u >> 16) & 1u)) >> 16;
    const unsigned hi = (b.u + 0x7FFFu + ((b.u >> 16) & 1u)) & 0xFFFF0000u;
    return (lo & 0xFFFFu) | hi;
}
__device__ inline float edgew(unsigned u) {
    return __half2float(__ushort_as_half((unsigned short)(u >> 16)));
}

// ================= CSR build =================
__global__ __launch_bounds__(256) void hist_k(const int* __restrict__ dst, int* __restrict__ deg)
{
    const int e = blockIdx.x * 256 + threadIdx.x;
    if (e < NE) atomicAdd(&deg[dst[e]], 1);
}

__global__ __launch_bounds__(256) void scan1_k(const int* __restrict__ deg, int* __restrict__ rs, int* __restrict__ bsum)
{
    __shared__ int tmp[256];
    const int i = blockIdx.x * 256 + threadIdx.x;
    const int v = (i < NN) ? deg[i] : 0;
    tmp[threadIdx.x] = v;
    __syncthreads();
    for (int off = 1; off < 256; off <<= 1) {
        const int t = (threadIdx.x >= off) ? tmp[threadIdx.x - off] : 0;
        __syncthreads();
        tmp[threadIdx.x] += t;
        __syncthreads();
    }
    if (i < NN) rs[i] = tmp[threadIdx.x] - v;
    if (threadIdx.x == 255) bsum[blockIdx.x] = tmp[255];
}

__global__ void scan2_k(const int* __restrict__ bsum, int* __restrict__ boff, int nb)
{
    __shared__ int tmp[256];
    const int v = (threadIdx.x < nb) ? bsum[threadIdx.x] : 0;
    tmp[threadIdx.x] = v;
    __syncthreads();
    for (int off = 1; off < 256; off <<= 1) {
        const int t = (threadIdx.x >= off) ? tmp[threadIdx.x - off] : 0;
        __syncthreads();
        tmp[threadIdx.x] += t;
        __syncthreads();
    }
    if (threadIdx.x < nb) boff[threadIdx.x] = tmp[threadIdx.x] - v;
}

__global__ __launch_bounds__(256) void addoff_k(int* __restrict__ rs, const int* __restrict__ boff, int* __restrict__ cursor)
{
    const int i = blockIdx.x * 256 + threadIdx.x;
    if (i < NN) {
        const int r = rs[i] + boff[blockIdx.x];
        rs[i] = r;
        cursor[i] = r;
    }
    if (i == 0) rs[NN] = NE;
}

// packed edge: low 16 = src, high 16 = f16(weight)
__global__ __launch_bounds__(256) void fill_k(
    const int* __restrict__ src, const int* __restrict__ dst, const float* __restrict__ ew,
    int* __restrict__ cursor, unsigned* __restrict__ pe)
{
    const int e = blockIdx.x * 256 + threadIdx.x;
    if (e >= NE) return;
    const int d = dst[e];
    const int pos = atomicAdd(&cursor[d], 1);
    const unsigned wb = (unsigned)__half_as_ushort(__float2half_rn(ew[e]));
    pe[pos] = ((unsigned)src[e] & 0xFFFFu) | (wb << 16);
}

// ================= weight packing =================
// Bp[((ks*NT+nt)*64+lane)*8+j] = bf16(B[(ks*32+(lane>>4)*8+j)][nt*16+(lane&15)])
__global__ __launch_bounds__(256) void packb_k(const float* __restrict__ B, short* __restrict__ Bp, int NT)
{
    const int o = blockIdx.x * 256 + threadIdx.x;
    if (o >= 4096 * NT) return;
    const int j = o & 7;
    const int lane = (o >> 3) & 63;
    const int tnt = o >> 9;
    const int nt = tnt % NT, ks = tnt / NT;
    const int k = ks * 32 + (lane >> 4) * 8 + j;
    const int n = nt * 16 + (lane & 15);
    Bp[o] = (short)f2b(B[k * (NT * 16) + n]);
}

// ================= MFMA GEMM: C[M, NT*16] = A[M, 256] @ B, bf16 out =================
template <int NT, bool A32>
__global__ __launch_bounds__(256) void gemm_mfma(
    const void* __restrict__ Av, const short* __restrict__ Bp,
    short* __restrict__ C, int M)
{
    __shared__ short Al[64 * 264];   // row stride 264 bf16 = 528 B
    const int tid = threadIdx.x;
    const int w = tid >> 6;
    const int lane = tid & 63;
    const int row0 = blockIdx.x * 64;

    if (A32) {
        const float* A = (const float*)Av;
#pragma unroll
        for (int i = 0; i < 16; ++i) {
            const int idx = tid + i * 256;      // 0..4095, 4-elem groups
            const int r = idx >> 6;
            const int c4 = idx & 63;
            float4 v = make_float4(0.f, 0.f, 0.f, 0.f);
            if (row0 + r < M) v = *(const float4*)&A[(long)(row0 + r) * 256 + c4 * 4];
            uint2 o; o.x = pack2(v.x, v.y); o.y = pack2(v.z, v.w);
            *(uint2*)&Al[r * 264 + c4 * 4] = o;
        }
    } else {
        const short* A = (const short*)Av;
#pragma unroll
        for (int i = 0; i < 8; ++i) {
            const int chunk = tid + i * 256;    // 0..2047, 8-elem groups
            const int r = chunk >> 5;
            const int c8 = chunk & 31;
            float4 v = make_float4(0.f, 0.f, 0.f, 0.f);
            if (row0 + r < M) v = *(const float4*)&A[(long)(row0 + r) * 256 + c8 * 8];
            *(float4*)&Al[r * 264 + c8 * 8] = v;
        }
    }
    __syncthreads();

    f32x4 acc[NT];
#pragma unroll
    for (int t = 0; t < NT; ++t) acc[t] = (f32x4){0.f, 0.f, 0.f, 0.f};

    const int quad = lane >> 4;
    const int abase = (w * 16 + (lane & 15)) * 264 + quad * 8;
#pragma unroll
    for (int ks = 0; ks < 8; ++ks) {
        const bf16x8 af = *(const bf16x8*)&Al[abase + ks * 32];
#pragma unroll
        for (int t = 0; t < NT; ++t) {
            const bf16x8 bf = *(const bf16x8*)&Bp[(((ks * NT + t) * 64) + lane) * 8];
            acc[t] = __builtin_amdgcn_mfma_f32_16x16x32_bf16(af, bf, acc[t], 0, 0, 0);
        }
    }

    __syncthreads();   // done reading A tile; reuse LDS for epilogue
    const int NC = NT * 16;
    float* Cl = (float*)Al + w * (16 * NC);
#pragma unroll
    for (int t = 0; t < NT; ++t)
#pragma unroll
        for (int r = 0; r < 4; ++r)
            Cl[(quad * 4 + r) * NC + t * 16 + (lane & 15)] = acc[t][r];
#pragma unroll
    for (int i = 0; i < NC / 32; ++i) {
        const int f = i * 512 + lane * 8;
        const int r = f / NC;
        const int col = f % NC;
        const int grow = row0 + w * 16 + r;
        const float4 lo = *(float4*)&Cl[f];
        const float4 hi = *(float4*)&Cl[f + 4];
        uint4 o;
        o.x = pack2(lo.x, lo.y);
        o.y = pack2(lo.z, lo.w);
        o.z = pack2(hi.x, hi.y);
        o.w = pack2(hi.z, hi.w);
        if (grow < M) *(uint4*)&C[(long)grow * NC + col] = o;
    }
}

// ================= gather aggregation (bf16 h, packed edges) =================
// one wave per node, 2 channels per lane; out row stride 128 uints (256 bf16)
__global__ __launch_bounds__(256) void agg128b(
    const unsigned* __restrict__ h2, const int* __restrict__ rs,
    const unsigned* __restrict__ pe, unsigned* __restrict__ outp)
{
    const int node = blockIdx.x * 4 + (threadIdx.x >> 6);
    const int l = threadIdx.x & 63;
    int j = rs[node];
    const int j1 = rs[node + 1];
    float x0 = 0.f, y0 = 0.f, x1 = 0.f, y1 = 0.f;
    float x2 = 0.f, y2 = 0.f, x3 = 0.f, y3 = 0.f;
    for (; j + 3 < j1; j += 4) {
        const unsigned u0 = pe[j], u1 = pe[j + 1], u2 = pe[j + 2], u3 = pe[j + 3];
        const unsigned v0 = h2[(long)(u0 & 0xFFFFu) * 64 + l];
        const unsigned v1 = h2[(long)(u1 & 0xFFFFu) * 64 + l];
        const unsigned v2 = h2[(long)(u2 & 0xFFFFu) * 64 + l];
        const unsigned v3 = h2[(long)(u3 & 0xFFFFu) * 64 + l];
        const float w0 = edgew(u0), w1 = edgew(u1), w2 = edgew(u2), w3 = edgew(u3);
        x0 = fmaf(w0, blo(v0), x0); y0 = fmaf(w0, bhi(v0), y0);
        x1 = fmaf(w1, blo(v1), x1); y1 = fmaf(w1, bhi(v1), y1);
        x2 = fmaf(w2, blo(v2), x2); y2 = fmaf(w2, bhi(v2), y2);
        x3 = fmaf(w3, blo(v3), x3); y3 = fmaf(w3, bhi(v3), y3);
    }
    for (; j < j1; ++j) {
        const unsigned u = pe[j];
        const unsigned v = h2[(long)(u & 0xFFFFu) * 64 + l];
        const float w0 = edgew(u);
        x0 = fmaf(w0, blo(v), x0); y0 = fmaf(w0, bhi(v), y0);
    }
    outp[(long)node * 128 + l] = pack2((x0 + x1) + (x2 + x3), (y0 + y1) + (y2 + y3));
}

// h rows of 32 bf16 (16 uints); 16 lanes/node; fp32 output [NN,32]
__global__ __launch_bounds__(256) void agg32b(
    const unsigned* __restrict__ h2, const int* __restrict__ rs,
    const unsigned* __restrict__ pe, float* __restrict__ out)
{
    const int node = blockIdx.x * 16 + (threadIdx.x >> 4);
    const int l = threadIdx.x & 15;
    int j = rs[node];
    const int j1 = rs[node + 1];
    float x0 = 0.f, y0 = 0.f, x1 = 0.f, y1 = 0.f;
    float x2 = 0.f, y2 = 0.f, x3 = 0.f, y3 = 0.f;
    for (; j + 3 < j1; j += 4) {
        const unsigned u0 = pe[j], u1 = pe[j + 1], u2 = pe[j + 2], u3 = pe[j + 3];
        const unsigned v0 = h2[(long)(u0 & 0xFFFFu) * 16 + l];
        const unsigned v1 = h2[(long)(u1 & 0xFFFFu) * 16 + l];
        const unsigned v2 = h2[(long)(u2 & 0xFFFFu) * 16 + l];
        const unsigned v3 = h2[(long)(u3 & 0xFFFFu) * 16 + l];
        const float w0 = edgew(u0), w1 = edgew(u1), w2 = edgew(u2), w3 = edgew(u3);
        x0 = fmaf(w0, blo(v0), x0); y0 = fmaf(w0, bhi(v0), y0);
        x1 = fmaf(w1, blo(v1), x1); y1 = fmaf(w1, bhi(v1), y1);
        x2 = fmaf(w2, blo(v2), x2); y2 = fmaf(w2, bhi(v2), y2);
        x3 = fmaf(w3, blo(v3), x3); y3 = fmaf(w3, bhi(v3), y3);
    }
    for (; j < j1; ++j) {
        const unsigned u = pe[j];
        const unsigned v = h2[(long)(u & 0xFFFFu) * 16 + l];
        const float w0 = edgew(u);
        x0 = fmaf(w0, blo(v), x0); y0 = fmaf(w0, bhi(v), y0);
    }
    float2 o;
    o.x = (x0 + x1) + (x2 + x3);
    o.y = (y0 + y1) + (y2 + y3);
    *(float2*)&out[(long)node * 32 + 2 * l] = o;
}

// ================= BN (bf16 data, fp32 stats) =================
__global__ __launch_bounds__(256) void bn_stats_b(
    const unsigned* __restrict__ pre, float* __restrict__ sum, float* __restrict__ ss, int M)
{
    const int c2 = threadIdx.x & 63;
    const int g = threadIdx.x >> 6;
    float s0 = 0.f, s1 = 0.f, q0 = 0.f, q1 = 0.f;
    for (int row = blockIdx.x * 4 + g; row < M; row += gridDim.x * 4) {
        const unsigned v = pre[(long)row * 128 + c2];
        const float lo = blo(v), hi = bhi(v);
        s0 += lo; s1 += hi;
        q0 = fmaf(lo, lo, q0); q1 = fmaf(hi, hi, q1);
    }
    __shared__ float A0[256], A1[256], B0[256], B1[256];
    A0[threadIdx.x] = s0; A1[threadIdx.x] = s1;
    B0[threadIdx.x] = q0; B1[threadIdx.x] = q1;
    __syncthreads();
    if (threadIdx.x < 64) {
        const int t = threadIdx.x;
        atomicAdd(&sum[2 * t],     A0[t] + A0[t + 64] + A0[t + 128] + A0[t + 192]);
        atomicAdd(&sum[2 * t + 1], A1[t] + A1[t + 64] + A1[t + 128] + A1[t + 192]);
        atomicAdd(&ss[2 * t],      B0[t] + B0[t + 64] + B0[t + 128] + B0[t + 192]);
        atomicAdd(&ss[2 * t + 1],  B1[t] + B1[t + 64] + B1[t + 128] + B1[t + 192]);
    }
}

// fused finalize+apply: reads pre (uints 64..127 of row), writes relu(bn) bf16 to uints 0..63
__global__ __launch_bounds__(256) void bn_apply_b(
    unsigned* __restrict__ x1, const float* __restrict__ sum, const float* __restrict__ ss,
    const float* __restrict__ gamma, const float* __restrict__ beta, int M)
{
    __shared__ float sc[128], sh[128];
    if (threadIdx.x < 128) {
        const int c = threadIdx.x;
        const float inv = 1.f / (float)M;
        const float mu = sum[c] * inv;
        const float var = ss[c] * inv - mu * mu;
        const float s = gamma[c] * rsqrtf(var + 1e-5f);
        sc[c] = s;
        sh[c] = beta[c] - mu * s;
    }
    __syncthreads();
    const int idx = blockIdx.x * 256 + threadIdx.x;
    const int row = idx >> 6;
    if (row >= M) return;
    const int c2 = idx & 63;
    const unsigned v = x1[(long)row * 128 + 64 + c2];
    const float lo = fmaxf(fmaf(blo(v), sc[2 * c2],     sh[2 * c2]),     0.f);
    const float hi = fmaxf(fmaf(bhi(v), sc[2 * c2 + 1], sh[2 * c2 + 1]), 0.f);
    x1[(long)row * 128 + c2] = pack2(lo, hi);
}

extern "C" void kernel_launch(void* const* d_in, const int* in_sizes, int n_in,
                              void* d_out, int out_size, void* d_ws, size_t ws_size,
                              hipStream_t stream) {
    const float* x   = (const float*)d_in[0];
    const int*   src = (const int*)d_in[1];
    const int*   dst = (const int*)d_in[2];
    const float* ew  = (const float*)d_in[3];
    const float* W0  = (const float*)d_in[4];
    const float* W1  = (const float*)d_in[5];
    const float* W2  = (const float*)d_in[6];
    const float* g0  = (const float*)d_in[7];
    const float* b0  = (const float*)d_in[8];
    const float* g1  = (const float*)d_in[9];
    const float* b1  = (const float*)d_in[10];
    float* out = (float*)d_out;

    // workspace layout
    short* h  = (short*)d_ws;                    // [NN*128] bf16 (also [NN*32] for out layer)
    short* x1 = h + (size_t)NN * 128;            // [NN*256] bf16 concat buffer
    float* st = (float*)(x1 + (size_t)NN * 256); // 1024 floats
    int*  rs  = (int*)(st + 1024);               // 50004
    int*  deg = rs + 50004;                      // NN (cursor)
    int*  bsum = deg + NN;                       // 256
    int*  boff = bsum + 256;                     // 256
    unsigned* pe = (unsigned*)(boff + 256);      // NE packed edges
    short* Bp0 = (short*)(pe + NE);              // 32768
    short* Bp1 = Bp0 + 32768;                    // 32768
    short* Bp2 = Bp1 + 32768;                    // 8192

    float* sum0 = st,       *ss0 = st + 128;
    float* sum1 = st + 512, *ss1 = st + 640;

    const int gE = (NE + 255) / 256;   // 3125
    const int gN = (NN + 255) / 256;   // 196

    // ---- CSR build ----
    hipMemsetAsync(deg, 0, (size_t)NN * 4, stream);
    hipMemsetAsync(st, 0, 1024 * 4, stream);
    hist_k<<<gE, 256, 0, stream>>>(dst, deg);
    scan1_k<<<gN, 256, 0, stream>>>(deg, rs, bsum);
    scan2_k<<<1, 256, 0, stream>>>(bsum, boff, gN);
    addoff_k<<<gN, 256, 0, stream>>>(rs, boff, deg);
    fill_k<<<gE, 256, 0, stream>>>(src, dst, ew, deg, pe);

    // ---- weight packing ----
    packb_k<<<128, 256, 0, stream>>>(W0, Bp0, 8);
    packb_k<<<128, 256, 0, stream>>>(W1, Bp1, 8);
    packb_k<<<32, 256, 0, stream>>>(W2, Bp2, 2);

    // ---- layer 0 (A is fp32 x, cast fused into staging) ----
    gemm_mfma<8, true><<<782, 256, 0, stream>>>(x, Bp0, h, NN);
    agg128b<<<12500, 256, 0, stream>>>((const unsigned*)h, rs, pe, (unsigned*)x1 + 64);
    bn_stats_b<<<256, 256, 0, stream>>>((const unsigned*)x1 + 64, sum0, ss0, NN);
    bn_apply_b<<<12500, 256, 0, stream>>>((unsigned*)x1, sum0, ss0, g0, b0, NN);

    // ---- layer 1 ----
    gemm_mfma<8, false><<<782, 256, 0, stream>>>(x1, Bp1, h, NN);
    agg128b<<<12500, 256, 0, stream>>>((const unsigned*)h, rs, pe, (unsigned*)x1 + 64);
    bn_stats_b<<<256, 256, 0, stream>>>((const unsigned*)x1 + 64, sum1, ss1, NN);
    bn_apply_b<<<12500, 256, 0, stream>>>((unsigned*)x1, sum1, ss1, g1, b1, NN);

    // ---- output layer ----
    gemm_mfma<2, false><<<782, 256, 0, stream>>>(x1, Bp2, h, NN);
    agg32b<<<3125, 256, 0, stream>>>((const unsigned*)h, rs, pe, out);
}

// Round 5
// 343.305 us; speedup vs baseline: 9.6842x; 1.1481x over previous
//
#include <hip/hip_runtime.h>
#include <hip/hip_fp16.h>

#define NN 50000
#define NE 800000
#define GB0 782   // gemm blocks in fused gemm0+hist

typedef __attribute__((ext_vector_type(8))) short bf16x8;
typedef __attribute__((ext_vector_type(4))) float f32x4;

__device__ inline float blo(unsigned u) { union { unsigned i; float f; } c; c.i = u << 16; return c.f; }
__device__ inline float bhi(unsigned u) { union { unsigned i; float f; } c; c.i = u & 0xFFFF0000u; return c.f; }
__device__ inline unsigned short f2b(float f) {
    union { float f; unsigned u; } c; c.f = f;
    return (unsigned short)((c.u + 0x7FFFu + ((c.u >> 16) & 1u)) >> 16);
}
__device__ inline unsigned pack2(float x, float y) {
    union { float f; unsigned u; } a, b; a.f = x; b.f = y;
    const unsigned lo = (a.u + 0x7FFFu + ((a.u >> 16) & 1u)) >> 16;
    const unsigned hi = (b.u + 0x7FFFu + ((b.u >> 16) & 1u)) & 0xFFFF0000u;
    return (lo & 0xFFFFu) | hi;
}
__device__ inline float edgew(unsigned u) {
    return __half2float(__ushort_as_half((unsigned short)(u >> 16)));
}

// ================= CSR build =================
__global__ __launch_bounds__(256) void scan1_k(const int* __restrict__ deg, int* __restrict__ rs, int* __restrict__ bsum)
{
    __shared__ int tmp[256];
    const int i = blockIdx.x * 256 + threadIdx.x;
    const int v = (i < NN) ? deg[i] : 0;
    tmp[threadIdx.x] = v;
    __syncthreads();
    for (int off = 1; off < 256; off <<= 1) {
        const int t = (threadIdx.x >= off) ? tmp[threadIdx.x - off] : 0;
        __syncthreads();
        tmp[threadIdx.x] += t;
        __syncthreads();
    }
    if (i < NN) rs[i] = tmp[threadIdx.x] - v;
    if (threadIdx.x == 255) bsum[blockIdx.x] = tmp[255];
}

__global__ void scan2_k(const int* __restrict__ bsum, int* __restrict__ boff, int nb)
{
    __shared__ int tmp[256];
    const int v = (threadIdx.x < nb) ? bsum[threadIdx.x] : 0;
    tmp[threadIdx.x] = v;
    __syncthreads();
    for (int off = 1; off < 256; off <<= 1) {
        const int t = (threadIdx.x >= off) ? tmp[threadIdx.x - off] : 0;
        __syncthreads();
        tmp[threadIdx.x] += t;
        __syncthreads();
    }
    if (threadIdx.x < nb) boff[threadIdx.x] = tmp[threadIdx.x] - v;
}

__global__ __launch_bounds__(256) void addoff_k(int* __restrict__ rs, const int* __restrict__ boff, int* __restrict__ cursor)
{
    const int i = blockIdx.x * 256 + threadIdx.x;
    if (i < NN) {
        const int r = rs[i] + boff[blockIdx.x];
        rs[i] = r;
        cursor[i] = r;
    }
    if (i == 0) rs[NN] = NE;
}

// XCD-partitioned CSR fill: block handles chunk blockIdx/8, octant blockIdx%8.
// All writes to a given pe/cursor line come from one XCD -> L2 write merging.
__global__ __launch_bounds__(256) void fill_oct(
    const int* __restrict__ src, const int* __restrict__ dst, const float* __restrict__ ew,
    int* __restrict__ cursor, unsigned* __restrict__ pe)
{
    const unsigned oct = blockIdx.x & 7;
    const int base = (blockIdx.x >> 3) * 2048;
#pragma unroll
    for (int i = 0; i < 8; ++i) {
        const int e = base + i * 256 + threadIdx.x;
        if (e < NE) {
            const int d = dst[e];
            if ((unsigned)d / 6250u == oct) {
                const int pos = atomicAdd(&cursor[d], 1);
                const unsigned wb = (unsigned)__half_as_ushort(__float2half_rn(ew[e]));
                pe[pos] = ((unsigned)src[e] & 0xFFFFu) | (wb << 16);
            }
        }
    }
}

// ================= weight packing (all three, one launch) =================
__device__ __forceinline__ void packb_body(const float* __restrict__ B, short* __restrict__ Bp, int NT, int b)
{
    const int o = b * 256 + threadIdx.x;
    if (o >= 4096 * NT) return;
    const int j = o & 7;
    const int lane = (o >> 3) & 63;
    const int tnt = o >> 9;
    const int nt = tnt % NT, ks = tnt / NT;
    const int k = ks * 32 + (lane >> 4) * 8 + j;
    const int n = nt * 16 + (lane & 15);
    Bp[o] = (short)f2b(B[k * (NT * 16) + n]);
}

__global__ __launch_bounds__(256) void packb_all(
    const float* __restrict__ W0, const float* __restrict__ W1, const float* __restrict__ W2,
    short* __restrict__ Bp0, short* __restrict__ Bp1, short* __restrict__ Bp2)
{
    const int b = blockIdx.x;
    if (b < 128)      packb_body(W0, Bp0, 8, b);
    else if (b < 256) packb_body(W1, Bp1, 8, b - 128);
    else              packb_body(W2, Bp2, 2, b - 256);
}

// ================= MFMA GEMM body =================
// MODE 0: A = fp32 [M,256] (layer 0, cast fused)
// MODE 1: A = x1p pre-only [M,64] uints; act half = relu(bn(pre)) computed in staging
template <int NT, int MODE>
__device__ __forceinline__ void gemm_body(
    const void* __restrict__ Av, const short* __restrict__ Bp,
    short* __restrict__ C, int M,
    const float* __restrict__ sum, const float* __restrict__ ss,
    const float* __restrict__ gam, const float* __restrict__ bet)
{
    __shared__ short Al[64 * 264];   // row stride 264 bf16 = 528 B
    __shared__ float scs[128], shs[128];
    const int tid = threadIdx.x;
    const int w = tid >> 6;
    const int lane = tid & 63;
    const int row0 = blockIdx.x * 64;

    if (MODE == 1) {
        if (tid < 128) {
            const float inv = 1.f / (float)M;
            const float mu = sum[tid] * inv;
            const float var = ss[tid] * inv - mu * mu;
            const float s = gam[tid] * rsqrtf(var + 1e-5f);
            scs[tid] = s;
            shs[tid] = bet[tid] - mu * s;
        }
        __syncthreads();
        const unsigned* A = (const unsigned*)Av;
#pragma unroll
        for (int i = 0; i < 16; ++i) {
            const int idx = tid + i * 256;      // 0..4095
            const int r = idx >> 6;
            const int c = idx & 63;
            unsigned v = 0;
            if (row0 + r < M) v = A[(long)(row0 + r) * 64 + c];
            const float a0 = fmaxf(fmaf(blo(v), scs[2 * c],     shs[2 * c]),     0.f);
            const float a1 = fmaxf(fmaf(bhi(v), scs[2 * c + 1], shs[2 * c + 1]), 0.f);
            unsigned* rowp = (unsigned*)&Al[r * 264];
            rowp[c] = pack2(a0, a1);            // act half (cols 0..127)
            rowp[64 + c] = v;                   // pre half (cols 128..255)
        }
    } else {
        const float* A = (const float*)Av;
#pragma unroll
        for (int i = 0; i < 16; ++i) {
            const int idx = tid + i * 256;
            const int r = idx >> 6;
            const int c4 = idx & 63;
            float4 v = make_float4(0.f, 0.f, 0.f, 0.f);
            if (row0 + r < M) v = *(const float4*)&A[(long)(row0 + r) * 256 + c4 * 4];
            uint2 o; o.x = pack2(v.x, v.y); o.y = pack2(v.z, v.w);
            *(uint2*)&Al[r * 264 + c4 * 4] = o;
        }
    }
    __syncthreads();

    f32x4 acc[NT];
#pragma unroll
    for (int t = 0; t < NT; ++t) acc[t] = (f32x4){0.f, 0.f, 0.f, 0.f};

    const int quad = lane >> 4;
    const int abase = (w * 16 + (lane & 15)) * 264 + quad * 8;
#pragma unroll
    for (int ks = 0; ks < 8; ++ks) {
        const bf16x8 af = *(const bf16x8*)&Al[abase + ks * 32];
#pragma unroll
        for (int t = 0; t < NT; ++t) {
            const bf16x8 bf = *(const bf16x8*)&Bp[(((ks * NT + t) * 64) + lane) * 8];
            acc[t] = __builtin_amdgcn_mfma_f32_16x16x32_bf16(af, bf, acc[t], 0, 0, 0);
        }
    }

    __syncthreads();   // done reading A tile; reuse LDS for epilogue
    const int NC = NT * 16;
    float* Cl = (float*)Al + w * (16 * NC);
#pragma unroll
    for (int t = 0; t < NT; ++t)
#pragma unroll
        for (int r = 0; r < 4; ++r)
            Cl[(quad * 4 + r) * NC + t * 16 + (lane & 15)] = acc[t][r];
#pragma unroll
    for (int i = 0; i < NC / 32; ++i) {
        const int f = i * 512 + lane * 8;
        const int r = f / NC;
        const int col = f % NC;
        const int grow = row0 + w * 16 + r;
        const float4 lo = *(float4*)&Cl[f];
        const float4 hi = *(float4*)&Cl[f + 4];
        uint4 o;
        o.x = pack2(lo.x, lo.y);
        o.y = pack2(lo.z, lo.w);
        o.z = pack2(hi.x, hi.y);
        o.w = pack2(hi.z, hi.w);
        if (grow < M) *(uint4*)&C[(long)grow * NC + col] = o;
    }
}

// fused: layer-0 GEMM (blocks 0..781) + dst histogram (blocks 782..)
__global__ __launch_bounds__(256) void gemm0_hist(
    const float* __restrict__ x, const short* __restrict__ Bp, short* __restrict__ C, int M,
    const int* __restrict__ dst, int* __restrict__ deg)
{
    if (blockIdx.x < GB0) {
        gemm_body<8, 0>(x, Bp, C, M, nullptr, nullptr, nullptr, nullptr);
    } else {
        const int e = (blockIdx.x - GB0) * 256 + threadIdx.x;
        if (e < NE) atomicAdd(&deg[dst[e]], 1);
    }
}

template <int NT>
__global__ __launch_bounds__(256) void gemm_bn(
    const unsigned* __restrict__ A, const short* __restrict__ Bp, short* __restrict__ C, int M,
    const float* __restrict__ sum, const float* __restrict__ ss,
    const float* __restrict__ gam, const float* __restrict__ bet)
{
    gemm_body<NT, 1>(A, Bp, C, M, sum, ss, gam, bet);
}

// ================= gather aggregation (bf16 h, packed edges) =================
// one wave per node; h rows 64 uints; out = pre-only x1p rows 64 uints
__global__ __launch_bounds__(256) void agg128b(
    const unsigned* __restrict__ h2, const int* __restrict__ rs,
    const unsigned* __restrict__ pe, unsigned* __restrict__ outp)
{
    const int node = blockIdx.x * 4 + (threadIdx.x >> 6);
    const int l = threadIdx.x & 63;
    int j = rs[node];
    const int j1 = rs[node + 1];
    float xs[8], ys[8];
#pragma unroll
    for (int t = 0; t < 8; ++t) { xs[t] = 0.f; ys[t] = 0.f; }
    for (; j + 7 < j1; j += 8) {
        unsigned u[8], v[8];
#pragma unroll
        for (int t = 0; t < 8; ++t) u[t] = pe[j + t];
#pragma unroll
        for (int t = 0; t < 8; ++t) v[t] = h2[(long)(u[t] & 0xFFFFu) * 64 + l];
#pragma unroll
        for (int t = 0; t < 8; ++t) {
            const float w = edgew(u[t]);
            xs[t] = fmaf(w, blo(v[t]), xs[t]);
            ys[t] = fmaf(w, bhi(v[t]), ys[t]);
        }
    }
    if (j + 3 < j1) {
        unsigned u[4], v[4];
#pragma unroll
        for (int t = 0; t < 4; ++t) u[t] = pe[j + t];
#pragma unroll
        for (int t = 0; t < 4; ++t) v[t] = h2[(long)(u[t] & 0xFFFFu) * 64 + l];
#pragma unroll
        for (int t = 0; t < 4; ++t) {
            const float w = edgew(u[t]);
            xs[t] = fmaf(w, blo(v[t]), xs[t]);
            ys[t] = fmaf(w, bhi(v[t]), ys[t]);
        }
        j += 4;
    }
    for (; j < j1; ++j) {
        const unsigned u = pe[j];
        const unsigned v = h2[(long)(u & 0xFFFFu) * 64 + l];
        const float w = edgew(u);
        xs[0] = fmaf(w, blo(v), xs[0]);
        ys[0] = fmaf(w, bhi(v), ys[0]);
    }
    const float X = ((xs[0] + xs[1]) + (xs[2] + xs[3])) + ((xs[4] + xs[5]) + (xs[6] + xs[7]));
    const float Y = ((ys[0] + ys[1]) + (ys[2] + ys[3])) + ((ys[4] + ys[5]) + (ys[6] + ys[7]));
    outp[(long)node * 64 + l] = pack2(X, Y);
}

// h rows of 32 bf16 (16 uints); 16 lanes/node; fp32 output [NN,32]
__global__ __launch_bounds__(256) void agg32b(
    const unsigned* __restrict__ h2, const int* __restrict__ rs,
    const unsigned* __restrict__ pe, float* __restrict__ out)
{
    const int node = blockIdx.x * 16 + (threadIdx.x >> 4);
    const int l = threadIdx.x & 15;
    int j = rs[node];
    const int j1 = rs[node + 1];
    float xs[8], ys[8];
#pragma unroll
    for (int t = 0; t < 8; ++t) { xs[t] = 0.f; ys[t] = 0.f; }
    for (; j + 7 < j1; j += 8) {
        unsigned u[8], v[8];
#pragma unroll
        for (int t = 0; t < 8; ++t) u[t] = pe[j + t];
#pragma unroll
        for (int t = 0; t < 8; ++t) v[t] = h2[(long)(u[t] & 0xFFFFu) * 16 + l];
#pragma unroll
        for (int t = 0; t < 8; ++t) {
            const float w = edgew(u[t]);
            xs[t] = fmaf(w, blo(v[t]), xs[t]);
            ys[t] = fmaf(w, bhi(v[t]), ys[t]);
        }
    }
    if (j + 3 < j1) {
        unsigned u[4], v[4];
#pragma unroll
        for (int t = 0; t < 4; ++t) u[t] = pe[j + t];
#pragma unroll
        for (int t = 0; t < 4; ++t) v[t] = h2[(long)(u[t] & 0xFFFFu) * 16 + l];
#pragma unroll
        for (int t = 0; t < 4; ++t) {
            const float w = edgew(u[t]);
            xs[t] = fmaf(w, blo(v[t]), xs[t]);
            ys[t] = fmaf(w, bhi(v[t]), ys[t]);
        }
        j += 4;
    }
    for (; j < j1; ++j) {
        const unsigned u = pe[j];
        const unsigned v = h2[(long)(u & 0xFFFFu) * 16 + l];
        const float w = edgew(u);
        xs[0] = fmaf(w, blo(v), xs[0]);
        ys[0] = fmaf(w, bhi(v), ys[0]);
    }
    float2 o;
    o.x = ((xs[0] + xs[1]) + (xs[2] + xs[3])) + ((xs[4] + xs[5]) + (xs[6] + xs[7]));
    o.y = ((ys[0] + ys[1]) + (ys[2] + ys[3])) + ((ys[4] + ys[5]) + (ys[6] + ys[7]));
    *(float2*)&out[(long)node * 32 + 2 * l] = o;
}

// ================= BN stats (pre rows = 64 uints) =================
__global__ __launch_bounds__(256) void bn_stats_b(
    const unsigned* __restrict__ pre, float* __restrict__ sum, float* __restrict__ ss, int M)
{
    const int c2 = threadIdx.x & 63;
    const int g = threadIdx.x >> 6;
    float s0 = 0.f, s1 = 0.f, q0 = 0.f, q1 = 0.f;
    for (int row = blockIdx.x * 4 + g; row < M; row += gridDim.x * 4) {
        const unsigned v = pre[(long)row * 64 + c2];
        const float lo = blo(v), hi = bhi(v);
        s0 += lo; s1 += hi;
        q0 = fmaf(lo, lo, q0); q1 = fmaf(hi, hi, q1);
    }
    __shared__ float A0[256], A1[256], B0[256], B1[256];
    A0[threadIdx.x] = s0; A1[threadIdx.x] = s1;
    B0[threadIdx.x] = q0; B1[threadIdx.x] = q1;
    __syncthreads();
    if (threadIdx.x < 64) {
        const int t = threadIdx.x;
        atomicAdd(&sum[2 * t],     A0[t] + A0[t + 64] + A0[t + 128] + A0[t + 192]);
        atomicAdd(&sum[2 * t + 1], A1[t] + A1[t + 64] + A1[t + 128] + A1[t + 192]);
        atomicAdd(&ss[2 * t],      B0[t] + B0[t + 64] + B0[t + 128] + B0[t + 192]);
        atomicAdd(&ss[2 * t + 1],  B1[t] + B1[t + 64] + B1[t + 128] + B1[t + 192]);
    }
}

extern "C" void kernel_launch(void* const* d_in, const int* in_sizes, int n_in,
                              void* d_out, int out_size, void* d_ws, size_t ws_size,
                              hipStream_t stream) {
    const float* x   = (const float*)d_in[0];
    const int*   src = (const int*)d_in[1];
    const int*   dst = (const int*)d_in[2];
    const float* ew  = (const float*)d_in[3];
    const float* W0  = (const float*)d_in[4];
    const float* W1  = (const float*)d_in[5];
    const float* W2  = (const float*)d_in[6];
    const float* g0  = (const float*)d_in[7];
    const float* b0  = (const float*)d_in[8];
    const float* g1  = (const float*)d_in[9];
    const float* b1  = (const float*)d_in[10];
    float* out = (float*)d_out;

    // workspace layout
    short* h   = (short*)d_ws;                    // [NN*128] bf16 (also [NN*32] for out layer)
    unsigned* x1p = (unsigned*)(h + (size_t)NN * 128); // [NN*64] uints = pre-only bf16x2
    float* st  = (float*)(x1p + (size_t)NN * 64); // 1024 floats
    int*  rs   = (int*)(st + 1024);               // 50004
    int*  deg  = rs + 50004;                      // NN (cursor)
    int*  bsum = deg + NN;                        // 256
    int*  boff = bsum + 256;                      // 256
    unsigned* pe = (unsigned*)(boff + 256);       // NE packed edges
    short* Bp0 = (short*)(pe + NE);               // 32768
    short* Bp1 = Bp0 + 32768;                     // 32768
    short* Bp2 = Bp1 + 32768;                     // 8192

    float* sum0 = st,       *ss0 = st + 128;
    float* sum1 = st + 512, *ss1 = st + 640;

    const int gN = (NN + 255) / 256;   // 196
    const int gE = (NE + 255) / 256;   // 3125

    hipMemsetAsync(deg, 0, (size_t)NN * 4, stream);
    hipMemsetAsync(st, 0, 1024 * 4, stream);

    // weights packed first (gemm0 needs Bp0)
    packb_all<<<288, 256, 0, stream>>>(W0, W1, W2, Bp0, Bp1, Bp2);

    // layer-0 GEMM fused with dst histogram (independent work, overlapped)
    gemm0_hist<<<GB0 + gE, 256, 0, stream>>>(x, Bp0, h, NN, dst, deg);

    scan1_k<<<gN, 256, 0, stream>>>(deg, rs, bsum);
    scan2_k<<<1, 256, 0, stream>>>(bsum, boff, gN);
    addoff_k<<<gN, 256, 0, stream>>>(rs, boff, deg);
    fill_oct<<<((NE + 2047) / 2048) * 8, 256, 0, stream>>>(src, dst, ew, deg, pe);

    // ---- layer 0 aggregation + stats ----
    agg128b<<<12500, 256, 0, stream>>>((const unsigned*)h, rs, pe, x1p);
    bn_stats_b<<<256, 256, 0, stream>>>(x1p, sum0, ss0, NN);

    // ---- layer 1 (BN0+ReLU fused into staging) ----
    gemm_bn<8><<<782, 256, 0, stream>>>(x1p, Bp1, h, NN, sum0, ss0, g0, b0);
    agg128b<<<12500, 256, 0, stream>>>((const unsigned*)h, rs, pe, x1p);
    bn_stats_b<<<256, 256, 0, stream>>>(x1p, sum1, ss1, NN);

    // ---- output layer (BN1+ReLU fused into staging) ----
    gemm_bn<2><<<782, 256, 0, stream>>>(x1p, Bp2, h, NN, sum1, ss1, g1, b1);
    agg32b<<<3125, 256, 0, stream>>>((const unsigned*)h, rs, pe, out);
}

// Round 6
// 335.040 us; speedup vs baseline: 9.9231x; 1.0247x over previous
//
#include <hip/hip_runtime.h>
#include <hip/hip_fp16.h>

#define NN 50000
#define NE 800000
#define GB0 782   // gemm blocks in fused gemm0+hist

typedef __attribute__((ext_vector_type(8))) short bf16x8;
typedef __attribute__((ext_vector_type(4))) float f32x4;

__device__ inline float blo(unsigned u) { union { unsigned i; float f; } c; c.i = u << 16; return c.f; }
__device__ inline float bhi(unsigned u) { union { unsigned i; float f; } c; c.i = u & 0xFFFF0000u; return c.f; }
__device__ inline unsigned short f2b(float f) {
    union { float f; unsigned u; } c; c.f = f;
    return (unsigned short)((c.u + 0x7FFFu + ((c.u >> 16) & 1u)) >> 16);
}
__device__ inline unsigned pack2(float x, float y) {
    union { float f; unsigned u; } a, b; a.f = x; b.f = y;
    const unsigned lo = (a.u + 0x7FFFu + ((a.u >> 16) & 1u)) >> 16;
    const unsigned hi = (b.u + 0x7FFFu + ((b.u >> 16) & 1u)) & 0xFFFF0000u;
    return (lo & 0xFFFFu) | hi;
}
__device__ inline float edgew(unsigned u) {
    return __half2float(__ushort_as_half((unsigned short)(u >> 16)));
}
__device__ inline bf16x8 u4_to_b8(unsigned a, unsigned b, unsigned c, unsigned d) {
    union { unsigned u[4]; bf16x8 v; } x;
    x.u[0] = a; x.u[1] = b; x.u[2] = c; x.u[3] = d;
    return x.v;
}

// ================= CSR build =================
__global__ __launch_bounds__(256) void scan1_k(const int* __restrict__ deg, int* __restrict__ rs, int* __restrict__ bsum)
{
    __shared__ int tmp[256];
    const int i = blockIdx.x * 256 + threadIdx.x;
    const int v = (i < NN) ? deg[i] : 0;
    tmp[threadIdx.x] = v;
    __syncthreads();
    for (int off = 1; off < 256; off <<= 1) {
        const int t = (threadIdx.x >= off) ? tmp[threadIdx.x - off] : 0;
        __syncthreads();
        tmp[threadIdx.x] += t;
        __syncthreads();
    }
    if (i < NN) rs[i] = tmp[threadIdx.x] - v;
    if (threadIdx.x == 255) bsum[blockIdx.x] = tmp[255];
}

__global__ void scan2_k(const int* __restrict__ bsum, int* __restrict__ boff, int nb)
{
    __shared__ int tmp[256];
    const int v = (threadIdx.x < nb) ? bsum[threadIdx.x] : 0;
    tmp[threadIdx.x] = v;
    __syncthreads();
    for (int off = 1; off < 256; off <<= 1) {
        const int t = (threadIdx.x >= off) ? tmp[threadIdx.x - off] : 0;
        __syncthreads();
        tmp[threadIdx.x] += t;
        __syncthreads();
    }
    if (threadIdx.x < nb) boff[threadIdx.x] = tmp[threadIdx.x] - v;
}

__global__ __launch_bounds__(256) void addoff_k(int* __restrict__ rs, const int* __restrict__ boff, int* __restrict__ cursor)
{
    const int i = blockIdx.x * 256 + threadIdx.x;
    if (i < NN) {
        const int r = rs[i] + boff[blockIdx.x];
        rs[i] = r;
        cursor[i] = r;
    }
    if (i == 0) rs[NN] = NE;
}

// XCD-partitioned CSR fill: block handles chunk blockIdx/8, octant blockIdx%8.
__global__ __launch_bounds__(256) void fill_oct(
    const int* __restrict__ src, const int* __restrict__ dst, const float* __restrict__ ew,
    int* __restrict__ cursor, unsigned* __restrict__ pe)
{
    const unsigned oct = blockIdx.x & 7;
    const int base = (blockIdx.x >> 3) * 2048;
#pragma unroll
    for (int i = 0; i < 8; ++i) {
        const int e = base + i * 256 + threadIdx.x;
        if (e < NE) {
            const int d = dst[e];
            if ((unsigned)d / 6250u == oct) {
                const int pos = atomicAdd(&cursor[d], 1);
                const unsigned wb = (unsigned)__half_as_ushort(__float2half_rn(ew[e]));
                pe[pos] = ((unsigned)src[e] & 0xFFFFu) | (wb << 16);
            }
        }
    }
}

// ================= weight packing (all three, one launch) =================
__device__ __forceinline__ void packb_body(const float* __restrict__ B, short* __restrict__ Bp, int NT, int b)
{
    const int o = b * 256 + threadIdx.x;
    if (o >= 4096 * NT) return;
    const int j = o & 7;
    const int lane = (o >> 3) & 63;
    const int tnt = o >> 9;
    const int nt = tnt % NT, ks = tnt / NT;
    const int k = ks * 32 + (lane >> 4) * 8 + j;
    const int n = nt * 16 + (lane & 15);
    Bp[o] = (short)f2b(B[k * (NT * 16) + n]);
}

__global__ __launch_bounds__(256) void packb_all(
    const float* __restrict__ W0, const float* __restrict__ W1, const float* __restrict__ W2,
    short* __restrict__ Bp0, short* __restrict__ Bp1, short* __restrict__ Bp2)
{
    const int b = blockIdx.x;
    if (b < 128)      packb_body(W0, Bp0, 8, b);
    else if (b < 256) packb_body(W1, Bp1, 8, b - 128);
    else              packb_body(W2, Bp2, 2, b - 256);
}

// ================= MFMA GEMM body — LDS-free A-fragment loads =================
// MODE 0: A = fp32 [M,256] (layer 0; fp32->bf16 cast in registers)
// MODE 1: A = x1p pre-only [M,64] uints; each fragment used twice:
//         raw bits -> pre half (cols 128..255), bn+relu -> act half (cols 0..127)
template <int NT, int MODE>
__device__ __forceinline__ void gemm_body(
    const void* __restrict__ Av, const short* __restrict__ Bp,
    short* __restrict__ C, int M,
    const float* __restrict__ sum, const float* __restrict__ ss,
    const float* __restrict__ gam, const float* __restrict__ bet)
{
    constexpr int TC = (NT > 4) ? 4 : NT;   // epilogue chunk: TC*16 cols
    constexpr int NCC = TC * 16;
    __shared__ float Cl[4][16 * NCC];       // per-wave C transpose buffer
    __shared__ float scs[128], shs[128];
    const int tid = threadIdx.x;
    const int w = tid >> 6;
    const int lane = tid & 63;
    const int lane15 = lane & 15;
    const int quad = lane >> 4;
    const int row0 = blockIdx.x * 64;
    const int m = row0 + w * 16 + lane15;
    const int mc = (m < M) ? m : 0;         // clamp: garbage rows never stored

    if (MODE == 1) {
        if (tid < 128) {
            const float inv = 1.f / (float)M;
            const float mu = sum[tid] * inv;
            const float var = ss[tid] * inv - mu * mu;
            const float s = gam[tid] * rsqrtf(var + 1e-5f);
            scs[tid] = s;
            shs[tid] = bet[tid] - mu * s;
        }
        __syncthreads();
    }

    f32x4 acc[NT];
#pragma unroll
    for (int t = 0; t < NT; ++t) acc[t] = (f32x4){0.f, 0.f, 0.f, 0.f};

    if (MODE == 0) {
        const float* arow = (const float*)Av + (long)mc * 256;
#pragma unroll
        for (int ks = 0; ks < 8; ++ks) {
            const float4 v0 = *(const float4*)&arow[ks * 32 + quad * 8];
            const float4 v1 = *(const float4*)&arow[ks * 32 + quad * 8 + 4];
            const bf16x8 af = u4_to_b8(pack2(v0.x, v0.y), pack2(v0.z, v0.w),
                                       pack2(v1.x, v1.y), pack2(v1.z, v1.w));
#pragma unroll
            for (int t = 0; t < NT; ++t) {
                const bf16x8 bf = *(const bf16x8*)&Bp[(((ks * NT + t) * 64) + lane) * 8];
                acc[t] = __builtin_amdgcn_mfma_f32_16x16x32_bf16(af, bf, acc[t], 0, 0, 0);
            }
        }
    } else {
        const unsigned* arow = (const unsigned*)Av + (long)mc * 64;
#pragma unroll
        for (int ks = 0; ks < 4; ++ks) {
            const uint4 pv = *(const uint4*)&arow[ks * 16 + quad * 4];
            const bf16x8 apre = u4_to_b8(pv.x, pv.y, pv.z, pv.w);
            const int c0 = ks * 32 + quad * 8;
            const float4 s0 = *(const float4*)&scs[c0];
            const float4 s1 = *(const float4*)&scs[c0 + 4];
            const float4 h0 = *(const float4*)&shs[c0];
            const float4 h1 = *(const float4*)&shs[c0 + 4];
            const bf16x8 aact = u4_to_b8(
                pack2(fmaxf(fmaf(blo(pv.x), s0.x, h0.x), 0.f), fmaxf(fmaf(bhi(pv.x), s0.y, h0.y), 0.f)),
                pack2(fmaxf(fmaf(blo(pv.y), s0.z, h0.z), 0.f), fmaxf(fmaf(bhi(pv.y), s0.w, h0.w), 0.f)),
                pack2(fmaxf(fmaf(blo(pv.z), s1.x, h1.x), 0.f), fmaxf(fmaf(bhi(pv.z), s1.y, h1.y), 0.f)),
                pack2(fmaxf(fmaf(blo(pv.w), s1.z, h1.z), 0.f), fmaxf(fmaf(bhi(pv.w), s1.w, h1.w), 0.f)));
#pragma unroll
            for (int t = 0; t < NT; ++t) {
                const bf16x8 bf = *(const bf16x8*)&Bp[(((ks * NT + t) * 64) + lane) * 8];
                acc[t] = __builtin_amdgcn_mfma_f32_16x16x32_bf16(aact, bf, acc[t], 0, 0, 0);
            }
#pragma unroll
            for (int t = 0; t < NT; ++t) {
                const bf16x8 bf = *(const bf16x8*)&Bp[((((ks + 4) * NT + t) * 64) + lane) * 8];
                acc[t] = __builtin_amdgcn_mfma_f32_16x16x32_bf16(apre, bf, acc[t], 0, 0, 0);
            }
        }
    }

    // per-wave chunked epilogue: LDS transpose -> bf16 pack -> 16B stores
    float* cl = Cl[w];
#pragma unroll
    for (int t0 = 0; t0 < NT; t0 += TC) {
#pragma unroll
        for (int tt = 0; tt < TC; ++tt)
#pragma unroll
            for (int r = 0; r < 4; ++r)
                cl[(quad * 4 + r) * NCC + tt * 16 + lane15] = acc[t0 + tt][r];
#pragma unroll
        for (int i = 0; i < (16 * NCC) / 512; ++i) {
            const int f = i * 512 + lane * 8;
            const int r = f / NCC;
            const int col = f % NCC;
            const int grow = row0 + w * 16 + r;
            const float4 lo = *(const float4*)&cl[f];
            const float4 hi = *(const float4*)&cl[f + 4];
            uint4 o;
            o.x = pack2(lo.x, lo.y);
            o.y = pack2(lo.z, lo.w);
            o.z = pack2(hi.x, hi.y);
            o.w = pack2(hi.z, hi.w);
            if (grow < M) *(uint4*)&C[(long)grow * (NT * 16) + t0 * 16 + col] = o;
        }
    }
}

// fused: layer-0 GEMM (blocks 0..781) + dst histogram (blocks 782..)
__global__ __launch_bounds__(256) void gemm0_hist(
    const float* __restrict__ x, const short* __restrict__ Bp, short* __restrict__ C, int M,
    const int* __restrict__ dst, int* __restrict__ deg)
{
    if (blockIdx.x < GB0) {
        gemm_body<8, 0>(x, Bp, C, M, nullptr, nullptr, nullptr, nullptr);
    } else {
        const int e = (blockIdx.x - GB0) * 256 + threadIdx.x;
        if (e < NE) atomicAdd(&deg[dst[e]], 1);
    }
}

template <int NT>
__global__ __launch_bounds__(256) void gemm_bn(
    const unsigned* __restrict__ A, const short* __restrict__ Bp, short* __restrict__ C, int M,
    const float* __restrict__ sum, const float* __restrict__ ss,
    const float* __restrict__ gam, const float* __restrict__ bet)
{
    gemm_body<NT, 1>(A, Bp, C, M, sum, ss, gam, bet);
}

// ================= gather aggregation (bf16 h, packed edges) =================
__global__ __launch_bounds__(256) void agg128b(
    const unsigned* __restrict__ h2, const int* __restrict__ rs,
    const unsigned* __restrict__ pe, unsigned* __restrict__ outp)
{
    const int node = blockIdx.x * 4 + (threadIdx.x >> 6);
    const int l = threadIdx.x & 63;
    int j = rs[node];
    const int j1 = rs[node + 1];
    float xs[8], ys[8];
#pragma unroll
    for (int t = 0; t < 8; ++t) { xs[t] = 0.f; ys[t] = 0.f; }
    for (; j + 7 < j1; j += 8) {
        unsigned u[8], v[8];
#pragma unroll
        for (int t = 0; t < 8; ++t) u[t] = pe[j + t];
#pragma unroll
        for (int t = 0; t < 8; ++t) v[t] = h2[(long)(u[t] & 0xFFFFu) * 64 + l];
#pragma unroll
        for (int t = 0; t < 8; ++t) {
            const float w = edgew(u[t]);
            xs[t] = fmaf(w, blo(v[t]), xs[t]);
            ys[t] = fmaf(w, bhi(v[t]), ys[t]);
        }
    }
    if (j + 3 < j1) {
        unsigned u[4], v[4];
#pragma unroll
        for (int t = 0; t < 4; ++t) u[t] = pe[j + t];
#pragma unroll
        for (int t = 0; t < 4; ++t) v[t] = h2[(long)(u[t] & 0xFFFFu) * 64 + l];
#pragma unroll
        for (int t = 0; t < 4; ++t) {
            const float w = edgew(u[t]);
            xs[t] = fmaf(w, blo(v[t]), xs[t]);
            ys[t] = fmaf(w, bhi(v[t]), ys[t]);
        }
        j += 4;
    }
    for (; j < j1; ++j) {
        const unsigned u = pe[j];
        const unsigned v = h2[(long)(u & 0xFFFFu) * 64 + l];
        const float w = edgew(u);
        xs[0] = fmaf(w, blo(v), xs[0]);
        ys[0] = fmaf(w, bhi(v), ys[0]);
    }
    const float X = ((xs[0] + xs[1]) + (xs[2] + xs[3])) + ((xs[4] + xs[5]) + (xs[6] + xs[7]));
    const float Y = ((ys[0] + ys[1]) + (ys[2] + ys[3])) + ((ys[4] + ys[5]) + (ys[6] + ys[7]));
    outp[(long)node * 64 + l] = pack2(X, Y);
}

__global__ __launch_bounds__(256) void agg32b(
    const unsigned* __restrict__ h2, const int* __restrict__ rs,
    const unsigned* __restrict__ pe, float* __restrict__ out)
{
    const int node = blockIdx.x * 16 + (threadIdx.x >> 4);
    const int l = threadIdx.x & 15;
    int j = rs[node];
    const int j1 = rs[node + 1];
    float xs[8], ys[8];
#pragma unroll
    for (int t = 0; t < 8; ++t) { xs[t] = 0.f; ys[t] = 0.f; }
    for (; j + 7 < j1; j += 8) {
        unsigned u[8], v[8];
#pragma unroll
        for (int t = 0; t < 8; ++t) u[t] = pe[j + t];
#pragma unroll
        for (int t = 0; t < 8; ++t) v[t] = h2[(long)(u[t] & 0xFFFFu) * 16 + l];
#pragma unroll
        for (int t = 0; t < 8; ++t) {
            const float w = edgew(u[t]);
            xs[t] = fmaf(w, blo(v[t]), xs[t]);
            ys[t] = fmaf(w, bhi(v[t]), ys[t]);
        }
    }
    if (j + 3 < j1) {
        unsigned u[4], v[4];
#pragma unroll
        for (int t = 0; t < 4; ++t) u[t] = pe[j + t];
#pragma unroll
        for (int t = 0; t < 4; ++t) v[t] = h2[(long)(u[t] & 0xFFFFu) * 16 + l];
#pragma unroll
        for (int t = 0; t < 4; ++t) {
            const float w = edgew(u[t]);
            xs[t] = fmaf(w, blo(v[t]), xs[t]);
            ys[t] = fmaf(w, bhi(v[t]), ys[t]);
        }
        j += 4;
    }
    for (; j < j1; ++j) {
        const unsigned u = pe[j];
        const unsigned v = h2[(long)(u & 0xFFFFu) * 16 + l];
        const float w = edgew(u);
        xs[0] = fmaf(w, blo(v), xs[0]);
        ys[0] = fmaf(w, bhi(v), ys[0]);
    }
    float2 o;
    o.x = ((xs[0] + xs[1]) + (xs[2] + xs[3])) + ((xs[4] + xs[5]) + (xs[6] + xs[7]));
    o.y = ((ys[0] + ys[1]) + (ys[2] + ys[3])) + ((ys[4] + ys[5]) + (ys[6] + ys[7]));
    *(float2*)&out[(long)node * 32 + 2 * l] = o;
}

// ================= BN stats (pre rows = 64 uints) =================
__global__ __launch_bounds__(256) void bn_stats_b(
    const unsigned* __restrict__ pre, float* __restrict__ sum, float* __restrict__ ss, int M)
{
    const int c2 = threadIdx.x & 63;
    const int g = threadIdx.x >> 6;
    float s0 = 0.f, s1 = 0.f, q0 = 0.f, q1 = 0.f;
    for (int row = blockIdx.x * 4 + g; row < M; row += gridDim.x * 4) {
        const unsigned v = pre[(long)row * 64 + c2];
        const float lo = blo(v), hi = bhi(v);
        s0 += lo; s1 += hi;
        q0 = fmaf(lo, lo, q0); q1 = fmaf(hi, hi, q1);
    }
    __shared__ float A0[256], A1[256], B0[256], B1[256];
    A0[threadIdx.x] = s0; A1[threadIdx.x] = s1;
    B0[threadIdx.x] = q0; B1[threadIdx.x] = q1;
    __syncthreads();
    if (threadIdx.x < 64) {
        const int t = threadIdx.x;
        atomicAdd(&sum[2 * t],     A0[t] + A0[t + 64] + A0[t + 128] + A0[t + 192]);
        atomicAdd(&sum[2 * t + 1], A1[t] + A1[t + 64] + A1[t + 128] + A1[t + 192]);
        atomicAdd(&ss[2 * t],      B0[t] + B0[t + 64] + B0[t + 128] + B0[t + 192]);
        atomicAdd(&ss[2 * t + 1],  B1[t] + B1[t + 64] + B1[t + 128] + B1[t + 192]);
    }
}

extern "C" void kernel_launch(void* const* d_in, const int* in_sizes, int n_in,
                              void* d_out, int out_size, void* d_ws, size_t ws_size,
                              hipStream_t stream) {
    const float* x   = (const float*)d_in[0];
    const int*   src = (const int*)d_in[1];
    const int*   dst = (const int*)d_in[2];
    const float* ew  = (const float*)d_in[3];
    const float* W0  = (const float*)d_in[4];
    const float* W1  = (const float*)d_in[5];
    const float* W2  = (const float*)d_in[6];
    const float* g0  = (const float*)d_in[7];
    const float* b0  = (const float*)d_in[8];
    const float* g1  = (const float*)d_in[9];
    const float* b1  = (const float*)d_in[10];
    float* out = (float*)d_out;

    // workspace layout
    short* h   = (short*)d_ws;                         // [NN*128] bf16 (also [NN*32] for out layer)
    unsigned* x1p = (unsigned*)(h + (size_t)NN * 128); // [NN*64] uints = pre-only bf16x2
    float* st  = (float*)(x1p + (size_t)NN * 64);      // 1024 floats
    int*  rs   = (int*)(st + 1024);                    // 50004
    int*  deg  = rs + 50004;                           // NN (cursor)
    int*  bsum = deg + NN;                             // 256
    int*  boff = bsum + 256;                           // 256
    unsigned* pe = (unsigned*)(boff + 256);            // NE packed edges
    short* Bp0 = (short*)(pe + NE);                    // 32768
    short* Bp1 = Bp0 + 32768;                          // 32768
    short* Bp2 = Bp1 + 32768;                          // 8192

    float* sum0 = st,       *ss0 = st + 128;
    float* sum1 = st + 512, *ss1 = st + 640;

    const int gN = (NN + 255) / 256;   // 196
    const int gE = (NE + 255) / 256;   // 3125

    hipMemsetAsync(deg, 0, (size_t)NN * 4, stream);
    hipMemsetAsync(st, 0, 1024 * 4, stream);

    packb_all<<<288, 256, 0, stream>>>(W0, W1, W2, Bp0, Bp1, Bp2);

    gemm0_hist<<<GB0 + gE, 256, 0, stream>>>(x, Bp0, h, NN, dst, deg);

    scan1_k<<<gN, 256, 0, stream>>>(deg, rs, bsum);
    scan2_k<<<1, 256, 0, stream>>>(bsum, boff, gN);
    addoff_k<<<gN, 256, 0, stream>>>(rs, boff, deg);
    fill_oct<<<((NE + 2047) / 2048) * 8, 256, 0, stream>>>(src, dst, ew, deg, pe);

    // ---- layer 0 aggregation + stats ----
    agg128b<<<12500, 256, 0, stream>>>((const unsigned*)h, rs, pe, x1p);
    bn_stats_b<<<256, 256, 0, stream>>>(x1p, sum0, ss0, NN);

    // ---- layer 1 (BN0+ReLU fused into fragment load) ----
    gemm_bn<8><<<782, 256, 0, stream>>>(x1p, Bp1, h, NN, sum0, ss0, g0, b0);
    agg128b<<<12500, 256, 0, stream>>>((const unsigned*)h, rs, pe, x1p);
    bn_stats_b<<<256, 256, 0, stream>>>(x1p, sum1, ss1, NN);

    // ---- output layer (BN1+ReLU fused into fragment load) ----
    gemm_bn<2><<<782, 256, 0, stream>>>(x1p, Bp2, h, NN, sum1, ss1, g1, b1);
    agg32b<<<3125, 256, 0, stream>>>((const unsigned*)h, rs, pe, out);
}

// Round 7
// 333.685 us; speedup vs baseline: 9.9634x; 1.0041x over previous
//
#include <hip/hip_runtime.h>
#include <hip/hip_fp16.h>

#define NN 50000
#define NE 800000
#define GB0 782       // gemm blocks in fused gemm0+hist
#define DEGSTRIDE 50048

typedef __attribute__((ext_vector_type(8))) short bf16x8;
typedef __attribute__((ext_vector_type(4))) float f32x4;

__device__ inline float blo(unsigned u) { union { unsigned i; float f; } c; c.i = u << 16; return c.f; }
__device__ inline float bhi(unsigned u) { union { unsigned i; float f; } c; c.i = u & 0xFFFF0000u; return c.f; }
__device__ inline unsigned short f2b(float f) {
    union { float f; unsigned u; } c; c.f = f;
    return (unsigned short)((c.u + 0x7FFFu + ((c.u >> 16) & 1u)) >> 16);
}
__device__ inline unsigned pack2(float x, float y) {
    union { float f; unsigned u; } a, b; a.f = x; b.f = y;
    const unsigned lo = (a.u + 0x7FFFu + ((a.u >> 16) & 1u)) >> 16;
    const unsigned hi = (b.u + 0x7FFFu + ((b.u >> 16) & 1u)) & 0xFFFF0000u;
    return (lo & 0xFFFFu) | hi;
}
__device__ inline float edgew(unsigned u) {
    return __half2float(__ushort_as_half((unsigned short)(u >> 16)));
}
__device__ inline bf16x8 u4_to_b8(unsigned a, unsigned b, unsigned c, unsigned d) {
    union { unsigned u[4]; bf16x8 v; } x;
    x.u[0] = a; x.u[1] = b; x.u[2] = c; x.u[3] = d;
    return x.v;
}

// ================= CSR build =================
// scan1 sums the 8 XCD-replicated histograms, then block-local exclusive scan
__global__ __launch_bounds__(256) void scan1_k(const int* __restrict__ degrep, int* __restrict__ rs, int* __restrict__ bsum)
{
    __shared__ int tmp[256];
    const int i = blockIdx.x * 256 + threadIdx.x;
    int v = 0;
    if (i < NN) {
#pragma unroll
        for (int r = 0; r < 8; ++r) v += degrep[r * DEGSTRIDE + i];
    }
    tmp[threadIdx.x] = v;
    __syncthreads();
    for (int off = 1; off < 256; off <<= 1) {
        const int t = (threadIdx.x >= off) ? tmp[threadIdx.x - off] : 0;
        __syncthreads();
        tmp[threadIdx.x] += t;
        __syncthreads();
    }
    if (i < NN) rs[i] = tmp[threadIdx.x] - v;
    if (threadIdx.x == 255) bsum[blockIdx.x] = tmp[255];
}

__global__ void scan2_k(const int* __restrict__ bsum, int* __restrict__ boff, int nb)
{
    __shared__ int tmp[256];
    const int v = (threadIdx.x < nb) ? bsum[threadIdx.x] : 0;
    tmp[threadIdx.x] = v;
    __syncthreads();
    for (int off = 1; off < 256; off <<= 1) {
        const int t = (threadIdx.x >= off) ? tmp[threadIdx.x - off] : 0;
        __syncthreads();
        tmp[threadIdx.x] += t;
        __syncthreads();
    }
    if (threadIdx.x < nb) boff[threadIdx.x] = tmp[threadIdx.x] - v;
}

__global__ __launch_bounds__(256) void addoff_k(int* __restrict__ rs, const int* __restrict__ boff, int* __restrict__ cursor)
{
    const int i = blockIdx.x * 256 + threadIdx.x;
    if (i < NN) {
        const int r = rs[i] + boff[blockIdx.x];
        rs[i] = r;
        cursor[i] = r;
    }
    if (i == 0) rs[NN] = NE;
}

// XCD-partitioned CSR fill: block handles chunk blockIdx/8, octant blockIdx%8.
__global__ __launch_bounds__(256) void fill_oct(
    const int* __restrict__ src, const int* __restrict__ dst, const float* __restrict__ ew,
    int* __restrict__ cursor, unsigned* __restrict__ pe)
{
    const unsigned oct = blockIdx.x & 7;
    const int base = (blockIdx.x >> 3) * 2048;
#pragma unroll
    for (int i = 0; i < 8; ++i) {
        const int e = base + i * 256 + threadIdx.x;
        if (e < NE) {
            const int d = dst[e];
            if ((unsigned)d / 6250u == oct) {
                const int pos = atomicAdd(&cursor[d], 1);
                const unsigned wb = (unsigned)__half_as_ushort(__float2half_rn(ew[e]));
                pe[pos] = ((unsigned)src[e] & 0xFFFFu) | (wb << 16);
            }
        }
    }
}

// ================= weight packing (all three, one launch) =================
__device__ __forceinline__ void packb_body(const float* __restrict__ B, short* __restrict__ Bp, int NT, int b)
{
    const int o = b * 256 + threadIdx.x;
    if (o >= 4096 * NT) return;
    const int j = o & 7;
    const int lane = (o >> 3) & 63;
    const int tnt = o >> 9;
    const int nt = tnt % NT, ks = tnt / NT;
    const int k = ks * 32 + (lane >> 4) * 8 + j;
    const int n = nt * 16 + (lane & 15);
    Bp[o] = (short)f2b(B[k * (NT * 16) + n]);
}

__global__ __launch_bounds__(256) void packb_all(
    const float* __restrict__ W0, const float* __restrict__ W1, const float* __restrict__ W2,
    short* __restrict__ Bp0, short* __restrict__ Bp1, short* __restrict__ Bp2)
{
    const int b = blockIdx.x;
    if (b < 128)      packb_body(W0, Bp0, 8, b);
    else if (b < 256) packb_body(W1, Bp1, 8, b - 128);
    else              packb_body(W2, Bp2, 2, b - 256);
}

// ================= MFMA GEMM body — LDS-free A-fragment loads =================
// MODE 0: A = fp32 [M,256] (layer 0; fp32->bf16 cast in registers)
// MODE 1: A = x1p pre-only [M,64] uints; each fragment used twice:
//         raw bits -> pre half (cols 128..255), bn+relu -> act half (cols 0..127)
template <int NT, int MODE>
__device__ __forceinline__ void gemm_body(
    const void* __restrict__ Av, const short* __restrict__ Bp,
    short* __restrict__ C, int M,
    const float* __restrict__ sum, const float* __restrict__ ss,
    const float* __restrict__ gam, const float* __restrict__ bet)
{
    constexpr int TC = (NT > 4) ? 4 : NT;   // epilogue chunk: TC*16 cols
    constexpr int NCC = TC * 16;
    __shared__ float Cl[4][16 * NCC];       // per-wave C transpose buffer
    __shared__ float scs[128], shs[128];
    const int tid = threadIdx.x;
    const int w = tid >> 6;
    const int lane = tid & 63;
    const int lane15 = lane & 15;
    const int quad = lane >> 4;
    const int row0 = blockIdx.x * 64;
    const int m = row0 + w * 16 + lane15;
    const int mc = (m < M) ? m : 0;         // clamp: garbage rows never stored

    if (MODE == 1) {
        if (tid < 128) {
            const float inv = 1.f / (float)M;
            const float mu = sum[tid] * inv;
            const float var = ss[tid] * inv - mu * mu;
            const float s = gam[tid] * rsqrtf(var + 1e-5f);
            scs[tid] = s;
            shs[tid] = bet[tid] - mu * s;
        }
        __syncthreads();
    }

    f32x4 acc[NT];
#pragma unroll
    for (int t = 0; t < NT; ++t) acc[t] = (f32x4){0.f, 0.f, 0.f, 0.f};

    if (MODE == 0) {
        const float* arow = (const float*)Av + (long)mc * 256;
#pragma unroll
        for (int ks = 0; ks < 8; ++ks) {
            const float4 v0 = *(const float4*)&arow[ks * 32 + quad * 8];
            const float4 v1 = *(const float4*)&arow[ks * 32 + quad * 8 + 4];
            const bf16x8 af = u4_to_b8(pack2(v0.x, v0.y), pack2(v0.z, v0.w),
                                       pack2(v1.x, v1.y), pack2(v1.z, v1.w));
#pragma unroll
            for (int t = 0; t < NT; ++t) {
                const bf16x8 bf = *(const bf16x8*)&Bp[(((ks * NT + t) * 64) + lane) * 8];
                acc[t] = __builtin_amdgcn_mfma_f32_16x16x32_bf16(af, bf, acc[t], 0, 0, 0);
            }
        }
    } else {
        const unsigned* arow = (const unsigned*)Av + (long)mc * 64;
#pragma unroll
        for (int ks = 0; ks < 4; ++ks) {
            const uint4 pv = *(const uint4*)&arow[ks * 16 + quad * 4];
            const bf16x8 apre = u4_to_b8(pv.x, pv.y, pv.z, pv.w);
            const int c0 = ks * 32 + quad * 8;
            const float4 s0 = *(const float4*)&scs[c0];
            const float4 s1 = *(const float4*)&scs[c0 + 4];
            const float4 h0 = *(const float4*)&shs[c0];
            const float4 h1 = *(const float4*)&shs[c0 + 4];
            const bf16x8 aact = u4_to_b8(
                pack2(fmaxf(fmaf(blo(pv.x), s0.x, h0.x), 0.f), fmaxf(fmaf(bhi(pv.x), s0.y, h0.y), 0.f)),
                pack2(fmaxf(fmaf(blo(pv.y), s0.z, h0.z), 0.f), fmaxf(fmaf(bhi(pv.y), s0.w, h0.w), 0.f)),
                pack2(fmaxf(fmaf(blo(pv.z), s1.x, h1.x), 0.f), fmaxf(fmaf(bhi(pv.z), s1.y, h1.y), 0.f)),
                pack2(fmaxf(fmaf(blo(pv.w), s1.z, h1.z), 0.f), fmaxf(fmaf(bhi(pv.w), s1.w, h1.w), 0.f)));
#pragma unroll
            for (int t = 0; t < NT; ++t) {
                const bf16x8 bf = *(const bf16x8*)&Bp[(((ks * NT + t) * 64) + lane) * 8];
                acc[t] = __builtin_amdgcn_mfma_f32_16x16x32_bf16(aact, bf, acc[t], 0, 0, 0);
            }
#pragma unroll
            for (int t = 0; t < NT; ++t) {
                const bf16x8 bf = *(const bf16x8*)&Bp[((((ks + 4) * NT + t) * 64) + lane) * 8];
                acc[t] = __builtin_amdgcn_mfma_f32_16x16x32_bf16(apre, bf, acc[t], 0, 0, 0);
            }
        }
    }

    // per-wave chunked epilogue: LDS transpose -> bf16 pack -> 16B stores
    float* cl = Cl[w];
#pragma unroll
    for (int t0 = 0; t0 < NT; t0 += TC) {
#pragma unroll
        for (int tt = 0; tt < TC; ++tt)
#pragma unroll
            for (int r = 0; r < 4; ++r)
                cl[(quad * 4 + r) * NCC + tt * 16 + lane15] = acc[t0 + tt][r];
#pragma unroll
        for (int i = 0; i < (16 * NCC) / 512; ++i) {
            const int f = i * 512 + lane * 8;
            const int r = f / NCC;
            const int col = f % NCC;
            const int grow = row0 + w * 16 + r;
            const float4 lo = *(const float4*)&cl[f];
            const float4 hi = *(const float4*)&cl[f + 4];
            uint4 o;
            o.x = pack2(lo.x, lo.y);
            o.y = pack2(lo.z, lo.w);
            o.z = pack2(hi.x, hi.y);
            o.w = pack2(hi.z, hi.w);
            if (grow < M) *(uint4*)&C[(long)grow * (NT * 16) + t0 * 16 + col] = o;
        }
    }
}

// fused: layer-0 GEMM (blocks 0..781) + XCD-replicated dst histogram (blocks 782..)
__global__ __launch_bounds__(256) void gemm0_hist(
    const float* __restrict__ x, const short* __restrict__ Bp, short* __restrict__ C, int M,
    const int* __restrict__ dst, int* __restrict__ degrep)
{
    if (blockIdx.x < GB0) {
        gemm_body<8, 0>(x, Bp, C, M, nullptr, nullptr, nullptr, nullptr);
    } else {
        // replica = blockIdx&7: consecutive blocks round-robin XCDs, so each
        // replica's lines stay in one XCD L2 -> no cross-XCD atomic ping-pong
        const int e = (blockIdx.x - GB0) * 256 + threadIdx.x;
        if (e < NE) atomicAdd(&degrep[(blockIdx.x & 7) * DEGSTRIDE + dst[e]], 1);
    }
}

template <int NT>
__global__ __launch_bounds__(256) void gemm_bn(
    const unsigned* __restrict__ A, const short* __restrict__ Bp, short* __restrict__ C, int M,
    const float* __restrict__ sum, const float* __restrict__ ss,
    const float* __restrict__ gam, const float* __restrict__ bet)
{
    gemm_body<NT, 1>(A, Bp, C, M, sum, ss, gam, bet);
}

// ================= gather aggregation (bf16 h, packed edges) =================
__global__ __launch_bounds__(256) void agg128b(
    const unsigned* __restrict__ h2, const int* __restrict__ rs,
    const unsigned* __restrict__ pe, unsigned* __restrict__ outp)
{
    const int node = blockIdx.x * 4 + (threadIdx.x >> 6);
    const int l = threadIdx.x & 63;
    int j = rs[node];
    const int j1 = rs[node + 1];
    float xs[8], ys[8];
#pragma unroll
    for (int t = 0; t < 8; ++t) { xs[t] = 0.f; ys[t] = 0.f; }
    for (; j + 7 < j1; j += 8) {
        unsigned u[8], v[8];
#pragma unroll
        for (int t = 0; t < 8; ++t) u[t] = pe[j + t];
#pragma unroll
        for (int t = 0; t < 8; ++t) v[t] = h2[(long)(u[t] & 0xFFFFu) * 64 + l];
#pragma unroll
        for (int t = 0; t < 8; ++t) {
            const float w = edgew(u[t]);
            xs[t] = fmaf(w, blo(v[t]), xs[t]);
            ys[t] = fmaf(w, bhi(v[t]), ys[t]);
        }
    }
    if (j + 3 < j1) {
        unsigned u[4], v[4];
#pragma unroll
        for (int t = 0; t < 4; ++t) u[t] = pe[j + t];
#pragma unroll
        for (int t = 0; t < 4; ++t) v[t] = h2[(long)(u[t] & 0xFFFFu) * 64 + l];
#pragma unroll
        for (int t = 0; t < 4; ++t) {
            const float w = edgew(u[t]);
            xs[t] = fmaf(w, blo(v[t]), xs[t]);
            ys[t] = fmaf(w, bhi(v[t]), ys[t]);
        }
        j += 4;
    }
    for (; j < j1; ++j) {
        const unsigned u = pe[j];
        const unsigned v = h2[(long)(u & 0xFFFFu) * 64 + l];
        const float w = edgew(u);
        xs[0] = fmaf(w, blo(v), xs[0]);
        ys[0] = fmaf(w, bhi(v), ys[0]);
    }
    const float X = ((xs[0] + xs[1]) + (xs[2] + xs[3])) + ((xs[4] + xs[5]) + (xs[6] + xs[7]));
    const float Y = ((ys[0] + ys[1]) + (ys[2] + ys[3])) + ((ys[4] + ys[5]) + (ys[6] + ys[7]));
    outp[(long)node * 64 + l] = pack2(X, Y);
}

__global__ __launch_bounds__(256) void agg32b(
    const unsigned* __restrict__ h2, const int* __restrict__ rs,
    const unsigned* __restrict__ pe, float* __restrict__ out)
{
    const int node = blockIdx.x * 16 + (threadIdx.x >> 4);
    const int l = threadIdx.x & 15;
    int j = rs[node];
    const int j1 = rs[node + 1];
    float xs[8], ys[8];
#pragma unroll
    for (int t = 0; t < 8; ++t) { xs[t] = 0.f; ys[t] = 0.f; }
    for (; j + 7 < j1; j += 8) {
        unsigned u[8], v[8];
#pragma unroll
        for (int t = 0; t < 8; ++t) u[t] = pe[j + t];
#pragma unroll
        for (int t = 0; t < 8; ++t) v[t] = h2[(long)(u[t] & 0xFFFFu) * 16 + l];
#pragma unroll
        for (int t = 0; t < 8; ++t) {
            const float w = edgew(u[t]);
            xs[t] = fmaf(w, blo(v[t]), xs[t]);
            ys[t] = fmaf(w, bhi(v[t]), ys[t]);
        }
    }
    if (j + 3 < j1) {
        unsigned u[4], v[4];
#pragma unroll
        for (int t = 0; t < 4; ++t) u[t] = pe[j + t];
#pragma unroll
        for (int t = 0; t < 4; ++t) v[t] = h2[(long)(u[t] & 0xFFFFu) * 16 + l];
#pragma unroll
        for (int t = 0; t < 4; ++t) {
            const float w = edgew(u[t]);
            xs[t] = fmaf(w, blo(v[t]), xs[t]);
            ys[t] = fmaf(w, bhi(v[t]), ys[t]);
        }
        j += 4;
    }
    for (; j < j1; ++j) {
        const unsigned u = pe[j];
        const unsigned v = h2[(long)(u & 0xFFFFu) * 16 + l];
        const float w = edgew(u);
        xs[0] = fmaf(w, blo(v), xs[0]);
        ys[0] = fmaf(w, bhi(v), ys[0]);
    }
    float2 o;
    o.x = ((xs[0] + xs[1]) + (xs[2] + xs[3])) + ((xs[4] + xs[5]) + (xs[6] + xs[7]));
    o.y = ((ys[0] + ys[1]) + (ys[2] + ys[3])) + ((ys[4] + ys[5]) + (ys[6] + ys[7]));
    *(float2*)&out[(long)node * 32 + 2 * l] = o;
}

// ================= BN stats (pre rows = 64 uints) =================
__global__ __launch_bounds__(256) void bn_stats_b(
    const unsigned* __restrict__ pre, float* __restrict__ sum, float* __restrict__ ss, int M)
{
    const int c2 = threadIdx.x & 63;
    const int g = threadIdx.x >> 6;
    float s0 = 0.f, s1 = 0.f, q0 = 0.f, q1 = 0.f;
    for (int row = blockIdx.x * 4 + g; row < M; row += gridDim.x * 4) {
        const unsigned v = pre[(long)row * 64 + c2];
        const float lo = blo(v), hi = bhi(v);
        s0 += lo; s1 += hi;
        q0 = fmaf(lo, lo, q0); q1 = fmaf(hi, hi, q1);
    }
    __shared__ float A0[256], A1[256], B0[256], B1[256];
    A0[threadIdx.x] = s0; A1[threadIdx.x] = s1;
    B0[threadIdx.x] = q0; B1[threadIdx.x] = q1;
    __syncthreads();
    if (threadIdx.x < 64) {
        const int t = threadIdx.x;
        atomicAdd(&sum[2 * t],     A0[t] + A0[t + 64] + A0[t + 128] + A0[t + 192]);
        atomicAdd(&sum[2 * t + 1], A1[t] + A1[t + 64] + A1[t + 128] + A1[t + 192]);
        atomicAdd(&ss[2 * t],      B0[t] + B0[t + 64] + B0[t + 128] + B0[t + 192]);
        atomicAdd(&ss[2 * t + 1],  B1[t] + B1[t + 64] + B1[t + 128] + B1[t + 192]);
    }
}

extern "C" void kernel_launch(void* const* d_in, const int* in_sizes, int n_in,
                              void* d_out, int out_size, void* d_ws, size_t ws_size,
                              hipStream_t stream) {
    const float* x   = (const float*)d_in[0];
    const int*   src = (const int*)d_in[1];
    const int*   dst = (const int*)d_in[2];
    const float* ew  = (const float*)d_in[3];
    const float* W0  = (const float*)d_in[4];
    const float* W1  = (const float*)d_in[5];
    const float* W2  = (const float*)d_in[6];
    const float* g0  = (const float*)d_in[7];
    const float* b0  = (const float*)d_in[8];
    const float* g1  = (const float*)d_in[9];
    const float* b1  = (const float*)d_in[10];
    float* out = (float*)d_out;

    // workspace layout
    short* h   = (short*)d_ws;                         // [NN*128] bf16 (also [NN*32] for out layer)
    unsigned* x1p = (unsigned*)(h + (size_t)NN * 128); // [NN*64] uints = pre-only bf16x2
    float* st  = (float*)(x1p + (size_t)NN * 64);      // 1024 floats
    int*  rs   = (int*)(st + 1024);                    // 50004
    int*  degrep = rs + 50004;                         // 8 * DEGSTRIDE replicated hist
    int*  cursor = degrep + 8 * DEGSTRIDE;             // NN
    int*  bsum = cursor + NN;                          // 256
    int*  boff = bsum + 256;                           // 256
    unsigned* pe = (unsigned*)(boff + 256);            // NE packed edges
    short* Bp0 = (short*)(pe + NE);                    // 32768
    short* Bp1 = Bp0 + 32768;                          // 32768
    short* Bp2 = Bp1 + 32768;                          // 8192

    float* sum0 = st,       *ss0 = st + 128;
    float* sum1 = st + 512, *ss1 = st + 640;

    const int gN = (NN + 255) / 256;   // 196
    const int gE = (NE + 255) / 256;   // 3125

    hipMemsetAsync(degrep, 0, (size_t)8 * DEGSTRIDE * 4, stream);
    hipMemsetAsync(st, 0, 1024 * 4, stream);

    packb_all<<<288, 256, 0, stream>>>(W0, W1, W2, Bp0, Bp1, Bp2);

    gemm0_hist<<<GB0 + gE, 256, 0, stream>>>(x, Bp0, h, NN, dst, degrep);

    scan1_k<<<gN, 256, 0, stream>>>(degrep, rs, bsum);
    scan2_k<<<1, 256, 0, stream>>>(bsum, boff, gN);
    addoff_k<<<gN, 256, 0, stream>>>(rs, boff, cursor);
    fill_oct<<<((NE + 2047) / 2048) * 8, 256, 0, stream>>>(src, dst, ew, cursor, pe);

    // ---- layer 0 aggregation + stats ----
    agg128b<<<12500, 256, 0, stream>>>((const unsigned*)h, rs, pe, x1p);
    bn_stats_b<<<256, 256, 0, stream>>>(x1p, sum0, ss0, NN);

    // ---- layer 1 (BN0+ReLU fused into fragment load) ----
    gemm_bn<8><<<782, 256, 0, stream>>>(x1p, Bp1, h, NN, sum0, ss0, g0, b0);
    agg128b<<<12500, 256, 0, stream>>>((const unsigned*)h, rs, pe, x1p);
    bn_stats_b<<<256, 256, 0, stream>>>(x1p, sum1, ss1, NN);

    // ---- output layer (BN1+ReLU fused into fragment load) ----
    gemm_bn<2><<<782, 256, 0, stream>>>(x1p, Bp2, h, NN, sum1, ss1, g1, b1);
    agg32b<<<3125, 256, 0, stream>>>((const unsigned*)h, rs, pe, out);
}

// Round 8
// 307.884 us; speedup vs baseline: 10.7983x; 1.0838x over previous
//
#include <hip/hip_runtime.h>
#include <hip/hip_fp16.h>

#define NN 50000
#define NE 800000
#define GB0 782       // gemm blocks in fused gemm0+hist1
#define NBLK1 391     // phase-1 blocks, 2048 edges each
#define NBUCK 196     // coarse buckets = dst>>8

typedef __attribute__((ext_vector_type(8))) short bf16x8;
typedef __attribute__((ext_vector_type(4))) float f32x4;

__device__ inline float blo(unsigned u) { union { unsigned i; float f; } c; c.i = u << 16; return c.f; }
__device__ inline float bhi(unsigned u) { union { unsigned i; float f; } c; c.i = u & 0xFFFF0000u; return c.f; }
__device__ inline unsigned short f2b(float f) {
    union { float f; unsigned u; } c; c.f = f;
    return (unsigned short)((c.u + 0x7FFFu + ((c.u >> 16) & 1u)) >> 16);
}
__device__ inline unsigned pack2(float x, float y) {
    union { float f; unsigned u; } a, b; a.f = x; b.f = y;
    const unsigned lo = (a.u + 0x7FFFu + ((a.u >> 16) & 1u)) >> 16;
    const unsigned hi = (b.u + 0x7FFFu + ((b.u >> 16) & 1u)) & 0xFFFF0000u;
    return (lo & 0xFFFFu) | hi;
}
__device__ inline float edgew(unsigned u) {
    return __half2float(__ushort_as_half((unsigned short)(u >> 16)));
}
__device__ inline bf16x8 u4_to_b8(unsigned a, unsigned b, unsigned c, unsigned d) {
    union { unsigned u[4]; bf16x8 v; } x;
    x.u[0] = a; x.u[1] = b; x.u[2] = c; x.u[3] = d;
    return x.v;
}

// ================= weight packing (all three, one launch) =================
__device__ __forceinline__ void packb_body(const float* __restrict__ B, short* __restrict__ Bp, int NT, int b)
{
    const int o = b * 256 + threadIdx.x;
    if (o >= 4096 * NT) return;
    const int j = o & 7;
    const int lane = (o >> 3) & 63;
    const int tnt = o >> 9;
    const int nt = tnt % NT, ks = tnt / NT;
    const int k = ks * 32 + (lane >> 4) * 8 + j;
    const int n = nt * 16 + (lane & 15);
    Bp[o] = (short)f2b(B[k * (NT * 16) + n]);
}

__global__ __launch_bounds__(256) void packb_all(
    const float* __restrict__ W0, const float* __restrict__ W1, const float* __restrict__ W2,
    short* __restrict__ Bp0, short* __restrict__ Bp1, short* __restrict__ Bp2)
{
    const int b = blockIdx.x;
    if (b < 128)      packb_body(W0, Bp0, 8, b);
    else if (b < 256) packb_body(W1, Bp1, 8, b - 128);
    else              packb_body(W2, Bp2, 2, b - 256);
}

// ================= MFMA GEMM body — LDS-free A-fragment loads =================
template <int NT, int MODE>
__device__ __forceinline__ void gemm_body(
    const void* __restrict__ Av, const short* __restrict__ Bp,
    short* __restrict__ C, int M,
    const float* __restrict__ sum, const float* __restrict__ ss,
    const float* __restrict__ gam, const float* __restrict__ bet)
{
    constexpr int TC = (NT > 4) ? 4 : NT;
    constexpr int NCC = TC * 16;
    __shared__ float Cl[4][16 * NCC];
    __shared__ float scs[128], shs[128];
    const int tid = threadIdx.x;
    const int w = tid >> 6;
    const int lane = tid & 63;
    const int lane15 = lane & 15;
    const int quad = lane >> 4;
    const int row0 = blockIdx.x * 64;
    const int m = row0 + w * 16 + lane15;
    const int mc = (m < M) ? m : 0;

    if (MODE == 1) {
        if (tid < 128) {
            const float inv = 1.f / (float)M;
            const float mu = sum[tid] * inv;
            const float var = ss[tid] * inv - mu * mu;
            const float s = gam[tid] * rsqrtf(var + 1e-5f);
            scs[tid] = s;
            shs[tid] = bet[tid] - mu * s;
        }
        __syncthreads();
    }

    f32x4 acc[NT];
#pragma unroll
    for (int t = 0; t < NT; ++t) acc[t] = (f32x4){0.f, 0.f, 0.f, 0.f};

    if (MODE == 0) {
        const float* arow = (const float*)Av + (long)mc * 256;
#pragma unroll
        for (int ks = 0; ks < 8; ++ks) {
            const float4 v0 = *(const float4*)&arow[ks * 32 + quad * 8];
            const float4 v1 = *(const float4*)&arow[ks * 32 + quad * 8 + 4];
            const bf16x8 af = u4_to_b8(pack2(v0.x, v0.y), pack2(v0.z, v0.w),
                                       pack2(v1.x, v1.y), pack2(v1.z, v1.w));
#pragma unroll
            for (int t = 0; t < NT; ++t) {
                const bf16x8 bf = *(const bf16x8*)&Bp[(((ks * NT + t) * 64) + lane) * 8];
                acc[t] = __builtin_amdgcn_mfma_f32_16x16x32_bf16(af, bf, acc[t], 0, 0, 0);
            }
        }
    } else {
        const unsigned* arow = (const unsigned*)Av + (long)mc * 64;
#pragma unroll
        for (int ks = 0; ks < 4; ++ks) {
            const uint4 pv = *(const uint4*)&arow[ks * 16 + quad * 4];
            const bf16x8 apre = u4_to_b8(pv.x, pv.y, pv.z, pv.w);
            const int c0 = ks * 32 + quad * 8;
            const float4 s0 = *(const float4*)&scs[c0];
            const float4 s1 = *(const float4*)&scs[c0 + 4];
            const float4 h0 = *(const float4*)&shs[c0];
            const float4 h1 = *(const float4*)&shs[c0 + 4];
            const bf16x8 aact = u4_to_b8(
                pack2(fmaxf(fmaf(blo(pv.x), s0.x, h0.x), 0.f), fmaxf(fmaf(bhi(pv.x), s0.y, h0.y), 0.f)),
                pack2(fmaxf(fmaf(blo(pv.y), s0.z, h0.z), 0.f), fmaxf(fmaf(bhi(pv.y), s0.w, h0.w), 0.f)),
                pack2(fmaxf(fmaf(blo(pv.z), s1.x, h1.x), 0.f), fmaxf(fmaf(bhi(pv.z), s1.y, h1.y), 0.f)),
                pack2(fmaxf(fmaf(blo(pv.w), s1.z, h1.z), 0.f), fmaxf(fmaf(bhi(pv.w), s1.w, h1.w), 0.f)));
#pragma unroll
            for (int t = 0; t < NT; ++t) {
                const bf16x8 bf = *(const bf16x8*)&Bp[(((ks * NT + t) * 64) + lane) * 8];
                acc[t] = __builtin_amdgcn_mfma_f32_16x16x32_bf16(aact, bf, acc[t], 0, 0, 0);
            }
#pragma unroll
            for (int t = 0; t < NT; ++t) {
                const bf16x8 bf = *(const bf16x8*)&Bp[((((ks + 4) * NT + t) * 64) + lane) * 8];
                acc[t] = __builtin_amdgcn_mfma_f32_16x16x32_bf16(apre, bf, acc[t], 0, 0, 0);
            }
        }
    }

    float* cl = Cl[w];
#pragma unroll
    for (int t0 = 0; t0 < NT; t0 += TC) {
#pragma unroll
        for (int tt = 0; tt < TC; ++tt)
#pragma unroll
            for (int r = 0; r < 4; ++r)
                cl[(quad * 4 + r) * NCC + tt * 16 + lane15] = acc[t0 + tt][r];
#pragma unroll
        for (int i = 0; i < (16 * NCC) / 512; ++i) {
            const int f = i * 512 + lane * 8;
            const int r = f / NCC;
            const int col = f % NCC;
            const int grow = row0 + w * 16 + r;
            const float4 lo = *(const float4*)&cl[f];
            const float4 hi = *(const float4*)&cl[f + 4];
            uint4 o;
            o.x = pack2(lo.x, lo.y);
            o.y = pack2(lo.z, lo.w);
            o.z = pack2(hi.x, hi.y);
            o.w = pack2(hi.z, hi.w);
            if (grow < M) *(uint4*)&C[(long)grow * (NT * 16) + t0 * 16 + col] = o;
        }
    }
}

// fused: layer-0 GEMM (blocks 0..GB0-1) + phase-1 LDS histogram (blocks GB0..)
// bh[k*256 + b] = count of bucket b in chunk k. NO global atomics.
__global__ __launch_bounds__(256) void gemm0_hist1(
    const float* __restrict__ x, const short* __restrict__ Bp, short* __restrict__ C, int M,
    const int* __restrict__ dst, int* __restrict__ bh)
{
    __shared__ int cnt[256];
    if (blockIdx.x < GB0) {
        gemm_body<8, 0>(x, Bp, C, M, nullptr, nullptr, nullptr, nullptr);
    } else {
        const int k = blockIdx.x - GB0;
        cnt[threadIdx.x] = 0;
        __syncthreads();
        const int base = k * 2048;
#pragma unroll
        for (int i = 0; i < 8; ++i) {
            const int e = base + i * 256 + threadIdx.x;
            if (e < NE) atomicAdd(&cnt[(unsigned)dst[e] >> 8], 1);
        }
        __syncthreads();
        bh[k * 256 + threadIdx.x] = cnt[threadIdx.x];
    }
}

// S1: per-bucket exclusive prefix over the NBLK1 chunk-counts (in place), total -> btot
__global__ __launch_bounds__(256) void s1_k(int* __restrict__ bh, int* __restrict__ btot)
{
    __shared__ int a[512];
    const int b = blockIdx.x;       // bucket
    const int t = threadIdx.x;
    const int v0 = (t < NBLK1) ? bh[t * 256 + b] : 0;
    const int v1 = (t + 256 < NBLK1) ? bh[(t + 256) * 256 + b] : 0;
    a[t] = v0; a[256 + t] = v1;
    __syncthreads();
    for (int off = 1; off < 256; off <<= 1) {
        const int t0 = (t >= off) ? a[t - off] : 0;
        const int t1 = (t >= off) ? a[256 + t - off] : 0;
        __syncthreads();
        a[t] += t0; a[256 + t] += t1;
        __syncthreads();
    }
    const int half = a[255];
    __syncthreads();
    a[256 + t] += half;
    __syncthreads();
    bh[t * 256 + b] = a[t] - v0;
    if (t + 256 < NBLK1) bh[(t + 256) * 256 + b] = a[256 + t] - v1;
    if (t == 255) btot[b] = a[511];
}

// S2: exclusive scan of 196 bucket totals -> base[0..255] (entries >=196 == NE)
__global__ void s2_k(const int* __restrict__ btot, int* __restrict__ base)
{
    __shared__ int tmp[256];
    const int t = threadIdx.x;
    const int v = (t < NBUCK) ? btot[t] : 0;
    tmp[t] = v;
    __syncthreads();
    for (int off = 1; off < 256; off <<= 1) {
        const int x = (t >= off) ? tmp[t - off] : 0;
        __syncthreads();
        tmp[t] += x;
        __syncthreads();
    }
    base[t] = tmp[t] - v;
}

// scatter1: partition edges into bucket-contiguous staging, LDS cursors only
__global__ __launch_bounds__(256) void scatter1_k(
    const int* __restrict__ src, const int* __restrict__ dst, const float* __restrict__ ew,
    const int* __restrict__ bh, const int* __restrict__ base,
    unsigned* __restrict__ ebA, unsigned char* __restrict__ ebB)
{
    __shared__ int myoff[256];
    const int k = blockIdx.x;
    myoff[threadIdx.x] = bh[k * 256 + threadIdx.x] + base[threadIdx.x];
    __syncthreads();
    const int ebase = k * 2048;
#pragma unroll
    for (int i = 0; i < 8; ++i) {
        const int e = ebase + i * 256 + threadIdx.x;
        if (e < NE) {
            const int d = dst[e];
            const int pos = atomicAdd(&myoff[(unsigned)d >> 8], 1);
            const unsigned wb = (unsigned)__half_as_ushort(__float2half_rn(ew[e]));
            ebA[pos] = ((unsigned)src[e] & 0xFFFFu) | (wb << 16);
            ebB[pos] = (unsigned char)(d & 255);
        }
    }
}

// phase2: per bucket (256 nodes): count -> scan -> rs + final pe scatter (LDS only)
__global__ __launch_bounds__(256) void phase2_k(
    const unsigned* __restrict__ ebA, const unsigned char* __restrict__ ebB,
    const int* __restrict__ base, int* __restrict__ rs, unsigned* __restrict__ pe)
{
    __shared__ int cnt[256];
    __shared__ int cur[256];
    const int b = blockIdx.x;
    const int t = threadIdx.x;
    const int e0 = base[b], e1 = base[b + 1];
    cnt[t] = 0;
    __syncthreads();
    for (int e = e0 + t; e < e1; e += 256) atomicAdd(&cnt[ebB[e]], 1);
    __syncthreads();
    const int v = cnt[t];
    __syncthreads();
    // inclusive scan (reuse cnt)
    for (int off = 1; off < 256; off <<= 1) {
        const int x = (t >= off) ? cnt[t - off] : 0;
        __syncthreads();
        cnt[t] += x;
        __syncthreads();
    }
    const int exc = cnt[t] - v;
    const int node = b * 256 + t;
    if (node < NN) rs[node] = e0 + exc;
    if (b == 0 && t == 0) rs[NN] = NE;
    cur[t] = e0 + exc;
    __syncthreads();
    for (int e = e0 + t; e < e1; e += 256) {
        const int pos = atomicAdd(&cur[ebB[e]], 1);
        pe[pos] = ebA[e];
    }
}

template <int NT>
__global__ __launch_bounds__(256) void gemm_bn(
    const unsigned* __restrict__ A, const short* __restrict__ Bp, short* __restrict__ C, int M,
    const float* __restrict__ sum, const float* __restrict__ ss,
    const float* __restrict__ gam, const float* __restrict__ bet)
{
    gemm_body<NT, 1>(A, Bp, C, M, sum, ss, gam, bet);
}

// ================= gather aggregation (bf16 h, packed edges) =================
__global__ __launch_bounds__(256) void agg128b(
    const unsigned* __restrict__ h2, const int* __restrict__ rs,
    const unsigned* __restrict__ pe, unsigned* __restrict__ outp)
{
    const int node = blockIdx.x * 4 + (threadIdx.x >> 6);
    const int l = threadIdx.x & 63;
    int j = rs[node];
    const int j1 = rs[node + 1];
    float xs[8], ys[8];
#pragma unroll
    for (int t = 0; t < 8; ++t) { xs[t] = 0.f; ys[t] = 0.f; }
    for (; j + 7 < j1; j += 8) {
        unsigned u[8], v[8];
#pragma unroll
        for (int t = 0; t < 8; ++t) u[t] = pe[j + t];
#pragma unroll
        for (int t = 0; t < 8; ++t) v[t] = h2[(long)(u[t] & 0xFFFFu) * 64 + l];
#pragma unroll
        for (int t = 0; t < 8; ++t) {
            const float w = edgew(u[t]);
            xs[t] = fmaf(w, blo(v[t]), xs[t]);
            ys[t] = fmaf(w, bhi(v[t]), ys[t]);
        }
    }
    if (j + 3 < j1) {
        unsigned u[4], v[4];
#pragma unroll
        for (int t = 0; t < 4; ++t) u[t] = pe[j + t];
#pragma unroll
        for (int t = 0; t < 4; ++t) v[t] = h2[(long)(u[t] & 0xFFFFu) * 64 + l];
#pragma unroll
        for (int t = 0; t < 4; ++t) {
            const float w = edgew(u[t]);
            xs[t] = fmaf(w, blo(v[t]), xs[t]);
            ys[t] = fmaf(w, bhi(v[t]), ys[t]);
        }
        j += 4;
    }
    for (; j < j1; ++j) {
        const unsigned u = pe[j];
        const unsigned v = h2[(long)(u & 0xFFFFu) * 64 + l];
        const float w = edgew(u);
        xs[0] = fmaf(w, blo(v), xs[0]);
        ys[0] = fmaf(w, bhi(v), ys[0]);
    }
    const float X = ((xs[0] + xs[1]) + (xs[2] + xs[3])) + ((xs[4] + xs[5]) + (xs[6] + xs[7]));
    const float Y = ((ys[0] + ys[1]) + (ys[2] + ys[3])) + ((ys[4] + ys[5]) + (ys[6] + ys[7]));
    outp[(long)node * 64 + l] = pack2(X, Y);
}

__global__ __launch_bounds__(256) void agg32b(
    const unsigned* __restrict__ h2, const int* __restrict__ rs,
    const unsigned* __restrict__ pe, float* __restrict__ out)
{
    const int node = blockIdx.x * 16 + (threadIdx.x >> 4);
    const int l = threadIdx.x & 15;
    int j = rs[node];
    const int j1 = rs[node + 1];
    float xs[8], ys[8];
#pragma unroll
    for (int t = 0; t < 8; ++t) { xs[t] = 0.f; ys[t] = 0.f; }
    for (; j + 7 < j1; j += 8) {
        unsigned u[8], v[8];
#pragma unroll
        for (int t = 0; t < 8; ++t) u[t] = pe[j + t];
#pragma unroll
        for (int t = 0; t < 8; ++t) v[t] = h2[(long)(u[t] & 0xFFFFu) * 16 + l];
#pragma unroll
        for (int t = 0; t < 8; ++t) {
            const float w = edgew(u[t]);
            xs[t] = fmaf(w, blo(v[t]), xs[t]);
            ys[t] = fmaf(w, bhi(v[t]), ys[t]);
        }
    }
    if (j + 3 < j1) {
        unsigned u[4], v[4];
#pragma unroll
        for (int t = 0; t < 4; ++t) u[t] = pe[j + t];
#pragma unroll
        for (int t = 0; t < 4; ++t) v[t] = h2[(long)(u[t] & 0xFFFFu) * 16 + l];
#pragma unroll
        for (int t = 0; t < 4; ++t) {
            const float w = edgew(u[t]);
            xs[t] = fmaf(w, blo(v[t]), xs[t]);
            ys[t] = fmaf(w, bhi(v[t]), ys[t]);
        }
        j += 4;
    }
    for (; j < j1; ++j) {
        const unsigned u = pe[j];
        const unsigned v = h2[(long)(u & 0xFFFFu) * 16 + l];
        const float w = edgew(u);
        xs[0] = fmaf(w, blo(v), xs[0]);
        ys[0] = fmaf(w, bhi(v), ys[0]);
    }
    float2 o;
    o.x = ((xs[0] + xs[1]) + (xs[2] + xs[3])) + ((xs[4] + xs[5]) + (xs[6] + xs[7]));
    o.y = ((ys[0] + ys[1]) + (ys[2] + ys[3])) + ((ys[4] + ys[5]) + (ys[6] + ys[7]));
    *(float2*)&out[(long)node * 32 + 2 * l] = o;
}

// ================= BN stats (pre rows = 64 uints) =================
__global__ __launch_bounds__(256) void bn_stats_b(
    const unsigned* __restrict__ pre, float* __restrict__ sum, float* __restrict__ ss, int M)
{
    const int c2 = threadIdx.x & 63;
    const int g = threadIdx.x >> 6;
    float s0 = 0.f, s1 = 0.f, q0 = 0.f, q1 = 0.f;
    for (int row = blockIdx.x * 4 + g; row < M; row += gridDim.x * 4) {
        const unsigned v = pre[(long)row * 64 + c2];
        const float lo = blo(v), hi = bhi(v);
        s0 += lo; s1 += hi;
        q0 = fmaf(lo, lo, q0); q1 = fmaf(hi, hi, q1);
    }
    __shared__ float A0[256], A1[256], B0[256], B1[256];
    A0[threadIdx.x] = s0; A1[threadIdx.x] = s1;
    B0[threadIdx.x] = q0; B1[threadIdx.x] = q1;
    __syncthreads();
    if (threadIdx.x < 64) {
        const int t = threadIdx.x;
        atomicAdd(&sum[2 * t],     A0[t] + A0[t + 64] + A0[t + 128] + A0[t + 192]);
        atomicAdd(&sum[2 * t + 1], A1[t] + A1[t + 64] + A1[t + 128] + A1[t + 192]);
        atomicAdd(&ss[2 * t],      B0[t] + B0[t + 64] + B0[t + 128] + B0[t + 192]);
        atomicAdd(&ss[2 * t + 1],  B1[t] + B1[t + 64] + B1[t + 128] + B1[t + 192]);
    }
}

extern "C" void kernel_launch(void* const* d_in, const int* in_sizes, int n_in,
                              void* d_out, int out_size, void* d_ws, size_t ws_size,
                              hipStream_t stream) {
    const float* x   = (const float*)d_in[0];
    const int*   src = (const int*)d_in[1];
    const int*   dst = (const int*)d_in[2];
    const float* ew  = (const float*)d_in[3];
    const float* W0  = (const float*)d_in[4];
    const float* W1  = (const float*)d_in[5];
    const float* W2  = (const float*)d_in[6];
    const float* g0  = (const float*)d_in[7];
    const float* b0  = (const float*)d_in[8];
    const float* g1  = (const float*)d_in[9];
    const float* b1  = (const float*)d_in[10];
    float* out = (float*)d_out;

    // workspace layout
    short* h   = (short*)d_ws;                         // [NN*128] bf16
    unsigned* x1p = (unsigned*)(h + (size_t)NN * 128); // [NN*64] uints = pre-only bf16x2
    float* st  = (float*)(x1p + (size_t)NN * 64);      // 1024 floats
    int*  rs   = (int*)(st + 1024);                    // 50004
    int*  bh   = rs + 50004;                           // NBLK1*256 = 100096
    int*  btot = bh + NBLK1 * 256;                     // 256
    int*  base = btot + 256;                           // 260
    unsigned* ebA = (unsigned*)(base + 260);           // NE staged src|w
    unsigned char* ebB = (unsigned char*)(ebA + NE);   // NE dst low bytes
    unsigned* pe = (unsigned*)(ebB + ((NE + 255) & ~255)); // NE final packed edges
    short* Bp0 = (short*)(pe + NE);                    // 32768
    short* Bp1 = Bp0 + 32768;                          // 32768
    short* Bp2 = Bp1 + 32768;                          // 8192

    float* sum0 = st,       *ss0 = st + 128;
    float* sum1 = st + 512, *ss1 = st + 640;

    hipMemsetAsync(st, 0, 1024 * 4, stream);

    packb_all<<<288, 256, 0, stream>>>(W0, W1, W2, Bp0, Bp1, Bp2);

    // layer-0 GEMM + phase-1 histogram (no global atomics anywhere below)
    gemm0_hist1<<<GB0 + NBLK1, 256, 0, stream>>>(x, Bp0, h, NN, dst, bh);

    s1_k<<<NBUCK, 256, 0, stream>>>(bh, btot);
    s2_k<<<1, 256, 0, stream>>>(btot, base);
    scatter1_k<<<NBLK1, 256, 0, stream>>>(src, dst, ew, bh, base, ebA, ebB);
    phase2_k<<<NBUCK, 256, 0, stream>>>(ebA, ebB, base, rs, pe);

    // ---- layer 0 aggregation + stats ----
    agg128b<<<12500, 256, 0, stream>>>((const unsigned*)h, rs, pe, x1p);
    bn_stats_b<<<256, 256, 0, stream>>>(x1p, sum0, ss0, NN);

    // ---- layer 1 (BN0+ReLU fused into fragment load) ----
    gemm_bn<8><<<782, 256, 0, stream>>>(x1p, Bp1, h, NN, sum0, ss0, g0, b0);
    agg128b<<<12500, 256, 0, stream>>>((const unsigned*)h, rs, pe, x1p);
    bn_stats_b<<<256, 256, 0, stream>>>(x1p, sum1, ss1, NN);

    // ---- output layer (BN1+ReLU fused into fragment load) ----
    gemm_bn<2><<<782, 256, 0, stream>>>(x1p, Bp2, h, NN, sum1, ss1, g1, b1);
    agg32b<<<3125, 256, 0, stream>>>((const unsigned*)h, rs, pe, out);
}

// Round 9
// 299.560 us; speedup vs baseline: 11.0984x; 1.0278x over previous
//
#include <hip/hip_runtime.h>
#include <hip/hip_fp16.h>

#define NN 50000
#define NE 800000
#define GB0 782       // gemm blocks in fused gemm0+hist1
#define NBLK1 391     // phase-1 blocks, 2048 edges each
#define NBUCK 196     // coarse buckets = dst>>8

typedef __attribute__((ext_vector_type(8))) short bf16x8;
typedef __attribute__((ext_vector_type(4))) float f32x4;

__device__ inline float blo(unsigned u) { union { unsigned i; float f; } c; c.i = u << 16; return c.f; }
__device__ inline float bhi(unsigned u) { union { unsigned i; float f; } c; c.i = u & 0xFFFF0000u; return c.f; }
__device__ inline unsigned short f2b(float f) {
    union { float f; unsigned u; } c; c.f = f;
    return (unsigned short)((c.u + 0x7FFFu + ((c.u >> 16) & 1u)) >> 16);
}
__device__ inline unsigned pack2(float x, float y) {
    union { float f; unsigned u; } a, b; a.f = x; b.f = y;
    const unsigned lo = (a.u + 0x7FFFu + ((a.u >> 16) & 1u)) >> 16;
    const unsigned hi = (b.u + 0x7FFFu + ((b.u >> 16) & 1u)) & 0xFFFF0000u;
    return (lo & 0xFFFFu) | hi;
}
__device__ inline float edgew(unsigned u) {
    return __half2float(__ushort_as_half((unsigned short)(u >> 16)));
}
__device__ inline bf16x8 u4_to_b8(unsigned a, unsigned b, unsigned c, unsigned d) {
    union { unsigned u[4]; bf16x8 v; } x;
    x.u[0] = a; x.u[1] = b; x.u[2] = c; x.u[3] = d;
    return x.v;
}

// ================= weight packing =================
__device__ __forceinline__ void packb_body(const float* __restrict__ B, short* __restrict__ Bp, int NT, int b)
{
    const int o = b * 256 + threadIdx.x;
    if (o >= 4096 * NT) return;
    const int j = o & 7;
    const int lane = (o >> 3) & 63;
    const int tnt = o >> 9;
    const int nt = tnt % NT, ks = tnt / NT;
    const int k = ks * 32 + (lane >> 4) * 8 + j;
    const int n = nt * 16 + (lane & 15);
    Bp[o] = (short)f2b(B[k * (NT * 16) + n]);
}

__global__ __launch_bounds__(256) void packb0_k(const float* __restrict__ W0, short* __restrict__ Bp0)
{
    packb_body(W0, Bp0, 8, blockIdx.x);
}

// ================= MFMA GEMM body — LDS-free A-fragment loads =================
template <int NT, int MODE>
__device__ __forceinline__ void gemm_body(
    const void* __restrict__ Av, const short* __restrict__ Bp,
    short* __restrict__ C, int M,
    const float* __restrict__ sum, const float* __restrict__ ss,
    const float* __restrict__ gam, const float* __restrict__ bet)
{
    constexpr int TC = (NT > 4) ? 4 : NT;
    constexpr int NCC = TC * 16;
    __shared__ float Cl[4][16 * NCC];
    __shared__ float scs[128], shs[128];
    const int tid = threadIdx.x;
    const int w = tid >> 6;
    const int lane = tid & 63;
    const int lane15 = lane & 15;
    const int quad = lane >> 4;
    const int row0 = blockIdx.x * 64;
    const int m = row0 + w * 16 + lane15;
    const int mc = (m < M) ? m : 0;

    if (MODE == 1) {
        if (tid < 128) {
            const float inv = 1.f / (float)M;
            const float mu = sum[tid] * inv;
            const float var = ss[tid] * inv - mu * mu;
            const float s = gam[tid] * rsqrtf(var + 1e-5f);
            scs[tid] = s;
            shs[tid] = bet[tid] - mu * s;
        }
        __syncthreads();
    }

    f32x4 acc[NT];
#pragma unroll
    for (int t = 0; t < NT; ++t) acc[t] = (f32x4){0.f, 0.f, 0.f, 0.f};

    if (MODE == 0) {
        const float* arow = (const float*)Av + (long)mc * 256;
#pragma unroll
        for (int ks = 0; ks < 8; ++ks) {
            const float4 v0 = *(const float4*)&arow[ks * 32 + quad * 8];
            const float4 v1 = *(const float4*)&arow[ks * 32 + quad * 8 + 4];
            const bf16x8 af = u4_to_b8(pack2(v0.x, v0.y), pack2(v0.z, v0.w),
                                       pack2(v1.x, v1.y), pack2(v1.z, v1.w));
#pragma unroll
            for (int t = 0; t < NT; ++t) {
                const bf16x8 bf = *(const bf16x8*)&Bp[(((ks * NT + t) * 64) + lane) * 8];
                acc[t] = __builtin_amdgcn_mfma_f32_16x16x32_bf16(af, bf, acc[t], 0, 0, 0);
            }
        }
    } else {
        const unsigned* arow = (const unsigned*)Av + (long)mc * 64;
#pragma unroll
        for (int ks = 0; ks < 4; ++ks) {
            const uint4 pv = *(const uint4*)&arow[ks * 16 + quad * 4];
            const bf16x8 apre = u4_to_b8(pv.x, pv.y, pv.z, pv.w);
            const int c0 = ks * 32 + quad * 8;
            const float4 s0 = *(const float4*)&scs[c0];
            const float4 s1 = *(const float4*)&scs[c0 + 4];
            const float4 h0 = *(const float4*)&shs[c0];
            const float4 h1 = *(const float4*)&shs[c0 + 4];
            const bf16x8 aact = u4_to_b8(
                pack2(fmaxf(fmaf(blo(pv.x), s0.x, h0.x), 0.f), fmaxf(fmaf(bhi(pv.x), s0.y, h0.y), 0.f)),
                pack2(fmaxf(fmaf(blo(pv.y), s0.z, h0.z), 0.f), fmaxf(fmaf(bhi(pv.y), s0.w, h0.w), 0.f)),
                pack2(fmaxf(fmaf(blo(pv.z), s1.x, h1.x), 0.f), fmaxf(fmaf(bhi(pv.z), s1.y, h1.y), 0.f)),
                pack2(fmaxf(fmaf(blo(pv.w), s1.z, h1.z), 0.f), fmaxf(fmaf(bhi(pv.w), s1.w, h1.w), 0.f)));
#pragma unroll
            for (int t = 0; t < NT; ++t) {
                const bf16x8 bf = *(const bf16x8*)&Bp[(((ks * NT + t) * 64) + lane) * 8];
                acc[t] = __builtin_amdgcn_mfma_f32_16x16x32_bf16(aact, bf, acc[t], 0, 0, 0);
            }
#pragma unroll
            for (int t = 0; t < NT; ++t) {
                const bf16x8 bf = *(const bf16x8*)&Bp[((((ks + 4) * NT + t) * 64) + lane) * 8];
                acc[t] = __builtin_amdgcn_mfma_f32_16x16x32_bf16(apre, bf, acc[t], 0, 0, 0);
            }
        }
    }

    float* cl = Cl[w];
#pragma unroll
    for (int t0 = 0; t0 < NT; t0 += TC) {
#pragma unroll
        for (int tt = 0; tt < TC; ++tt)
#pragma unroll
            for (int r = 0; r < 4; ++r)
                cl[(quad * 4 + r) * NCC + tt * 16 + lane15] = acc[t0 + tt][r];
#pragma unroll
        for (int i = 0; i < (16 * NCC) / 512; ++i) {
            const int f = i * 512 + lane * 8;
            const int r = f / NCC;
            const int col = f % NCC;
            const int grow = row0 + w * 16 + r;
            const float4 lo = *(const float4*)&cl[f];
            const float4 hi = *(const float4*)&cl[f + 4];
            uint4 o;
            o.x = pack2(lo.x, lo.y);
            o.y = pack2(lo.z, lo.w);
            o.z = pack2(hi.x, hi.y);
            o.w = pack2(hi.z, hi.w);
            if (grow < M) *(uint4*)&C[(long)grow * (NT * 16) + t0 * 16 + col] = o;
        }
    }
}

// fused: layer-0 GEMM + phase-1 LDS histogram + W1/W2 packing
__global__ __launch_bounds__(256) void gemm0_hist1(
    const float* __restrict__ x, const short* __restrict__ Bp, short* __restrict__ C, int M,
    const int* __restrict__ dst, int* __restrict__ bh,
    const float* __restrict__ W1, const float* __restrict__ W2,
    short* __restrict__ Bp1, short* __restrict__ Bp2)
{
    __shared__ int cnt[256];
    if (blockIdx.x < GB0) {
        gemm_body<8, 0>(x, Bp, C, M, nullptr, nullptr, nullptr, nullptr);
    } else if (blockIdx.x < GB0 + NBLK1) {
        const int k = blockIdx.x - GB0;
        cnt[threadIdx.x] = 0;
        __syncthreads();
        const int base = k * 2048;
#pragma unroll
        for (int i = 0; i < 8; ++i) {
            const int e = base + i * 256 + threadIdx.x;
            if (e < NE) atomicAdd(&cnt[(unsigned)dst[e] >> 8], 1);
        }
        __syncthreads();
        bh[k * 256 + threadIdx.x] = cnt[threadIdx.x];
    } else if (blockIdx.x < GB0 + NBLK1 + 128) {
        packb_body(W1, Bp1, 8, blockIdx.x - (GB0 + NBLK1));
    } else {
        packb_body(W2, Bp2, 2, blockIdx.x - (GB0 + NBLK1 + 128));
    }
}

// S1: per-bucket exclusive prefix over the NBLK1 chunk-counts (in place), total -> btot
__global__ __launch_bounds__(256) void s1_k(int* __restrict__ bh, int* __restrict__ btot)
{
    __shared__ int a[512];
    const int b = blockIdx.x;
    const int t = threadIdx.x;
    const int v0 = (t < NBLK1) ? bh[t * 256 + b] : 0;
    const int v1 = (t + 256 < NBLK1) ? bh[(t + 256) * 256 + b] : 0;
    a[t] = v0; a[256 + t] = v1;
    __syncthreads();
    for (int off = 1; off < 256; off <<= 1) {
        const int t0 = (t >= off) ? a[t - off] : 0;
        const int t1 = (t >= off) ? a[256 + t - off] : 0;
        __syncthreads();
        a[t] += t0; a[256 + t] += t1;
        __syncthreads();
    }
    const int half = a[255];
    __syncthreads();
    a[256 + t] += half;
    __syncthreads();
    bh[t * 256 + b] = a[t] - v0;
    if (t + 256 < NBLK1) bh[(t + 256) * 256 + b] = a[256 + t] - v1;
    if (t == 255) btot[b] = a[511];
}

// scatter1: partition into bucket-contiguous staging; base computed by LDS scan of btot
__global__ __launch_bounds__(256) void scatter1_k(
    const int* __restrict__ src, const int* __restrict__ dst, const float* __restrict__ ew,
    const int* __restrict__ bh, const int* __restrict__ btot,
    unsigned* __restrict__ ebA, unsigned char* __restrict__ ebB)
{
    __shared__ int tmp[256];
    __shared__ int myoff[256];
    const int k = blockIdx.x;
    const int t = threadIdx.x;
    const int v = (t < NBUCK) ? btot[t] : 0;
    tmp[t] = v;
    __syncthreads();
    for (int off = 1; off < 256; off <<= 1) {
        const int x = (t >= off) ? tmp[t - off] : 0;
        __syncthreads();
        tmp[t] += x;
        __syncthreads();
    }
    myoff[t] = bh[k * 256 + t] + (tmp[t] - v);
    __syncthreads();
    const int ebase = k * 2048;
#pragma unroll
    for (int i = 0; i < 8; ++i) {
        const int e = ebase + i * 256 + t;
        if (e < NE) {
            const int d = dst[e];
            const int pos = atomicAdd(&myoff[(unsigned)d >> 8], 1);
            const unsigned wb = (unsigned)__half_as_ushort(__float2half_rn(ew[e]));
            ebA[pos] = ((unsigned)src[e] & 0xFFFFu) | (wb << 16);
            ebB[pos] = (unsigned char)(d & 255);
        }
    }
}

// phase2: per bucket: count -> scan -> rs + final pe scatter (LDS only)
__global__ __launch_bounds__(256) void phase2_k(
    const unsigned* __restrict__ ebA, const unsigned char* __restrict__ ebB,
    const int* __restrict__ btot, int* __restrict__ rs, unsigned* __restrict__ pe)
{
    __shared__ int bscan[256];
    __shared__ int cnt[256];
    __shared__ int cur[256];
    const int b = blockIdx.x;
    const int t = threadIdx.x;
    const int v0 = (t < NBUCK) ? btot[t] : 0;
    bscan[t] = v0;
    __syncthreads();
    for (int off = 1; off < 256; off <<= 1) {
        const int x = (t >= off) ? bscan[t - off] : 0;
        __syncthreads();
        bscan[t] += x;
        __syncthreads();
    }
    const int e1 = bscan[b];
    const int e0 = e1 - btot[b];
    cnt[t] = 0;
    __syncthreads();
    for (int e = e0 + t; e < e1; e += 256) atomicAdd(&cnt[ebB[e]], 1);
    __syncthreads();
    const int v = cnt[t];
    __syncthreads();
    for (int off = 1; off < 256; off <<= 1) {
        const int x = (t >= off) ? cnt[t - off] : 0;
        __syncthreads();
        cnt[t] += x;
        __syncthreads();
    }
    const int exc = cnt[t] - v;
    const int node = b * 256 + t;
    if (node < NN) rs[node] = e0 + exc;
    if (b == 0 && t == 0) rs[NN] = NE;
    cur[t] = e0 + exc;
    __syncthreads();
    for (int e = e0 + t; e < e1; e += 256) {
        const int pos = atomicAdd(&cur[ebB[e]], 1);
        pe[pos] = ebA[e];
    }
}

template <int NT>
__global__ __launch_bounds__(256) void gemm_bn(
    const unsigned* __restrict__ A, const short* __restrict__ Bp, short* __restrict__ C, int M,
    const float* __restrict__ sum, const float* __restrict__ ss,
    const float* __restrict__ gam, const float* __restrict__ bet)
{
    gemm_body<NT, 1>(A, Bp, C, M, sum, ss, gam, bet);
}

// ================= gather aggregation: 2 nodes/wave, 32 lanes/node, uint2 gathers =================
__global__ __launch_bounds__(256) void agg128b(
    const unsigned* __restrict__ h2, const int* __restrict__ rs,
    const unsigned* __restrict__ pe, unsigned* __restrict__ outp)
{
    const int node = blockIdx.x * 8 + (threadIdx.x >> 5);
    const int l = threadIdx.x & 31;
    int j = rs[node];
    const int j1 = rs[node + 1];
    const uint2* hp = (const uint2*)h2;   // rows of 32 uint2
    float xa[4], ya[4], xb[4], yb[4];
#pragma unroll
    for (int t = 0; t < 4; ++t) { xa[t] = 0.f; ya[t] = 0.f; xb[t] = 0.f; yb[t] = 0.f; }
    for (; j + 7 < j1; j += 8) {
        unsigned u[8]; uint2 v[8];
#pragma unroll
        for (int t = 0; t < 8; ++t) u[t] = pe[j + t];
#pragma unroll
        for (int t = 0; t < 8; ++t) v[t] = hp[(long)(u[t] & 0xFFFFu) * 32 + l];
#pragma unroll
        for (int t = 0; t < 8; ++t) {
            const float w = edgew(u[t]);
            xa[t & 3] = fmaf(w, blo(v[t].x), xa[t & 3]);
            ya[t & 3] = fmaf(w, bhi(v[t].x), ya[t & 3]);
            xb[t & 3] = fmaf(w, blo(v[t].y), xb[t & 3]);
            yb[t & 3] = fmaf(w, bhi(v[t].y), yb[t & 3]);
        }
    }
    for (; j < j1; ++j) {
        const unsigned u = pe[j];
        const uint2 v = hp[(long)(u & 0xFFFFu) * 32 + l];
        const float w = edgew(u);
        xa[0] = fmaf(w, blo(v.x), xa[0]); ya[0] = fmaf(w, bhi(v.x), ya[0]);
        xb[0] = fmaf(w, blo(v.y), xb[0]); yb[0] = fmaf(w, bhi(v.y), yb[0]);
    }
    uint2 o;
    o.x = pack2((xa[0] + xa[1]) + (xa[2] + xa[3]), (ya[0] + ya[1]) + (ya[2] + ya[3]));
    o.y = pack2((xb[0] + xb[1]) + (xb[2] + xb[3]), (yb[0] + yb[1]) + (yb[2] + yb[3]));
    ((uint2*)outp)[(long)node * 32 + l] = o;
}

// 8 lanes/node, uint2 gathers, float4 fp32 output [NN,32]
__global__ __launch_bounds__(256) void agg32b(
    const unsigned* __restrict__ h2, const int* __restrict__ rs,
    const unsigned* __restrict__ pe, float* __restrict__ out)
{
    const int node = blockIdx.x * 32 + (threadIdx.x >> 3);
    if (node >= NN) return;
    const int l = threadIdx.x & 7;
    int j = rs[node];
    const int j1 = rs[node + 1];
    const uint2* hp = (const uint2*)h2;   // rows of 8 uint2
    float xa[4], ya[4], xb[4], yb[4];
#pragma unroll
    for (int t = 0; t < 4; ++t) { xa[t] = 0.f; ya[t] = 0.f; xb[t] = 0.f; yb[t] = 0.f; }
    for (; j + 7 < j1; j += 8) {
        unsigned u[8]; uint2 v[8];
#pragma unroll
        for (int t = 0; t < 8; ++t) u[t] = pe[j + t];
#pragma unroll
        for (int t = 0; t < 8; ++t) v[t] = hp[(long)(u[t] & 0xFFFFu) * 8 + l];
#pragma unroll
        for (int t = 0; t < 8; ++t) {
            const float w = edgew(u[t]);
            xa[t & 3] = fmaf(w, blo(v[t].x), xa[t & 3]);
            ya[t & 3] = fmaf(w, bhi(v[t].x), ya[t & 3]);
            xb[t & 3] = fmaf(w, blo(v[t].y), xb[t & 3]);
            yb[t & 3] = fmaf(w, bhi(v[t].y), yb[t & 3]);
        }
    }
    for (; j < j1; ++j) {
        const unsigned u = pe[j];
        const uint2 v = hp[(long)(u & 0xFFFFu) * 8 + l];
        const float w = edgew(u);
        xa[0] = fmaf(w, blo(v.x), xa[0]); ya[0] = fmaf(w, bhi(v.x), ya[0]);
        xb[0] = fmaf(w, blo(v.y), xb[0]); yb[0] = fmaf(w, bhi(v.y), yb[0]);
    }
    float4 o;
    o.x = (xa[0] + xa[1]) + (xa[2] + xa[3]);
    o.y = (ya[0] + ya[1]) + (ya[2] + ya[3]);
    o.z = (xb[0] + xb[1]) + (xb[2] + xb[3]);
    o.w = (yb[0] + yb[1]) + (yb[2] + yb[3]);
    ((float4*)out)[(long)node * 8 + l] = o;
}

// ================= BN stats (pre rows = 64 uints), row-pair unrolled =================
__global__ __launch_bounds__(256) void bn_stats_b(
    const unsigned* __restrict__ pre, float* __restrict__ sum, float* __restrict__ ss, int M)
{
    const int c2 = threadIdx.x & 63;
    const int g = threadIdx.x >> 6;
    float s0 = 0.f, s1 = 0.f, q0 = 0.f, q1 = 0.f;
    float s2 = 0.f, s3 = 0.f, q2 = 0.f, q3 = 0.f;
    for (int row = blockIdx.x * 8 + g * 2; row < M; row += gridDim.x * 8) {
        const unsigned v = pre[(long)row * 64 + c2];
        const unsigned v2 = pre[(long)(row + 1) * 64 + c2];   // M even: row+1 < M
        const float lo = blo(v), hi = bhi(v);
        const float lo2 = blo(v2), hi2 = bhi(v2);
        s0 += lo; s1 += hi;
        q0 = fmaf(lo, lo, q0); q1 = fmaf(hi, hi, q1);
        s2 += lo2; s3 += hi2;
        q2 = fmaf(lo2, lo2, q2); q3 = fmaf(hi2, hi2, q3);
    }
    s0 += s2; s1 += s3; q0 += q2; q1 += q3;
    __shared__ float A0[256], A1[256], B0[256], B1[256];
    A0[threadIdx.x] = s0; A1[threadIdx.x] = s1;
    B0[threadIdx.x] = q0; B1[threadIdx.x] = q1;
    __syncthreads();
    if (threadIdx.x < 64) {
        const int t = threadIdx.x;
        atomicAdd(&sum[2 * t],     A0[t] + A0[t + 64] + A0[t + 128] + A0[t + 192]);
        atomicAdd(&sum[2 * t + 1], A1[t] + A1[t + 64] + A1[t + 128] + A1[t + 192]);
        atomicAdd(&ss[2 * t],      B0[t] + B0[t + 64] + B0[t + 128] + B0[t + 192]);
        atomicAdd(&ss[2 * t + 1],  B1[t] + B1[t + 64] + B1[t + 128] + B1[t + 192]);
    }
}

extern "C" void kernel_launch(void* const* d_in, const int* in_sizes, int n_in,
                              void* d_out, int out_size, void* d_ws, size_t ws_size,
                              hipStream_t stream) {
    const float* x   = (const float*)d_in[0];
    const int*   src = (const int*)d_in[1];
    const int*   dst = (const int*)d_in[2];
    const float* ew  = (const float*)d_in[3];
    const float* W0  = (const float*)d_in[4];
    const float* W1  = (const float*)d_in[5];
    const float* W2  = (const float*)d_in[6];
    const float* g0  = (const float*)d_in[7];
    const float* b0  = (const float*)d_in[8];
    const float* g1  = (const float*)d_in[9];
    const float* b1  = (const float*)d_in[10];
    float* out = (float*)d_out;

    // workspace layout
    short* h   = (short*)d_ws;                         // [NN*128] bf16
    unsigned* x1p = (unsigned*)(h + (size_t)NN * 128); // [NN*64] uints = pre-only bf16x2
    float* st  = (float*)(x1p + (size_t)NN * 64);      // 1024 floats
    int*  rs   = (int*)(st + 1024);                    // 50004
    int*  bh   = rs + 50004;                           // NBLK1*256
    int*  btot = bh + NBLK1 * 256;                     // 256
    unsigned* ebA = (unsigned*)(btot + 256);           // NE staged src|w
    unsigned char* ebB = (unsigned char*)(ebA + NE);   // NE dst low bytes
    unsigned* pe = (unsigned*)(ebB + ((NE + 255) & ~255)); // NE final packed edges
    short* Bp0 = (short*)(pe + NE);                    // 32768
    short* Bp1 = Bp0 + 32768;                          // 32768
    short* Bp2 = Bp1 + 32768;                          // 8192

    float* sum0 = st,       *ss0 = st + 128;
    float* sum1 = st + 512, *ss1 = st + 640;

    hipMemsetAsync(st, 0, 1024 * 4, stream);

    packb0_k<<<128, 256, 0, stream>>>(W0, Bp0);

    // layer-0 GEMM + phase-1 histogram + W1/W2 packing (one launch)
    gemm0_hist1<<<GB0 + NBLK1 + 160, 256, 0, stream>>>(x, Bp0, h, NN, dst, bh, W1, W2, Bp1, Bp2);

    s1_k<<<NBUCK, 256, 0, stream>>>(bh, btot);
    scatter1_k<<<NBLK1, 256, 0, stream>>>(src, dst, ew, bh, btot, ebA, ebB);
    phase2_k<<<NBUCK, 256, 0, stream>>>(ebA, ebB, btot, rs, pe);

    // ---- layer 0 aggregation + stats ----
    agg128b<<<6250, 256, 0, stream>>>((const unsigned*)h, rs, pe, x1p);
    bn_stats_b<<<256, 256, 0, stream>>>(x1p, sum0, ss0, NN);

    // ---- layer 1 (BN0+ReLU fused into fragment load) ----
    gemm_bn<8><<<782, 256, 0, stream>>>(x1p, Bp1, h, NN, sum0, ss0, g0, b0);
    agg128b<<<6250, 256, 0, stream>>>((const unsigned*)h, rs, pe, x1p);
    bn_stats_b<<<256, 256, 0, stream>>>(x1p, sum1, ss1, NN);

    // ---- output layer (BN1+ReLU fused into fragment load) ----
    gemm_bn<2><<<782, 256, 0, stream>>>(x1p, Bp2, h, NN, sum1, ss1, g1, b1);
    agg32b<<<1563, 256, 0, stream>>>((const unsigned*)h, rs, pe, out);
}

// Round 11
// 288.615 us; speedup vs baseline: 11.5193x; 1.0379x over previous
//
#include <hip/hip_runtime.h>
#include <hip/hip_fp16.h>

#define NN 50000
#define NE 800000
#define GB0 782       // gemm blocks in fused gemm0+hist1
#define NBLK1 391     // phase-1 blocks, 2048 edges each
#define NBUCK 196     // coarse buckets = dst>>8

typedef __attribute__((ext_vector_type(8))) short bf16x8;
typedef __attribute__((ext_vector_type(4))) float f32x4;
typedef __attribute__((ext_vector_type(2))) float f32x2;

__device__ inline float blo(unsigned u) { union { unsigned i; float f; } c; c.i = u << 16; return c.f; }
__device__ inline float bhi(unsigned u) { union { unsigned i; float f; } c; c.i = u & 0xFFFF0000u; return c.f; }
__device__ inline unsigned short f2b(float f) {
    union { float f; unsigned u; } c; c.f = f;
    return (unsigned short)((c.u + 0x7FFFu + ((c.u >> 16) & 1u)) >> 16);
}
__device__ inline unsigned pack2(float x, float y) {
    union { float f; unsigned u; } a, b; a.f = x; b.f = y;
    const unsigned lo = (a.u + 0x7FFFu + ((a.u >> 16) & 1u)) >> 16;
    const unsigned hi = (b.u + 0x7FFFu + ((b.u >> 16) & 1u)) & 0xFFFF0000u;
    return (lo & 0xFFFFu) | hi;
}
__device__ inline float edgew(unsigned u) {
    return __half2float(__ushort_as_half((unsigned short)(u >> 16)));
}
__device__ inline bf16x8 u4_to_b8(unsigned a, unsigned b, unsigned c, unsigned d) {
    union { unsigned u[4]; bf16x8 v; } x;
    x.u[0] = a; x.u[1] = b; x.u[2] = c; x.u[3] = d;
    return x.v;
}
// pack 4 fp32 -> 4 fp8 e4m3 (one uint)
__device__ inline unsigned pk_fp8x4(float a, float b, float c, float d) {
    int t = 0;
    t = __builtin_amdgcn_cvt_pk_fp8_f32(a, b, t, false);
    t = __builtin_amdgcn_cvt_pk_fp8_f32(c, d, t, true);
    return (unsigned)t;
}

// ================= weight packing =================
__device__ __forceinline__ void packb_body(const float* __restrict__ B, short* __restrict__ Bp, int NT, int b)
{
    const int o = b * 256 + threadIdx.x;
    if (o >= 4096 * NT) return;
    const int j = o & 7;
    const int lane = (o >> 3) & 63;
    const int tnt = o >> 9;
    const int nt = tnt % NT, ks = tnt / NT;
    const int k = ks * 32 + (lane >> 4) * 8 + j;
    const int n = nt * 16 + (lane & 15);
    Bp[o] = (short)f2b(B[k * (NT * 16) + n]);
}

__global__ __launch_bounds__(256) void packb0_k(const float* __restrict__ W0, short* __restrict__ Bp0)
{
    packb_body(W0, Bp0, 8, blockIdx.x);
}

// ================= MFMA GEMM body — LDS-free A-fragment loads =================
// MODE 0: A = fp32 [M,256]; MODE 1: A = x1p pre-only [M,64] uints (frag used twice)
// FP8OUT: C is fp8 e4m3 [M, NT*16] bytes; else bf16 [M, NT*16] shorts
template <int NT, int MODE, bool FP8OUT>
__device__ __forceinline__ void gemm_body(
    const void* __restrict__ Av, const short* __restrict__ Bp,
    void* __restrict__ Cv, int M,
    const float* __restrict__ sum, const float* __restrict__ ss,
    const float* __restrict__ gam, const float* __restrict__ bet)
{
    constexpr int TC = (NT > 4) ? 4 : NT;
    constexpr int NCC = TC * 16;
    __shared__ float Cl[4][16 * NCC];
    __shared__ float scs[128], shs[128];
    const int tid = threadIdx.x;
    const int w = tid >> 6;
    const int lane = tid & 63;
    const int lane15 = lane & 15;
    const int quad = lane >> 4;
    const int row0 = blockIdx.x * 64;
    const int m = row0 + w * 16 + lane15;
    const int mc = (m < M) ? m : 0;

    if (MODE == 1) {
        if (tid < 128) {
            const float inv = 1.f / (float)M;
            const float mu = sum[tid] * inv;
            const float var = ss[tid] * inv - mu * mu;
            const float s = gam[tid] * rsqrtf(var + 1e-5f);
            scs[tid] = s;
            shs[tid] = bet[tid] - mu * s;
        }
        __syncthreads();
    }

    f32x4 acc[NT];
#pragma unroll
    for (int t = 0; t < NT; ++t) acc[t] = (f32x4){0.f, 0.f, 0.f, 0.f};

    if (MODE == 0) {
        const float* arow = (const float*)Av + (long)mc * 256;
#pragma unroll
        for (int ks = 0; ks < 8; ++ks) {
            const float4 v0 = *(const float4*)&arow[ks * 32 + quad * 8];
            const float4 v1 = *(const float4*)&arow[ks * 32 + quad * 8 + 4];
            const bf16x8 af = u4_to_b8(pack2(v0.x, v0.y), pack2(v0.z, v0.w),
                                       pack2(v1.x, v1.y), pack2(v1.z, v1.w));
#pragma unroll
            for (int t = 0; t < NT; ++t) {
                const bf16x8 bf = *(const bf16x8*)&Bp[(((ks * NT + t) * 64) + lane) * 8];
                acc[t] = __builtin_amdgcn_mfma_f32_16x16x32_bf16(af, bf, acc[t], 0, 0, 0);
            }
        }
    } else {
        const unsigned* arow = (const unsigned*)Av + (long)mc * 64;
#pragma unroll
        for (int ks = 0; ks < 4; ++ks) {
            const uint4 pv = *(const uint4*)&arow[ks * 16 + quad * 4];
            const bf16x8 apre = u4_to_b8(pv.x, pv.y, pv.z, pv.w);
            const int c0 = ks * 32 + quad * 8;
            const float4 s0 = *(const float4*)&scs[c0];
            const float4 s1 = *(const float4*)&scs[c0 + 4];
            const float4 h0 = *(const float4*)&shs[c0];
            const float4 h1 = *(const float4*)&shs[c0 + 4];
            const bf16x8 aact = u4_to_b8(
                pack2(fmaxf(fmaf(blo(pv.x), s0.x, h0.x), 0.f), fmaxf(fmaf(bhi(pv.x), s0.y, h0.y), 0.f)),
                pack2(fmaxf(fmaf(blo(pv.y), s0.z, h0.z), 0.f), fmaxf(fmaf(bhi(pv.y), s0.w, h0.w), 0.f)),
                pack2(fmaxf(fmaf(blo(pv.z), s1.x, h1.x), 0.f), fmaxf(fmaf(bhi(pv.z), s1.y, h1.y), 0.f)),
                pack2(fmaxf(fmaf(blo(pv.w), s1.z, h1.z), 0.f), fmaxf(fmaf(bhi(pv.w), s1.w, h1.w), 0.f)));
#pragma unroll
            for (int t = 0; t < NT; ++t) {
                const bf16x8 bf = *(const bf16x8*)&Bp[(((ks * NT + t) * 64) + lane) * 8];
                acc[t] = __builtin_amdgcn_mfma_f32_16x16x32_bf16(aact, bf, acc[t], 0, 0, 0);
            }
#pragma unroll
            for (int t = 0; t < NT; ++t) {
                const bf16x8 bf = *(const bf16x8*)&Bp[((((ks + 4) * NT + t) * 64) + lane) * 8];
                acc[t] = __builtin_amdgcn_mfma_f32_16x16x32_bf16(apre, bf, acc[t], 0, 0, 0);
            }
        }
    }

    // per-wave chunked epilogue: LDS transpose -> pack -> vector stores
    float* cl = Cl[w];
#pragma unroll
    for (int t0 = 0; t0 < NT; t0 += TC) {
#pragma unroll
        for (int tt = 0; tt < TC; ++tt)
#pragma unroll
            for (int r = 0; r < 4; ++r)
                cl[(quad * 4 + r) * NCC + tt * 16 + lane15] = acc[t0 + tt][r];
        if (FP8OUT) {
            constexpr int BPL = NCC / 4;     // fp8 bytes per lane
            const int f = lane * BPL;
            const int r = f / NCC;
            const int col = f % NCC;
            const int grow = row0 + w * 16 + r;
            unsigned ou[BPL / 4];
#pragma unroll
            for (int q = 0; q < BPL / 4; ++q) {
                const float4 v = *(const float4*)&cl[f + q * 4];
                ou[q] = pk_fp8x4(v.x, v.y, v.z, v.w);
            }
            if (grow < M) {
                unsigned char* cp = (unsigned char*)Cv + (long)grow * (NT * 16) + t0 * 16 + col;
                if (BPL == 16) *(uint4*)cp = make_uint4(ou[0], ou[1], ou[2], ou[3]);
                else           *(uint2*)cp = make_uint2(ou[0], ou[1]);
            }
        } else {
#pragma unroll
            for (int i = 0; i < (16 * NCC) / 512; ++i) {
                const int f = i * 512 + lane * 8;
                const int r = f / NCC;
                const int col = f % NCC;
                const int grow = row0 + w * 16 + r;
                const float4 lo = *(const float4*)&cl[f];
                const float4 hi = *(const float4*)&cl[f + 4];
                uint4 o;
                o.x = pack2(lo.x, lo.y);
                o.y = pack2(lo.z, lo.w);
                o.z = pack2(hi.x, hi.y);
                o.w = pack2(hi.z, hi.w);
                if (grow < M) *(uint4*)((short*)Cv + (long)grow * (NT * 16) + t0 * 16 + col) = o;
            }
        }
    }
}

// fused: layer-0 GEMM (fp8 C) + phase-1 LDS histogram + W1/W2 packing
__global__ __launch_bounds__(256) void gemm0_hist1(
    const float* __restrict__ x, const short* __restrict__ Bp, unsigned char* __restrict__ C, int M,
    const int* __restrict__ dst, int* __restrict__ bh,
    const float* __restrict__ W1, const float* __restrict__ W2,
    short* __restrict__ Bp1, short* __restrict__ Bp2)
{
    __shared__ int cnt[256];
    if (blockIdx.x < GB0) {
        gemm_body<8, 0, true>(x, Bp, C, M, nullptr, nullptr, nullptr, nullptr);
    } else if (blockIdx.x < GB0 + NBLK1) {
        const int k = blockIdx.x - GB0;
        cnt[threadIdx.x] = 0;
        __syncthreads();
        const int base = k * 2048;
#pragma unroll
        for (int i = 0; i < 8; ++i) {
            const int e = base + i * 256 + threadIdx.x;
            if (e < NE) atomicAdd(&cnt[(unsigned)dst[e] >> 8], 1);
        }
        __syncthreads();
        bh[k * 256 + threadIdx.x] = cnt[threadIdx.x];
    } else if (blockIdx.x < GB0 + NBLK1 + 128) {
        packb_body(W1, Bp1, 8, blockIdx.x - (GB0 + NBLK1));
    } else {
        packb_body(W2, Bp2, 2, blockIdx.x - (GB0 + NBLK1 + 128));
    }
}

// S1: per-bucket exclusive prefix over the NBLK1 chunk-counts (in place), total -> btot
__global__ __launch_bounds__(256) void s1_k(int* __restrict__ bh, int* __restrict__ btot)
{
    __shared__ int a[512];
    const int b = blockIdx.x;
    const int t = threadIdx.x;
    const int v0 = (t < NBLK1) ? bh[t * 256 + b] : 0;
    const int v1 = (t + 256 < NBLK1) ? bh[(t + 256) * 256 + b] : 0;
    a[t] = v0; a[256 + t] = v1;
    __syncthreads();
    for (int off = 1; off < 256; off <<= 1) {
        const int t0 = (t >= off) ? a[t - off] : 0;
        const int t1 = (t >= off) ? a[256 + t - off] : 0;
        __syncthreads();
        a[t] += t0; a[256 + t] += t1;
        __syncthreads();
    }
    const int half = a[255];
    __syncthreads();
    a[256 + t] += half;
    __syncthreads();
    bh[t * 256 + b] = a[t] - v0;
    if (t + 256 < NBLK1) bh[(t + 256) * 256 + b] = a[256 + t] - v1;
    if (t == 255) btot[b] = a[511];
}

// scatter1: partition into bucket-contiguous staging; base computed by LDS scan of btot
__global__ __launch_bounds__(256) void scatter1_k(
    const int* __restrict__ src, const int* __restrict__ dst, const float* __restrict__ ew,
    const int* __restrict__ bh, const int* __restrict__ btot,
    unsigned* __restrict__ ebA, unsigned char* __restrict__ ebB)
{
    __shared__ int tmp[256];
    __shared__ int myoff[256];
    const int k = blockIdx.x;
    const int t = threadIdx.x;
    const int v = (t < NBUCK) ? btot[t] : 0;
    tmp[t] = v;
    __syncthreads();
    for (int off = 1; off < 256; off <<= 1) {
        const int x = (t >= off) ? tmp[t - off] : 0;
        __syncthreads();
        tmp[t] += x;
        __syncthreads();
    }
    myoff[t] = bh[k * 256 + t] + (tmp[t] - v);
    __syncthreads();
    const int ebase = k * 2048;
#pragma unroll
    for (int i = 0; i < 8; ++i) {
        const int e = ebase + i * 256 + t;
        if (e < NE) {
            const int d = dst[e];
            const int pos = atomicAdd(&myoff[(unsigned)d >> 8], 1);
            const unsigned wb = (unsigned)__half_as_ushort(__float2half_rn(ew[e]));
            ebA[pos] = ((unsigned)src[e] & 0xFFFFu) | (wb << 16);
            ebB[pos] = (unsigned char)(d & 255);
        }
    }
}

// phase2: per bucket: count -> scan -> rs + final pe scatter (LDS only)
__global__ __launch_bounds__(256) void phase2_k(
    const unsigned* __restrict__ ebA, const unsigned char* __restrict__ ebB,
    const int* __restrict__ btot, int* __restrict__ rs, unsigned* __restrict__ pe)
{
    __shared__ int bscan[256];
    __shared__ int cnt[256];
    __shared__ int cur[256];
    const int b = blockIdx.x;
    const int t = threadIdx.x;
    const int v0 = (t < NBUCK) ? btot[t] : 0;
    bscan[t] = v0;
    __syncthreads();
    for (int off = 1; off < 256; off <<= 1) {
        const int x = (t >= off) ? bscan[t - off] : 0;
        __syncthreads();
        bscan[t] += x;
        __syncthreads();
    }
    const int e1 = bscan[b];
    const int e0 = e1 - btot[b];
    cnt[t] = 0;
    __syncthreads();
    for (int e = e0 + t; e < e1; e += 256) atomicAdd(&cnt[ebB[e]], 1);
    __syncthreads();
    const int v = cnt[t];
    __syncthreads();
    for (int off = 1; off < 256; off <<= 1) {
        const int x = (t >= off) ? cnt[t - off] : 0;
        __syncthreads();
        cnt[t] += x;
        __syncthreads();
    }
    const int exc = cnt[t] - v;
    const int node = b * 256 + t;
    if (node < NN) rs[node] = e0 + exc;
    if (b == 0 && t == 0) rs[NN] = NE;
    cur[t] = e0 + exc;
    __syncthreads();
    for (int e = e0 + t; e < e1; e += 256) {
        const int pos = atomicAdd(&cur[ebB[e]], 1);
        pe[pos] = ebA[e];
    }
}

template <int NT>
__global__ __launch_bounds__(256) void gemm_bn(
    const unsigned* __restrict__ A, const short* __restrict__ Bp, short* __restrict__ C, int M,
    const float* __restrict__ sum, const float* __restrict__ ss,
    const float* __restrict__ gam, const float* __restrict__ bet)
{
    gemm_body<NT, 1, false>(A, Bp, C, M, sum, ss, gam, bet);
}

// ================= aggregation, layer 0: fp8 h rows (128 B) =================
// 2 nodes/wave, 32 lanes/node; lane handles 4 channels (1 uint gather/edge)
__global__ __launch_bounds__(256) void agg128f8(
    const unsigned* __restrict__ h4, const int* __restrict__ rs,
    const unsigned* __restrict__ pe, unsigned* __restrict__ outp)
{
    const int node = blockIdx.x * 8 + (threadIdx.x >> 5);
    const int l = threadIdx.x & 31;
    int j = rs[node];
    const int j1 = rs[node + 1];
    float a0[4], a1[4], a2[4], a3[4];
#pragma unroll
    for (int t = 0; t < 4; ++t) { a0[t] = 0.f; a1[t] = 0.f; a2[t] = 0.f; a3[t] = 0.f; }
    for (; j + 7 < j1; j += 8) {
        unsigned u[8], v[8];
#pragma unroll
        for (int t = 0; t < 8; ++t) u[t] = pe[j + t];
#pragma unroll
        for (int t = 0; t < 8; ++t) v[t] = h4[(long)(u[t] & 0xFFFFu) * 32 + l];
#pragma unroll
        for (int t = 0; t < 8; ++t) {
            const float w = edgew(u[t]);
            const f32x2 lo = __builtin_amdgcn_cvt_pk_f32_fp8((int)v[t], false);
            const f32x2 hi = __builtin_amdgcn_cvt_pk_f32_fp8((int)v[t], true);
            a0[t & 3] = fmaf(w, lo.x, a0[t & 3]);
            a1[t & 3] = fmaf(w, lo.y, a1[t & 3]);
            a2[t & 3] = fmaf(w, hi.x, a2[t & 3]);
            a3[t & 3] = fmaf(w, hi.y, a3[t & 3]);
        }
    }
    for (; j < j1; ++j) {
        const unsigned u = pe[j];
        const unsigned v = h4[(long)(u & 0xFFFFu) * 32 + l];
        const float w = edgew(u);
        const f32x2 lo = __builtin_amdgcn_cvt_pk_f32_fp8((int)v, false);
        const f32x2 hi = __builtin_amdgcn_cvt_pk_f32_fp8((int)v, true);
        a0[0] = fmaf(w, lo.x, a0[0]);
        a1[0] = fmaf(w, lo.y, a1[0]);
        a2[0] = fmaf(w, hi.x, a2[0]);
        a3[0] = fmaf(w, hi.y, a3[0]);
    }
    uint2 o;
    o.x = pack2((a0[0] + a0[1]) + (a0[2] + a0[3]), (a1[0] + a1[1]) + (a1[2] + a1[3]));
    o.y = pack2((a2[0] + a2[1]) + (a2[2] + a2[3]), (a3[0] + a3[1]) + (a3[2] + a3[3]));
    ((uint2*)outp)[(long)node * 32 + l] = o;
}

// ================= aggregation, layer 1: bf16 h rows (256 B) =================
// 2 nodes/wave, 32 lanes/node, uint2 gathers
__global__ __launch_bounds__(256) void agg128b(
    const unsigned* __restrict__ h2, const int* __restrict__ rs,
    const unsigned* __restrict__ pe, unsigned* __restrict__ outp)
{
    const int node = blockIdx.x * 8 + (threadIdx.x >> 5);
    const int l = threadIdx.x & 31;
    int j = rs[node];
    const int j1 = rs[node + 1];
    const uint2* hp = (const uint2*)h2;   // rows of 32 uint2
    float xa[4], ya[4], xb[4], yb[4];
#pragma unroll
    for (int t = 0; t < 4; ++t) { xa[t] = 0.f; ya[t] = 0.f; xb[t] = 0.f; yb[t] = 0.f; }
    for (; j + 7 < j1; j += 8) {
        unsigned u[8]; uint2 v[8];
#pragma unroll
        for (int t = 0; t < 8; ++t) u[t] = pe[j + t];
#pragma unroll
        for (int t = 0; t < 8; ++t) v[t] = hp[(long)(u[t] & 0xFFFFu) * 32 + l];
#pragma unroll
        for (int t = 0; t < 8; ++t) {
            const float w = edgew(u[t]);
            xa[t & 3] = fmaf(w, blo(v[t].x), xa[t & 3]);
            ya[t & 3] = fmaf(w, bhi(v[t].x), ya[t & 3]);
            xb[t & 3] = fmaf(w, blo(v[t].y), xb[t & 3]);
            yb[t & 3] = fmaf(w, bhi(v[t].y), yb[t & 3]);
        }
    }
    for (; j < j1; ++j) {
        const unsigned u = pe[j];
        const uint2 v = hp[(long)(u & 0xFFFFu) * 32 + l];
        const float w = edgew(u);
        xa[0] = fmaf(w, blo(v.x), xa[0]); ya[0] = fmaf(w, bhi(v.x), ya[0]);
        xb[0] = fmaf(w, blo(v.y), xb[0]); yb[0] = fmaf(w, bhi(v.y), yb[0]);
    }
    uint2 o;
    o.x = pack2((xa[0] + xa[1]) + (xa[2] + xa[3]), (ya[0] + ya[1]) + (ya[2] + ya[3]));
    o.y = pack2((xb[0] + xb[1]) + (xb[2] + xb[3]), (yb[0] + yb[1]) + (yb[2] + yb[3]));
    ((uint2*)outp)[(long)node * 32 + l] = o;
}

// 8 lanes/node, uint2 gathers (bf16 h rows of 32), float4 fp32 output [NN,32]
__global__ __launch_bounds__(256) void agg32b(
    const unsigned* __restrict__ h2, const int* __restrict__ rs,
    const unsigned* __restrict__ pe, float* __restrict__ out)
{
    const int node = blockIdx.x * 32 + (threadIdx.x >> 3);
    if (node >= NN) return;
    const int l = threadIdx.x & 7;
    int j = rs[node];
    const int j1 = rs[node + 1];
    const uint2* hp = (const uint2*)h2;   // rows of 8 uint2
    float xa[4], ya[4], xb[4], yb[4];
#pragma unroll
    for (int t = 0; t < 4; ++t) { xa[t] = 0.f; ya[t] = 0.f; xb[t] = 0.f; yb[t] = 0.f; }
    for (; j + 7 < j1; j += 8) {
        unsigned u[8]; uint2 v[8];
#pragma unroll
        for (int t = 0; t < 8; ++t) u[t] = pe[j + t];
#pragma unroll
        for (int t = 0; t < 8; ++t) v[t] = hp[(long)(u[t] & 0xFFFFu) * 8 + l];
#pragma unroll
        for (int t = 0; t < 8; ++t) {
            const float w = edgew(u[t]);
            xa[t & 3] = fmaf(w, blo(v[t].x), xa[t & 3]);
            ya[t & 3] = fmaf(w, bhi(v[t].x), ya[t & 3]);
            xb[t & 3] = fmaf(w, blo(v[t].y), xb[t & 3]);
            yb[t & 3] = fmaf(w, bhi(v[t].y), yb[t & 3]);
        }
    }
    for (; j < j1; ++j) {
        const unsigned u = pe[j];
        const uint2 v = hp[(long)(u & 0xFFFFu) * 8 + l];
        const float w = edgew(u);
        xa[0] = fmaf(w, blo(v.x), xa[0]); ya[0] = fmaf(w, bhi(v.x), ya[0]);
        xb[0] = fmaf(w, blo(v.y), xb[0]); yb[0] = fmaf(w, bhi(v.y), yb[0]);
    }
    float4 o;
    o.x = (xa[0] + xa[1]) + (xa[2] + xa[3]);
    o.y = (ya[0] + ya[1]) + (ya[2] + ya[3]);
    o.z = (xb[0] + xb[1]) + (xb[2] + xb[3]);
    o.w = (yb[0] + yb[1]) + (yb[2] + yb[3]);
    ((float4*)out)[(long)node * 8 + l] = o;
}

// ================= BN stats (pre rows = 64 uints bf16x2), row-pair unrolled =================
__global__ __launch_bounds__(256) void bn_stats_b(
    const unsigned* __restrict__ pre, float* __restrict__ sum, float* __restrict__ ss, int M)
{
    const int c2 = threadIdx.x & 63;
    const int g = threadIdx.x >> 6;
    float s0 = 0.f, s1 = 0.f, q0 = 0.f, q1 = 0.f;
    float s2 = 0.f, s3 = 0.f, q2 = 0.f, q3 = 0.f;
    for (int row = blockIdx.x * 8 + g * 2; row < M; row += gridDim.x * 8) {
        const unsigned v = pre[(long)row * 64 + c2];
        const unsigned v2 = pre[(long)(row + 1) * 64 + c2];
        const float lo = blo(v), hi = bhi(v);
        const float lo2 = blo(v2), hi2 = bhi(v2);
        s0 += lo; s1 += hi;
        q0 = fmaf(lo, lo, q0); q1 = fmaf(hi, hi, q1);
        s2 += lo2; s3 += hi2;
        q2 = fmaf(lo2, lo2, q2); q3 = fmaf(hi2, hi2, q3);
    }
    s0 += s2; s1 += s3; q0 += q2; q1 += q3;
    __shared__ float A0[256], A1[256], B0[256], B1[256];
    A0[threadIdx.x] = s0; A1[threadIdx.x] = s1;
    B0[threadIdx.x] = q0; B1[threadIdx.x] = q1;
    __syncthreads();
    if (threadIdx.x < 64) {
        const int t = threadIdx.x;
        atomicAdd(&sum[2 * t],     A0[t] + A0[t + 64] + A0[t + 128] + A0[t + 192]);
        atomicAdd(&sum[2 * t + 1], A1[t] + A1[t + 64] + A1[t + 128] + A1[t + 192]);
        atomicAdd(&ss[2 * t],      B0[t] + B0[t + 64] + B0[t + 128] + B0[t + 192]);
        atomicAdd(&ss[2 * t + 1],  B1[t] + B1[t + 64] + B1[t + 128] + B1[t + 192]);
    }
}

extern "C" void kernel_launch(void* const* d_in, const int* in_sizes, int n_in,
                              void* d_out, int out_size, void* d_ws, size_t ws_size,
                              hipStream_t stream) {
    const float* x   = (const float*)d_in[0];
    const int*   src = (const int*)d_in[1];
    const int*   dst = (const int*)d_in[2];
    const float* ew  = (const float*)d_in[3];
    const float* W0  = (const float*)d_in[4];
    const float* W1  = (const float*)d_in[5];
    const float* W2  = (const float*)d_in[6];
    const float* g0  = (const float*)d_in[7];
    const float* b0  = (const float*)d_in[8];
    const float* g1  = (const float*)d_in[9];
    const float* b1  = (const float*)d_in[10];
    float* out = (float*)d_out;

    // workspace layout (h sized for bf16 [NN,128]; fp8 layer-0 aliases the front)
    short* h   = (short*)d_ws;                         // bf16 [NN*128] / fp8 [NN*128] bytes
    unsigned* x1p = (unsigned*)(h + (size_t)NN * 128); // [NN*64] uints = pre-only bf16x2
    float* st  = (float*)(x1p + (size_t)NN * 64);      // 1024 floats
    int*  rs   = (int*)(st + 1024);                    // 50004
    int*  bh   = rs + 50004;                           // NBLK1*256
    int*  btot = bh + NBLK1 * 256;                     // 256
    unsigned* ebA = (unsigned*)(btot + 256);           // NE staged src|w
    unsigned char* ebB = (unsigned char*)(ebA + NE);   // NE dst low bytes
    unsigned* pe = (unsigned*)(ebB + ((NE + 255) & ~255)); // NE final packed edges
    short* Bp0 = (short*)(pe + NE);                    // 32768
    short* Bp1 = Bp0 + 32768;                          // 32768
    short* Bp2 = Bp1 + 32768;                          // 8192

    float* sum0 = st,       *ss0 = st + 128;
    float* sum1 = st + 512, *ss1 = st + 640;

    hipMemsetAsync(st, 0, 1024 * 4, stream);

    packb0_k<<<128, 256, 0, stream>>>(W0, Bp0);

    // layer-0 GEMM (fp8 h) + phase-1 histogram + W1/W2 packing (one launch)
    gemm0_hist1<<<GB0 + NBLK1 + 160, 256, 0, stream>>>(x, Bp0, (unsigned char*)h, NN, dst, bh, W1, W2, Bp1, Bp2);

    s1_k<<<NBUCK, 256, 0, stream>>>(bh, btot);
    scatter1_k<<<NBLK1, 256, 0, stream>>>(src, dst, ew, bh, btot, ebA, ebB);
    phase2_k<<<NBUCK, 256, 0, stream>>>(ebA, ebB, btot, rs, pe);

    // ---- layer 0 aggregation (fp8 gathers) + stats ----
    agg128f8<<<6250, 256, 0, stream>>>((const unsigned*)h, rs, pe, x1p);
    bn_stats_b<<<256, 256, 0, stream>>>(x1p, sum0, ss0, NN);

    // ---- layer 1 (BN0+ReLU fused into fragment load; bf16 h out) ----
    gemm_bn<8><<<782, 256, 0, stream>>>(x1p, Bp1, h, NN, sum0, ss0, g0, b0);
    agg128b<<<6250, 256, 0, stream>>>((const unsigned*)h, rs, pe, x1p);
    bn_stats_b<<<256, 256, 0, stream>>>(x1p, sum1, ss1, NN);

    // ---- output layer (bf16 h out) ----
    gemm_bn<2><<<782, 256, 0, stream>>>(x1p, Bp2, h, NN, sum1, ss1, g1, b1);
    agg32b<<<1563, 256, 0, stream>>>((const unsigned*)h, rs, pe, out);
}